// Round 9
// baseline (1178.677 us; speedup 1.0000x reference)
//
#include <hip/hip_runtime.h>
#include <math.h>

#define B_   64
#define TOK_ 64
#define NT_  456
#define L_   457
#define D_   256
#define H_   8
#define HD_  32
#define FF_  1024
#define NL_  4
#define PH_  32
#define MPAD 29312   // 229 * 128 (rows padded for 128-row GEMM tiles)

typedef unsigned int uint;
typedef unsigned short ushort;
typedef __bf16 v8bf __attribute__((ext_vector_type(8)));
typedef __bf16 v4bf __attribute__((ext_vector_type(4)));
typedef short v4s __attribute__((ext_vector_type(4)));
typedef float v4f __attribute__((ext_vector_type(4)));

__device__ __forceinline__ float bu2f(ushort x) {
    return __uint_as_float(((uint)x) << 16);
}
__device__ __forceinline__ ushort f2bu(float f) {
    union { float f; uint u; } x; x.f = f;
    uint r = (x.u + 0x7fffu + ((x.u >> 16) & 1u)) >> 16;
    return (ushort)r;
}
__device__ __forceinline__ uint pack_bf2(float a, float b) {
#if defined(__HIP_DEVICE_COMPILE__) && __has_builtin(__builtin_amdgcn_cvt_pk_bf16_f32)
    typedef __bf16 bf2v __attribute__((ext_vector_type(2)));
    bf2v v = __builtin_amdgcn_cvt_pk_bf16_f32(a, b);
    return *(uint*)&v;
#else
    return (uint)f2bu(a) | ((uint)f2bu(b) << 16);
#endif
}

// K=16 bf16 MFMA (PV with register-resident P). Guarded for the host pass:
// hipcc compiles twice and __has_builtin(amdgcn.*) is false on host.
__device__ __forceinline__ v4f mfma16(uint2 a, uint2 b, v4f c) {
#if defined(__HIP_DEVICE_COMPILE__)
#if __has_builtin(__builtin_amdgcn_mfma_f32_16x16x16_bf16)
    return __builtin_amdgcn_mfma_f32_16x16x16_bf16(*(v4bf*)&a, *(v4bf*)&b, c, 0, 0, 0);
#else
    return __builtin_amdgcn_mfma_f32_16x16x16bf16_1k(*(v4s*)&a, *(v4s*)&b, c, 0, 0, 0);
#endif
#else
    (void)a; (void)b;
    return c;   // host pass: never executed
#endif
}

// async global->LDS 16B copy; lds base wave-uniform, data at base + lane*16.
__device__ __forceinline__ void gload16(const void* g, void* l) {
    __builtin_amdgcn_global_load_lds(
        (const __attribute__((address_space(1))) void*)(unsigned long long)(uintptr_t)g,
        (__attribute__((address_space(3))) void*)(uint)(uintptr_t)l,
        16, 0, 0);
}

// ---------------------------------------------------------------------------
// bf16 MFMA GEMM (m97 structure): C[M,N] = A[M,K]·W^T[N,K] + bias.
// ---------------------------------------------------------------------------
__global__ __launch_bounds__(256) void mfma_gemm(
    const ushort* __restrict__ A, const ushort* __restrict__ WT,
    const float* __restrict__ bias, void* __restrict__ Cout,
    int N, int K, int relu, int obf16)
{
    __shared__ ushort As[128 * 32];
    __shared__ ushort Bs[128 * 32];
    int tid = threadIdx.x;
    int wave = tid >> 6, lane = tid & 63;
    int colblk = blockIdx.x * 128;
    int rowblk = blockIdx.y * 128;
    int wm = wave >> 1, wn = wave & 1;

    v4f acc[4][4];
#pragma unroll
    for (int i = 0; i < 4; ++i)
#pragma unroll
        for (int j = 0; j < 4; ++j) acc[i][j] = (v4f)0.0f;

    int fr = lane & 15, fq = lane >> 4;
    int scol = fq ^ (lane & 3) ^ ((lane >> 2) & 1);

    int c0 = wave * 64 + lane;
    int r0 = c0 >> 2, k0g = (c0 & 3) ^ (r0 & 3) ^ ((r0 >> 2) & 1);
    int c1 = 256 + c0;
    int r1 = c1 >> 2, k1g = (c1 & 3) ^ (r1 & 3) ^ ((r1 >> 2) & 1);

    const ushort* Ag0 = A + (size_t)(rowblk + r0) * K + k0g * 8;
    const ushort* Ag1 = A + (size_t)(rowblk + r1) * K + k1g * 8;
    const ushort* Bg0 = WT + (size_t)(colblk + r0) * K + k0g * 8;
    const ushort* Bg1 = WT + (size_t)(colblk + r1) * K + k1g * 8;
    ushort* lA0 = As + (size_t)(wave * 64) * 8;
    ushort* lA1 = As + (size_t)(256 + wave * 64) * 8;
    ushort* lB0 = Bs + (size_t)(wave * 64) * 8;
    ushort* lB1 = Bs + (size_t)(256 + wave * 64) * 8;

    for (int kt = 0; kt < K; kt += 32) {
        gload16(Ag0 + kt, lA0);
        gload16(Ag1 + kt, lA1);
        gload16(Bg0 + kt, lB0);
        gload16(Bg1 + kt, lB1);
        __syncthreads();

        v8bf a[4], b[4];
#pragma unroll
        for (int mi = 0; mi < 4; ++mi)
            a[mi] = *(const v8bf*)(As + (size_t)(wm * 64 + mi * 16 + fr) * 32 + scol * 8);
#pragma unroll
        for (int ni = 0; ni < 4; ++ni)
            b[ni] = *(const v8bf*)(Bs + (size_t)(wn * 64 + ni * 16 + fr) * 32 + scol * 8);
#pragma unroll
        for (int mi = 0; mi < 4; ++mi)
#pragma unroll
            for (int ni = 0; ni < 4; ++ni)
                acc[mi][ni] = __builtin_amdgcn_mfma_f32_16x16x32_bf16(
                    a[mi], b[ni], acc[mi][ni], 0, 0, 0);
        __syncthreads();
    }

#pragma unroll
    for (int ni = 0; ni < 4; ++ni) {
        int col = colblk + wn * 64 + ni * 16 + fr;
        float bv = bias[col];
#pragma unroll
        for (int mi = 0; mi < 4; ++mi) {
            int row = rowblk + wm * 64 + mi * 16 + fq * 4;
#pragma unroll
            for (int r = 0; r < 4; ++r) {
                float v = acc[mi][ni][r] + bv;
                if (relu) v = fmaxf(v, 0.f);
                if (obf16)
                    ((ushort*)Cout)[(size_t)(row + r) * N + col] = f2bu(v);
                else
                    ((float*)Cout)[(size_t)(row + r) * N + col] = v;
            }
        }
    }
}

// ---------------------------------------------------------------------------
// Fused FFN2 + bias + residual + LayerNorm: tile 64 rows x 256 cols (full N).
// C = A[M,1024]·W2T[256,1024]; v = C + bias + X; X,Xb <- LN(v).
// 4 waves: wave wn covers cols wn*64.. ; per-row stats via in-reg fr-shuffles
// + cross-wave LDS combine. Grid: MPAD/64.
// ---------------------------------------------------------------------------
__global__ __launch_bounds__(256) void ffn2_ln(
    const ushort* __restrict__ A, const ushort* __restrict__ WT,
    const float* __restrict__ bias, const float* __restrict__ g,
    const float* __restrict__ bbeta, float* __restrict__ X,
    ushort* __restrict__ Xb)
{
    __shared__ ushort As[64 * 32];
    __shared__ ushort Bs[256 * 32];
    __shared__ float stats[4][64][2];
    int tid = threadIdx.x;
    int wave = tid >> 6, lane = tid & 63;
    int fr = lane & 15, fq = lane >> 4;
    int rowblk = blockIdx.x * 64;
    int wn = wave;

    v4f acc[4][4];
#pragma unroll
    for (int i = 0; i < 4; ++i)
#pragma unroll
        for (int j = 0; j < 4; ++j) acc[i][j] = (v4f)0.0f;

    int scol = fq ^ (lane & 3) ^ ((lane >> 2) & 1);

    int ca = wave * 64 + lane;
    int ar = ca >> 2, akg = (ca & 3) ^ (ar & 3) ^ ((ar >> 2) & 1);
    const ushort* Ag = A + (size_t)(rowblk + ar) * 1024 + akg * 8;
    ushort* lA = As + (size_t)(wave * 64) * 8;

    const ushort* Bg[4];
    ushort* lB[4];
#pragma unroll
    for (int p = 0; p < 4; ++p) {
        int c = p * 256 + ca;
        int br = c >> 2, bkg = (c & 3) ^ (br & 3) ^ ((br >> 2) & 1);
        Bg[p] = WT + (size_t)br * 1024 + bkg * 8;
        lB[p] = Bs + (size_t)(p * 256 + wave * 64) * 8;
    }

    for (int kt = 0; kt < 1024; kt += 32) {
        gload16(Ag + kt, lA);
#pragma unroll
        for (int p = 0; p < 4; ++p) gload16(Bg[p] + kt, lB[p]);
        __syncthreads();

        v8bf a[4], b[4];
#pragma unroll
        for (int mi = 0; mi < 4; ++mi)
            a[mi] = *(const v8bf*)(As + (size_t)(mi * 16 + fr) * 32 + scol * 8);
#pragma unroll
        for (int ni = 0; ni < 4; ++ni)
            b[ni] = *(const v8bf*)(Bs + (size_t)(wn * 64 + ni * 16 + fr) * 32 + scol * 8);
#pragma unroll
        for (int mi = 0; mi < 4; ++mi)
#pragma unroll
            for (int ni = 0; ni < 4; ++ni)
                acc[mi][ni] = __builtin_amdgcn_mfma_f32_16x16x32_bf16(
                    a[mi], b[ni], acc[mi][ni], 0, 0, 0);
        __syncthreads();
    }

    // ---- epilogue: bias + residual, per-row stats, LN, dual write ----
    int col[4];
    float bv[4], gv[4], bbv[4];
#pragma unroll
    for (int ni = 0; ni < 4; ++ni) {
        col[ni] = wn * 64 + ni * 16 + fr;
        bv[ni] = bias[col[ni]];
        gv[ni] = g[col[ni]];
        bbv[ni] = bbeta[col[ni]];
    }
#pragma unroll
    for (int mi = 0; mi < 4; ++mi) {
#pragma unroll
        for (int r = 0; r < 4; ++r) {
            int lr = mi * 16 + fq * 4 + r;
            int row = rowblk + lr;
            float s = 0.f, s2 = 0.f;
#pragma unroll
            for (int ni = 0; ni < 4; ++ni) {
                float v = acc[mi][ni][r] + bv[ni] + X[(size_t)row * 256 + col[ni]];
                acc[mi][ni][r] = v;
                s += v;
                s2 += v * v;
            }
#pragma unroll
            for (int o = 1; o < 16; o <<= 1) {
                s += __shfl_xor(s, o);
                s2 += __shfl_xor(s2, o);
            }
            if (fr == 0) {
                stats[wave][lr][0] = s;
                stats[wave][lr][1] = s2;
            }
        }
    }
    __syncthreads();
#pragma unroll
    for (int mi = 0; mi < 4; ++mi) {
#pragma unroll
        for (int r = 0; r < 4; ++r) {
            int lr = mi * 16 + fq * 4 + r;
            int row = rowblk + lr;
            float tot = stats[0][lr][0] + stats[1][lr][0] + stats[2][lr][0] + stats[3][lr][0];
            float tot2 = stats[0][lr][1] + stats[1][lr][1] + stats[2][lr][1] + stats[3][lr][1];
            float mean = tot * (1.0f / 256.0f);
            float var = tot2 * (1.0f / 256.0f) - mean * mean;
            float rstd = rsqrtf(fmaxf(var, 0.f) + 1e-5f);
#pragma unroll
            for (int ni = 0; ni < 4; ++ni) {
                float o = (acc[mi][ni][r] - mean) * rstd * gv[ni] + bbv[ni];
                X[(size_t)row * 256 + col[ni]] = o;
                Xb[(size_t)row * 256 + col[ni]] = f2bu(o);
            }
        }
    }
}

// ---------------------------------------------------------------------------
__global__ __launch_bounds__(256) void wcast_kernel(
    const float* __restrict__ W, ushort* __restrict__ WT, int K, int N)
{
    __shared__ float t[32][33];
    const float* Wl = W + (size_t)blockIdx.z * K * N;
    ushort* WTl = WT + (size_t)blockIdx.z * K * N;
    int n0 = blockIdx.x * 32, k0 = blockIdx.y * 32;
    int tx = threadIdx.x, ty = threadIdx.y;
#pragma unroll
    for (int r = 0; r < 32; r += 8)
        t[ty + r][tx] = Wl[(size_t)(k0 + ty + r) * N + n0 + tx];
    __syncthreads();
#pragma unroll
    for (int r = 0; r < 32; r += 8)
        WTl[(size_t)(n0 + ty + r) * K + k0 + tx] = f2bu(t[tx][ty + r]);
}

// ---------------------------------------------------------------------------
// fp32 SGEMM for the embed GEMM only; row-remap; writes fp32 X and bf16 Xb.
// ---------------------------------------------------------------------------
__global__ __launch_bounds__(256) void sgemm_kernel(
    const float* __restrict__ A, const float* __restrict__ W,
    const float* __restrict__ bias, float* __restrict__ C,
    ushort* __restrict__ Cb, int M, int N, int K)
{
    __shared__ float As_[16][64];
    __shared__ float Bs_[16][64];
    int tid = threadIdx.x;
    int rowblk = blockIdx.y * 64;
    int colblk = blockIdx.x * 64;
    int a_row = tid & 63, a_q = tid >> 6;
    int b_kr = tid >> 4, b_cg = tid & 15;
    int rm = tid >> 4, cn = tid & 15;
    float acc[4][4] = {};
    const float* Aptr = A + (size_t)(rowblk + a_row) * K;
    for (int kt = 0; kt < K; kt += 16) {
        float4 av = *(const float4*)(Aptr + kt + a_q * 4);
        float4 bv = *(const float4*)(W + (size_t)(kt + b_kr) * N + colblk + b_cg * 4);
        As_[a_q * 4 + 0][a_row] = av.x;
        As_[a_q * 4 + 1][a_row] = av.y;
        As_[a_q * 4 + 2][a_row] = av.z;
        As_[a_q * 4 + 3][a_row] = av.w;
        *(float4*)&Bs_[b_kr][b_cg * 4] = bv;
        __syncthreads();
#pragma unroll
        for (int kk = 0; kk < 16; ++kk) {
            float4 a4 = *(const float4*)&As_[kk][rm * 4];
            float4 b4 = *(const float4*)&Bs_[kk][cn * 4];
            float ar[4] = {a4.x, a4.y, a4.z, a4.w};
            float br[4] = {b4.x, b4.y, b4.z, b4.w};
#pragma unroll
            for (int i = 0; i < 4; ++i)
#pragma unroll
                for (int j = 0; j < 4; ++j) acc[i][j] += ar[i] * br[j];
        }
        __syncthreads();
    }
    float4 bv = *(const float4*)(bias + colblk + cn * 4);
    float bb[4] = {bv.x, bv.y, bv.z, bv.w};
#pragma unroll
    for (int i = 0; i < 4; ++i) {
        int grow = rowblk + rm * 4 + i;
        size_t orow = (size_t)(grow + grow / NT_ + 1);
        float4 r;
        r.x = acc[i][0] + bb[0]; r.y = acc[i][1] + bb[1];
        r.z = acc[i][2] + bb[2]; r.w = acc[i][3] + bb[3];
        *(float4*)(C + orow * N + colblk + cn * 4) = r;
        ushort4 h;
        h.x = f2bu(r.x); h.y = f2bu(r.y); h.z = f2bu(r.z); h.w = f2bu(r.w);
        *(ushort4*)(Cb + orow * N + colblk + cn * 4) = h;
    }
}

__global__ __launch_bounds__(256) void cls_kernel(
    const float* __restrict__ coords, const float* __restrict__ w_cls,
    const float* __restrict__ b_cls, float* __restrict__ X,
    ushort* __restrict__ Xb)
{
    int b = blockIdx.x;
    int t = threadIdx.x;
    float c0 = coords[b * 3 + 0], c1 = coords[b * 3 + 1], c2 = coords[b * 3 + 2];
    float v = c0 * w_cls[t] + c1 * w_cls[D_ + t] + c2 * w_cls[2 * D_ + t] + b_cls[t];
    X[(size_t)b * L_ * D_ + t] = v;
    Xb[(size_t)b * L_ * D_ + t] = f2bu(v);
}

// ---------------------------------------------------------------------------
// MFMA attention v5: one block per (b,h), 512 threads (8 waves).
// K/V^T staged once (68.4 KB, 2 blocks/CU). QK (A=K,B=Q) leaves lane (fr,fq)
// with P(q=fr, k=4fq+r) == the B-operand layout of a K=16 MFMA, so PV runs
// straight from registers via mfma16 (transposed output): no P LDS round
// trip, no shuffles for row sums (psum lives at q=fr), O stored as 2 float4.
// ---------------------------------------------------------------------------
__global__ __launch_bounds__(512) void attn_kernel(
    const ushort* __restrict__ qkv, float* __restrict__ out)
{
    __shared__ __align__(16) ushort Ks[464][40];    // 36.3 KB
    __shared__ __align__(16) ushort Vt[32][488];    // 30.5 KB

    int h = blockIdx.x, b = blockIdx.y;
    int tid = threadIdx.x;
    int wave = tid >> 6, lane = tid & 63;
    int fr = lane & 15, fq = lane >> 4;
    const float scale = 0.17677669529663687f;
    float slope = (h < 4) ? 1.0f : 0.5f;
    const ushort* base = qkv + (size_t)b * L_ * 768;

    for (int j = tid >> 2; j < 464; j += 128) {
        int c8 = (tid & 3) * 8;
        uint4 u = make_uint4(0u, 0u, 0u, 0u);
        if (j < L_) u = *(const uint4*)(base + (size_t)j * 768 + 256 + h * 32 + c8);
        *(uint4*)&Ks[j][c8] = u;
    }
    for (int m = wave; m < 32; m += 8) {
        int dg = (m >> 3) * 8, jb = m & 7;
        int j = jb * 64 + lane;
        uint4 u = make_uint4(0u, 0u, 0u, 0u);
        if (j < L_) u = *(const uint4*)(base + (size_t)j * 768 + 512 + h * 32 + dg);
        if (j < 488) {
            const ushort* pu = (const ushort*)&u;
#pragma unroll
            for (int e = 0; e < 8; ++e) Vt[dg + e][j] = pu[e];
        }
    }
    __syncthreads();

    for (int t = wave; t < 29; t += 8) {
        int q0 = t * 16;
        uint4 qu = *(const uint4*)(base + (size_t)(q0 + fr) * 768 + h * 32 + fq * 8);
        v8bf qfrag = *(v8bf*)&qu;
        float fmyq = (float)(q0 + fr);
        float psum = 0.f;
        v4f ot0 = (v4f)0.0f, ot1 = (v4f)0.0f;   // O^T tiles: d 0..15 / 16..31, col q=fr

        for (int kc = 0; kc < 14; ++kc) {
            int kb = kc * 32;
            v8bf kf0 = *(const v8bf*)&Ks[kb + fr][fq * 8];
            v8bf kf1 = *(const v8bf*)&Ks[kb + 16 + fr][fq * 8];
            v4f d0 = (v4f)0.0f, d1 = (v4f)0.0f;
            d0 = __builtin_amdgcn_mfma_f32_16x16x32_bf16(kf0, qfrag, d0, 0, 0, 0);
            d1 = __builtin_amdgcn_mfma_f32_16x16x32_bf16(kf1, qfrag, d1, 0, 0, 0);
            float ke = (float)(kb + 4 * fq);
            float pe[4], po[4];
#pragma unroll
            for (int r = 0; r < 4; ++r) {
                pe[r] = __expf(d0[r] * scale - slope * fabsf(fmyq - (ke + (float)r)));
                po[r] = __expf(d1[r] * scale - slope * fabsf(fmyq - (ke + 16.0f + (float)r)));
                psum += pe[r] + po[r];
            }
            uint2 ue, uo;
            ue.x = pack_bf2(pe[0], pe[1]); ue.y = pack_bf2(pe[2], pe[3]);
            uo.x = pack_bf2(po[0], po[1]); uo.y = pack_bf2(po[2], po[3]);
            uint2 va0 = *(const uint2*)&Vt[fr][kb + fq * 4];
            uint2 va1 = *(const uint2*)&Vt[16 + fr][kb + fq * 4];
            uint2 vb0 = *(const uint2*)&Vt[fr][kb + 16 + fq * 4];
            uint2 vb1 = *(const uint2*)&Vt[16 + fr][kb + 16 + fq * 4];
            ot0 = mfma16(va0, ue, ot0);
            ot1 = mfma16(va1, ue, ot1);
            ot0 = mfma16(vb0, uo, ot0);
            ot1 = mfma16(vb1, uo, ot1);
        }
        // tail: k 448..463
        {
            v8bf kf0 = *(const v8bf*)&Ks[448 + fr][fq * 8];
            v4f d0 = (v4f)0.0f;
            d0 = __builtin_amdgcn_mfma_f32_16x16x32_bf16(kf0, qfrag, d0, 0, 0, 0);
            float pe[4];
#pragma unroll
            for (int r = 0; r < 4; ++r) {
                int k = 448 + 4 * fq + r;
                pe[r] = (k < L_)
                    ? __expf(d0[r] * scale - slope * fabsf(fmyq - (float)k)) : 0.f;
                psum += pe[r];
            }
            uint2 ue;
            ue.x = pack_bf2(pe[0], pe[1]); ue.y = pack_bf2(pe[2], pe[3]);
            uint2 va0 = *(const uint2*)&Vt[fr][448 + fq * 4];
            uint2 va1 = *(const uint2*)&Vt[16 + fr][448 + fq * 4];
            ot0 = mfma16(va0, ue, ot0);
            ot1 = mfma16(va1, ue, ot1);
        }

        psum += __shfl_xor(psum, 16);
        psum += __shfl_xor(psum, 32);
        int q = q0 + fr;
        if (q < L_) {
            float inv = 1.0f / psum;
            float4 s0, s1;
            s0.x = ot0[0] * inv; s0.y = ot0[1] * inv;
            s0.z = ot0[2] * inv; s0.w = ot0[3] * inv;
            s1.x = ot1[0] * inv; s1.y = ot1[1] * inv;
            s1.z = ot1[2] * inv; s1.w = ot1[3] * inv;
            float* op = out + (size_t)(b * L_ + q) * D_ + h * 32;
            *(float4*)(op + fq * 4) = s0;
            *(float4*)(op + 16 + fq * 4) = s1;
        }
    }
}

// ---------------------------------------------------------------------------
// Fused residual+LN: wave per row, shuffle-only, 4 rows/block (attn path).
// ---------------------------------------------------------------------------
__global__ __launch_bounds__(256) void ln_kernel(
    const float* __restrict__ res, const float* __restrict__ y,
    const float* __restrict__ g, const float* __restrict__ bb,
    float* __restrict__ xout, ushort* __restrict__ xbout)
{
    int row = blockIdx.x * 4 + (threadIdx.x >> 6);
    int lane = threadIdx.x & 63;
    size_t off = (size_t)row * D_ + lane * 4;
    float4 rv = *(const float4*)(res + off);
    float4 yv = *(const float4*)(y + off);
    float4 v;
    v.x = rv.x + yv.x; v.y = rv.y + yv.y; v.z = rv.z + yv.z; v.w = rv.w + yv.w;

    float s = v.x + v.y + v.z + v.w;
#pragma unroll
    for (int o = 1; o < 64; o <<= 1) s += __shfl_xor(s, o);
    float mean = s * (1.0f / 256.0f);

    float4 d;
    d.x = v.x - mean; d.y = v.y - mean; d.z = v.z - mean; d.w = v.w - mean;
    float sq = d.x * d.x + d.y * d.y + d.z * d.z + d.w * d.w;
#pragma unroll
    for (int o = 1; o < 64; o <<= 1) sq += __shfl_xor(sq, o);
    float rstd = rsqrtf(sq * (1.0f / 256.0f) + 1e-5f);

    float4 gv = *(const float4*)(g + lane * 4);
    float4 bv = *(const float4*)(bb + lane * 4);
    float4 o;
    o.x = d.x * rstd * gv.x + bv.x;
    o.y = d.y * rstd * gv.y + bv.y;
    o.z = d.z * rstd * gv.z + bv.z;
    o.w = d.w * rstd * gv.w + bv.w;
    *(float4*)(xout + off) = o;
    ushort4 hb;
    hb.x = f2bu(o.x); hb.y = f2bu(o.y); hb.z = f2bu(o.z); hb.w = f2bu(o.w);
    *(ushort4*)(xbout + off) = hb;
}

__global__ __launch_bounds__(256) void head1_kernel(
    const float* __restrict__ X, const float* __restrict__ w1,
    const float* __restrict__ b1, const float* __restrict__ bng,
    const float* __restrict__ bnb, const float* __restrict__ w2,
    const float* __restrict__ b2, float* __restrict__ SCp)
{
    int row = blockIdx.x * 8 + (threadIdx.x >> 5);
    int j = threadIdx.x & 31;
    const float* x = X + (size_t)row * D_;
    float acc = 0.f;
    for (int d = 0; d < D_; ++d) acc += x[d] * w1[d * PH_ + j];
    acc += b1[j];
    float hb = acc * (bng[j] * rsqrtf(1.0f + 1e-5f)) + bnb[j];
    const float c = 0.7978845608028654f;
    float t = tanhf(c * (hb + 0.044715f * hb * hb * hb));
    float gl = 0.5f * hb * (1.0f + t);
    float sp = gl * w2[j];
#pragma unroll
    for (int o = 16; o > 0; o >>= 1) sp += __shfl_xor(sp, o);
    if (j == 0) SCp[row] = sp + b2[0];
}

// ---------------------------------------------------------------------------
// head2: block (colgroup, b); 64 cols x 4 L-partitions per block.
// ---------------------------------------------------------------------------
__global__ __launch_bounds__(256) void head2_kernel(
    const float* __restrict__ SCp, const float* __restrict__ X,
    float* __restrict__ outp)
{
    int cg = blockIdx.x, b = blockIdx.y;
    int tid = threadIdx.x;
    __shared__ float wbuf[L_];
    __shared__ float r1[4], r2[4];
    __shared__ float part[4][64];
    const float* s = SCp + (size_t)b * L_;

    float m = -1e30f;
    for (int j = tid; j < L_; j += 256) m = fmaxf(m, s[j]);
#pragma unroll
    for (int o = 1; o < 64; o <<= 1) m = fmaxf(m, __shfl_xor(m, o));
    if ((tid & 63) == 0) r1[tid >> 6] = m;
    __syncthreads();
    m = fmaxf(fmaxf(r1[0], r1[1]), fmaxf(r1[2], r1[3]));

    float sum = 0.f;
    for (int j = tid; j < L_; j += 256) {
        float e = __expf(s[j] - m);
        wbuf[j] = e;
        sum += e;
    }
#pragma unroll
    for (int o = 1; o < 64; o <<= 1) sum += __shfl_xor(sum, o);
    if ((tid & 63) == 0) r2[tid >> 6] = sum;
    __syncthreads();
    float inv = 1.0f / (r2[0] + r2[1] + r2[2] + r2[3]);

    int c = tid & 63, pt = tid >> 6;
    int col = cg * 64 + c;
    float acc = 0.f;
    const float* xb = X + (size_t)b * L_ * D_ + col;
    for (int l = pt; l < L_; l += 4) acc += wbuf[l] * xb[(size_t)l * D_];
    part[pt][c] = acc;
    __syncthreads();
    if (pt == 0)
        outp[b * D_ + col] = (part[0][c] + part[1][c] + part[2][c] + part[3][c]) * inv;
}

// ---------------------------------------------------------------------------
extern "C" void kernel_launch(void* const* d_in, const int* in_sizes, int n_in,
                              void* d_out, int out_size, void* d_ws, size_t ws_size,
                              hipStream_t stream)
{
    const float* gene   = (const float*)d_in[0];
    const float* coords = (const float*)d_in[1];
    const float* w_in   = (const float*)d_in[2];
    const float* b_in   = (const float*)d_in[3];
    const float* w_cls  = (const float*)d_in[4];
    const float* b_cls  = (const float*)d_in[5];
    const float* qkv_w  = (const float*)d_in[6];
    const float* qkv_b  = (const float*)d_in[7];
    const float* ln1_g  = (const float*)d_in[8];
    const float* ln1_b  = (const float*)d_in[9];
    const float* ffn_w1 = (const float*)d_in[10];
    const float* ffn_b1 = (const float*)d_in[11];
    const float* ffn_w2 = (const float*)d_in[12];
    const float* ffn_b2 = (const float*)d_in[13];
    const float* ln2_g  = (const float*)d_in[14];
    const float* ln2_b  = (const float*)d_in[15];
    const float* th1_w  = (const float*)d_in[16];
    const float* th1_b  = (const float*)d_in[17];
    const float* bn_g   = (const float*)d_in[18];
    const float* bn_b   = (const float*)d_in[19];
    const float* th2_w  = (const float*)d_in[20];
    const float* th2_b  = (const float*)d_in[21];
    float* out = (float*)d_out;

    const int ROWS = B_ * L_;   // 29248
    char* p = (char*)d_ws;
    float*  X    = (float*)p;  p += (size_t)MPAD * 256 * 4;
    float*  AO   = (float*)p;  p += (size_t)MPAD * 256 * 4;
    ushort* Xb   = (ushort*)p; p += (size_t)MPAD * 256 * 2;
    ushort* SH   = (ushort*)p; p += (size_t)MPAD * 1024 * 2;
    ushort* qkvT = (ushort*)p; p += (size_t)NL_ * 768 * 256 * 2;
    ushort* w1T  = (ushort*)p; p += (size_t)NL_ * 1024 * 256 * 2;
    ushort* w2T  = (ushort*)p; p += (size_t)NL_ * 256 * 1024 * 2;
    float*  SCp  = (float*)p;  p += (size_t)ROWS * 4;

    wcast_kernel<<<dim3(768 / 32, 256 / 32, NL_), dim3(32, 8), 0, stream>>>(qkv_w, qkvT, 256, 768);
    wcast_kernel<<<dim3(1024 / 32, 256 / 32, NL_), dim3(32, 8), 0, stream>>>(ffn_w1, w1T, 256, 1024);
    wcast_kernel<<<dim3(256 / 32, 1024 / 32, NL_), dim3(32, 8), 0, stream>>>(ffn_w2, w2T, 1024, 256);

    sgemm_kernel<<<dim3(D_ / 64, (B_ * NT_) / 64), 256, 0, stream>>>(
        gene, w_in, b_in, X, Xb, B_ * NT_, D_, TOK_);
    cls_kernel<<<B_, 256, 0, stream>>>(coords, w_cls, b_cls, X, Xb);

    for (int l = 0; l < NL_; ++l) {
        mfma_gemm<<<dim3(768 / 128, MPAD / 128), 256, 0, stream>>>(
            Xb, qkvT + (size_t)l * 768 * 256, qkv_b + l * 768, SH, 768, 256, 0, 1);
        attn_kernel<<<dim3(H_, B_), 512, 0, stream>>>(SH, AO);
        ln_kernel<<<ROWS / 4, 256, 0, stream>>>(X, AO, ln1_g + l * D_, ln1_b + l * D_, X, Xb);
        mfma_gemm<<<dim3(1024 / 128, MPAD / 128), 256, 0, stream>>>(
            Xb, w1T + (size_t)l * 1024 * 256, ffn_b1 + l * 1024, SH, 1024, 256, 1, 1);
        ffn2_ln<<<MPAD / 64, 256, 0, stream>>>(
            SH, w2T + (size_t)l * 256 * 1024, ffn_b2 + l * D_,
            ln2_g + l * D_, ln2_b + l * D_, X, Xb);
    }

    head1_kernel<<<ROWS / 8, 256, 0, stream>>>(
        X, th1_w, th1_b, bn_g, bn_b, th2_w, th2_b, SCp);
    head2_kernel<<<dim3(4, B_), 256, 0, stream>>>(SCp, X, out);
}

// Round 10
// 1046.794 us; speedup vs baseline: 1.1260x; 1.1260x over previous
//
#include <hip/hip_runtime.h>
#include <math.h>

#define B_   64
#define TOK_ 64
#define NT_  456
#define L_   457
#define D_   256
#define H_   8
#define HD_  32
#define FF_  1024
#define NL_  4
#define PH_  32
#define MPAD 29312   // 229 * 128 (rows padded for 128-row GEMM tiles)

typedef unsigned int uint;
typedef unsigned short ushort;
typedef __bf16 v8bf __attribute__((ext_vector_type(8)));
typedef __bf16 v4bf __attribute__((ext_vector_type(4)));
typedef short v4s __attribute__((ext_vector_type(4)));
typedef float v4f __attribute__((ext_vector_type(4)));

__device__ __forceinline__ float bu2f(ushort x) {
    return __uint_as_float(((uint)x) << 16);
}
__device__ __forceinline__ ushort f2bu(float f) {
    union { float f; uint u; } x; x.f = f;
    uint r = (x.u + 0x7fffu + ((x.u >> 16) & 1u)) >> 16;
    return (ushort)r;
}
__device__ __forceinline__ uint pack_bf2(float a, float b) {
#if defined(__HIP_DEVICE_COMPILE__) && __has_builtin(__builtin_amdgcn_cvt_pk_bf16_f32)
    typedef __bf16 bf2v __attribute__((ext_vector_type(2)));
    bf2v v = __builtin_amdgcn_cvt_pk_bf16_f32(a, b);
    return *(uint*)&v;
#else
    return (uint)f2bu(a) | ((uint)f2bu(b) << 16);
#endif
}

// K=16 bf16 MFMA (PV with register-resident P). Guarded for the host pass.
__device__ __forceinline__ v4f mfma16(uint2 a, uint2 b, v4f c) {
#if defined(__HIP_DEVICE_COMPILE__)
#if __has_builtin(__builtin_amdgcn_mfma_f32_16x16x16_bf16)
    return __builtin_amdgcn_mfma_f32_16x16x16_bf16(*(v4bf*)&a, *(v4bf*)&b, c, 0, 0, 0);
#else
    return __builtin_amdgcn_mfma_f32_16x16x16bf16_1k(*(v4s*)&a, *(v4s*)&b, c, 0, 0, 0);
#endif
#else
    (void)a; (void)b;
    return c;
#endif
}

// async global->LDS 16B copy; lds base wave-uniform, data at base + lane*16.
__device__ __forceinline__ void gload16(const void* g, void* l) {
    __builtin_amdgcn_global_load_lds(
        (const __attribute__((address_space(1))) void*)(unsigned long long)(uintptr_t)g,
        (__attribute__((address_space(3))) void*)(uint)(uintptr_t)l,
        16, 0, 0);
}

// ---------------------------------------------------------------------------
// bf16 MFMA GEMM (m97 structure): C[M,N] = A[M,K]·W^T[N,K] + bias.
// ---------------------------------------------------------------------------
__global__ __launch_bounds__(256) void mfma_gemm(
    const ushort* __restrict__ A, const ushort* __restrict__ WT,
    const float* __restrict__ bias, void* __restrict__ Cout,
    int N, int K, int relu, int obf16)
{
    __shared__ ushort As[128 * 32];
    __shared__ ushort Bs[128 * 32];
    int tid = threadIdx.x;
    int wave = tid >> 6, lane = tid & 63;
    int colblk = blockIdx.x * 128;
    int rowblk = blockIdx.y * 128;
    int wm = wave >> 1, wn = wave & 1;

    v4f acc[4][4];
#pragma unroll
    for (int i = 0; i < 4; ++i)
#pragma unroll
        for (int j = 0; j < 4; ++j) acc[i][j] = (v4f)0.0f;

    int fr = lane & 15, fq = lane >> 4;
    int scol = fq ^ (lane & 3) ^ ((lane >> 2) & 1);

    int c0 = wave * 64 + lane;
    int r0 = c0 >> 2, k0g = (c0 & 3) ^ (r0 & 3) ^ ((r0 >> 2) & 1);
    int c1 = 256 + c0;
    int r1 = c1 >> 2, k1g = (c1 & 3) ^ (r1 & 3) ^ ((r1 >> 2) & 1);

    const ushort* Ag0 = A + (size_t)(rowblk + r0) * K + k0g * 8;
    const ushort* Ag1 = A + (size_t)(rowblk + r1) * K + k1g * 8;
    const ushort* Bg0 = WT + (size_t)(colblk + r0) * K + k0g * 8;
    const ushort* Bg1 = WT + (size_t)(colblk + r1) * K + k1g * 8;
    ushort* lA0 = As + (size_t)(wave * 64) * 8;
    ushort* lA1 = As + (size_t)(256 + wave * 64) * 8;
    ushort* lB0 = Bs + (size_t)(wave * 64) * 8;
    ushort* lB1 = Bs + (size_t)(256 + wave * 64) * 8;

    for (int kt = 0; kt < K; kt += 32) {
        gload16(Ag0 + kt, lA0);
        gload16(Ag1 + kt, lA1);
        gload16(Bg0 + kt, lB0);
        gload16(Bg1 + kt, lB1);
        __syncthreads();

        v8bf a[4], b[4];
#pragma unroll
        for (int mi = 0; mi < 4; ++mi)
            a[mi] = *(const v8bf*)(As + (size_t)(wm * 64 + mi * 16 + fr) * 32 + scol * 8);
#pragma unroll
        for (int ni = 0; ni < 4; ++ni)
            b[ni] = *(const v8bf*)(Bs + (size_t)(wn * 64 + ni * 16 + fr) * 32 + scol * 8);
#pragma unroll
        for (int mi = 0; mi < 4; ++mi)
#pragma unroll
            for (int ni = 0; ni < 4; ++ni)
                acc[mi][ni] = __builtin_amdgcn_mfma_f32_16x16x32_bf16(
                    a[mi], b[ni], acc[mi][ni], 0, 0, 0);
        __syncthreads();
    }

#pragma unroll
    for (int ni = 0; ni < 4; ++ni) {
        int col = colblk + wn * 64 + ni * 16 + fr;
        float bv = bias[col];
#pragma unroll
        for (int mi = 0; mi < 4; ++mi) {
            int row = rowblk + wm * 64 + mi * 16 + fq * 4;
#pragma unroll
            for (int r = 0; r < 4; ++r) {
                float v = acc[mi][ni][r] + bv;
                if (relu) v = fmaxf(v, 0.f);
                if (obf16)
                    ((ushort*)Cout)[(size_t)(row + r) * N + col] = f2bu(v);
                else
                    ((float*)Cout)[(size_t)(row + r) * N + col] = v;
            }
        }
    }
}

// ---------------------------------------------------------------------------
__global__ __launch_bounds__(256) void wcast_kernel(
    const float* __restrict__ W, ushort* __restrict__ WT, int K, int N)
{
    __shared__ float t[32][33];
    const float* Wl = W + (size_t)blockIdx.z * K * N;
    ushort* WTl = WT + (size_t)blockIdx.z * K * N;
    int n0 = blockIdx.x * 32, k0 = blockIdx.y * 32;
    int tx = threadIdx.x, ty = threadIdx.y;
#pragma unroll
    for (int r = 0; r < 32; r += 8)
        t[ty + r][tx] = Wl[(size_t)(k0 + ty + r) * N + n0 + tx];
    __syncthreads();
#pragma unroll
    for (int r = 0; r < 32; r += 8)
        WTl[(size_t)(n0 + ty + r) * K + k0 + tx] = f2bu(t[tx][ty + r]);
}

// ---------------------------------------------------------------------------
// fp32 SGEMM for the embed GEMM only; row-remap; writes fp32 X and bf16 Xb.
// ---------------------------------------------------------------------------
__global__ __launch_bounds__(256) void sgemm_kernel(
    const float* __restrict__ A, const float* __restrict__ W,
    const float* __restrict__ bias, float* __restrict__ C,
    ushort* __restrict__ Cb, int M, int N, int K)
{
    __shared__ float As_[16][64];
    __shared__ float Bs_[16][64];
    int tid = threadIdx.x;
    int rowblk = blockIdx.y * 64;
    int colblk = blockIdx.x * 64;
    int a_row = tid & 63, a_q = tid >> 6;
    int b_kr = tid >> 4, b_cg = tid & 15;
    int rm = tid >> 4, cn = tid & 15;
    float acc[4][4] = {};
    const float* Aptr = A + (size_t)(rowblk + a_row) * K;
    for (int kt = 0; kt < K; kt += 16) {
        float4 av = *(const float4*)(Aptr + kt + a_q * 4);
        float4 bv = *(const float4*)(W + (size_t)(kt + b_kr) * N + colblk + b_cg * 4);
        As_[a_q * 4 + 0][a_row] = av.x;
        As_[a_q * 4 + 1][a_row] = av.y;
        As_[a_q * 4 + 2][a_row] = av.z;
        As_[a_q * 4 + 3][a_row] = av.w;
        *(float4*)&Bs_[b_kr][b_cg * 4] = bv;
        __syncthreads();
#pragma unroll
        for (int kk = 0; kk < 16; ++kk) {
            float4 a4 = *(const float4*)&As_[kk][rm * 4];
            float4 b4 = *(const float4*)&Bs_[kk][cn * 4];
            float ar[4] = {a4.x, a4.y, a4.z, a4.w};
            float br[4] = {b4.x, b4.y, b4.z, b4.w};
#pragma unroll
            for (int i = 0; i < 4; ++i)
#pragma unroll
                for (int j = 0; j < 4; ++j) acc[i][j] += ar[i] * br[j];
        }
        __syncthreads();
    }
    float4 bv = *(const float4*)(bias + colblk + cn * 4);
    float bb[4] = {bv.x, bv.y, bv.z, bv.w};
#pragma unroll
    for (int i = 0; i < 4; ++i) {
        int grow = rowblk + rm * 4 + i;
        size_t orow = (size_t)(grow + grow / NT_ + 1);
        float4 r;
        r.x = acc[i][0] + bb[0]; r.y = acc[i][1] + bb[1];
        r.z = acc[i][2] + bb[2]; r.w = acc[i][3] + bb[3];
        *(float4*)(C + orow * N + colblk + cn * 4) = r;
        ushort4 h;
        h.x = f2bu(r.x); h.y = f2bu(r.y); h.z = f2bu(r.z); h.w = f2bu(r.w);
        *(ushort4*)(Cb + orow * N + colblk + cn * 4) = h;
    }
}

__global__ __launch_bounds__(256) void cls_kernel(
    const float* __restrict__ coords, const float* __restrict__ w_cls,
    const float* __restrict__ b_cls, float* __restrict__ X,
    ushort* __restrict__ Xb)
{
    int b = blockIdx.x;
    int t = threadIdx.x;
    float c0 = coords[b * 3 + 0], c1 = coords[b * 3 + 1], c2 = coords[b * 3 + 2];
    float v = c0 * w_cls[t] + c1 * w_cls[D_ + t] + c2 * w_cls[2 * D_ + t] + b_cls[t];
    X[(size_t)b * L_ * D_ + t] = v;
    Xb[(size_t)b * L_ * D_ + t] = f2bu(v);
}

// ---------------------------------------------------------------------------
// MFMA attention v5: one block per (b,h), 512 threads (8 waves).
// K/V^T staged once (68.4 KB, 2 blocks/CU). QK (A=K,B=Q) leaves lane (fr,fq)
// with P(q=fr, k=4fq+r) == B-operand layout of a K=16 MFMA -> PV straight
// from registers (mfma16, transposed output). Output written bf16.
// ---------------------------------------------------------------------------
__global__ __launch_bounds__(512) void attn_kernel(
    const ushort* __restrict__ qkv, ushort* __restrict__ out)
{
    __shared__ __align__(16) ushort Ks[464][40];    // 36.3 KB
    __shared__ __align__(16) ushort Vt[32][488];    // 30.5 KB

    int h = blockIdx.x, b = blockIdx.y;
    int tid = threadIdx.x;
    int wave = tid >> 6, lane = tid & 63;
    int fr = lane & 15, fq = lane >> 4;
    const float scale = 0.17677669529663687f;
    float slope = (h < 4) ? 1.0f : 0.5f;
    const ushort* base = qkv + (size_t)b * L_ * 768;

    for (int j = tid >> 2; j < 464; j += 128) {
        int c8 = (tid & 3) * 8;
        uint4 u = make_uint4(0u, 0u, 0u, 0u);
        if (j < L_) u = *(const uint4*)(base + (size_t)j * 768 + 256 + h * 32 + c8);
        *(uint4*)&Ks[j][c8] = u;
    }
    for (int m = wave; m < 32; m += 8) {
        int dg = (m >> 3) * 8, jb = m & 7;
        int j = jb * 64 + lane;
        uint4 u = make_uint4(0u, 0u, 0u, 0u);
        if (j < L_) u = *(const uint4*)(base + (size_t)j * 768 + 512 + h * 32 + dg);
        if (j < 488) {
            const ushort* pu = (const ushort*)&u;
#pragma unroll
            for (int e = 0; e < 8; ++e) Vt[dg + e][j] = pu[e];
        }
    }
    __syncthreads();

    for (int t = wave; t < 29; t += 8) {
        int q0 = t * 16;
        uint4 qu = *(const uint4*)(base + (size_t)(q0 + fr) * 768 + h * 32 + fq * 8);
        v8bf qfrag = *(v8bf*)&qu;
        float fmyq = (float)(q0 + fr);
        float psum = 0.f;
        v4f ot0 = (v4f)0.0f, ot1 = (v4f)0.0f;

        for (int kc = 0; kc < 14; ++kc) {
            int kb = kc * 32;
            v8bf kf0 = *(const v8bf*)&Ks[kb + fr][fq * 8];
            v8bf kf1 = *(const v8bf*)&Ks[kb + 16 + fr][fq * 8];
            v4f d0 = (v4f)0.0f, d1 = (v4f)0.0f;
            d0 = __builtin_amdgcn_mfma_f32_16x16x32_bf16(kf0, qfrag, d0, 0, 0, 0);
            d1 = __builtin_amdgcn_mfma_f32_16x16x32_bf16(kf1, qfrag, d1, 0, 0, 0);
            float ke = (float)(kb + 4 * fq);
            float pe[4], po[4];
#pragma unroll
            for (int r = 0; r < 4; ++r) {
                pe[r] = __expf(d0[r] * scale - slope * fabsf(fmyq - (ke + (float)r)));
                po[r] = __expf(d1[r] * scale - slope * fabsf(fmyq - (ke + 16.0f + (float)r)));
                psum += pe[r] + po[r];
            }
            uint2 ue, uo;
            ue.x = pack_bf2(pe[0], pe[1]); ue.y = pack_bf2(pe[2], pe[3]);
            uo.x = pack_bf2(po[0], po[1]); uo.y = pack_bf2(po[2], po[3]);
            uint2 va0 = *(const uint2*)&Vt[fr][kb + fq * 4];
            uint2 va1 = *(const uint2*)&Vt[16 + fr][kb + fq * 4];
            uint2 vb0 = *(const uint2*)&Vt[fr][kb + 16 + fq * 4];
            uint2 vb1 = *(const uint2*)&Vt[16 + fr][kb + 16 + fq * 4];
            ot0 = mfma16(va0, ue, ot0);
            ot1 = mfma16(va1, ue, ot1);
            ot0 = mfma16(vb0, uo, ot0);
            ot1 = mfma16(vb1, uo, ot1);
        }
        // tail: k 448..463
        {
            v8bf kf0 = *(const v8bf*)&Ks[448 + fr][fq * 8];
            v4f d0 = (v4f)0.0f;
            d0 = __builtin_amdgcn_mfma_f32_16x16x32_bf16(kf0, qfrag, d0, 0, 0, 0);
            float pe[4];
#pragma unroll
            for (int r = 0; r < 4; ++r) {
                int k = 448 + 4 * fq + r;
                pe[r] = (k < L_)
                    ? __expf(d0[r] * scale - slope * fabsf(fmyq - (float)k)) : 0.f;
                psum += pe[r];
            }
            uint2 ue;
            ue.x = pack_bf2(pe[0], pe[1]); ue.y = pack_bf2(pe[2], pe[3]);
            uint2 va0 = *(const uint2*)&Vt[fr][448 + fq * 4];
            uint2 va1 = *(const uint2*)&Vt[16 + fr][448 + fq * 4];
            ot0 = mfma16(va0, ue, ot0);
            ot1 = mfma16(va1, ue, ot1);
        }

        psum += __shfl_xor(psum, 16);
        psum += __shfl_xor(psum, 32);
        int q = q0 + fr;
        if (q < L_) {
            float inv = 1.0f / psum;
            uint2 w0, w1;
            w0.x = pack_bf2(ot0[0] * inv, ot0[1] * inv);
            w0.y = pack_bf2(ot0[2] * inv, ot0[3] * inv);
            w1.x = pack_bf2(ot1[0] * inv, ot1[1] * inv);
            w1.y = pack_bf2(ot1[2] * inv, ot1[3] * inv);
            ushort* op = out + (size_t)(b * L_ + q) * D_ + h * 32;
            *(uint2*)(op + fq * 4) = w0;
            *(uint2*)(op + 16 + fq * 4) = w1;
        }
    }
}

// ---------------------------------------------------------------------------
// Fused residual+LN: wave per row, shuffle-only, 4 rows/block.
// y (branch output) is bf16; residual X fp32.
// ---------------------------------------------------------------------------
__global__ __launch_bounds__(256) void ln_kernel(
    const float* __restrict__ res, const ushort* __restrict__ y,
    const float* __restrict__ g, const float* __restrict__ bb,
    float* __restrict__ xout, ushort* __restrict__ xbout)
{
    int row = blockIdx.x * 4 + (threadIdx.x >> 6);
    int lane = threadIdx.x & 63;
    size_t off = (size_t)row * D_ + lane * 4;
    float4 rv = *(const float4*)(res + off);
    ushort4 yv4 = *(const ushort4*)(y + off);
    float4 v;
    v.x = rv.x + bu2f(yv4.x);
    v.y = rv.y + bu2f(yv4.y);
    v.z = rv.z + bu2f(yv4.z);
    v.w = rv.w + bu2f(yv4.w);

    float s = v.x + v.y + v.z + v.w;
#pragma unroll
    for (int o = 1; o < 64; o <<= 1) s += __shfl_xor(s, o);
    float mean = s * (1.0f / 256.0f);

    float4 d;
    d.x = v.x - mean; d.y = v.y - mean; d.z = v.z - mean; d.w = v.w - mean;
    float sq = d.x * d.x + d.y * d.y + d.z * d.z + d.w * d.w;
#pragma unroll
    for (int o = 1; o < 64; o <<= 1) sq += __shfl_xor(sq, o);
    float rstd = rsqrtf(sq * (1.0f / 256.0f) + 1e-5f);

    float4 gv = *(const float4*)(g + lane * 4);
    float4 bv = *(const float4*)(bb + lane * 4);
    float4 o;
    o.x = d.x * rstd * gv.x + bv.x;
    o.y = d.y * rstd * gv.y + bv.y;
    o.z = d.z * rstd * gv.z + bv.z;
    o.w = d.w * rstd * gv.w + bv.w;
    *(float4*)(xout + off) = o;
    ushort4 hb;
    hb.x = f2bu(o.x); hb.y = f2bu(o.y); hb.z = f2bu(o.z); hb.w = f2bu(o.w);
    *(ushort4*)(xbout + off) = hb;
}

__global__ __launch_bounds__(256) void head1_kernel(
    const float* __restrict__ X, const float* __restrict__ w1,
    const float* __restrict__ b1, const float* __restrict__ bng,
    const float* __restrict__ bnb, const float* __restrict__ w2,
    const float* __restrict__ b2, float* __restrict__ SCp)
{
    int row = blockIdx.x * 8 + (threadIdx.x >> 5);
    int j = threadIdx.x & 31;
    const float* x = X + (size_t)row * D_;
    float acc = 0.f;
    for (int d = 0; d < D_; ++d) acc += x[d] * w1[d * PH_ + j];
    acc += b1[j];
    float hb = acc * (bng[j] * rsqrtf(1.0f + 1e-5f)) + bnb[j];
    const float c = 0.7978845608028654f;
    float t = tanhf(c * (hb + 0.044715f * hb * hb * hb));
    float gl = 0.5f * hb * (1.0f + t);
    float sp = gl * w2[j];
#pragma unroll
    for (int o = 16; o > 0; o >>= 1) sp += __shfl_xor(sp, o);
    if (j == 0) SCp[row] = sp + b2[0];
}

// ---------------------------------------------------------------------------
// head2: block (colgroup, b); 64 cols x 4 L-partitions per block.
// ---------------------------------------------------------------------------
__global__ __launch_bounds__(256) void head2_kernel(
    const float* __restrict__ SCp, const float* __restrict__ X,
    float* __restrict__ outp)
{
    int cg = blockIdx.x, b = blockIdx.y;
    int tid = threadIdx.x;
    __shared__ float wbuf[L_];
    __shared__ float r1[4], r2[4];
    __shared__ float part[4][64];
    const float* s = SCp + (size_t)b * L_;

    float m = -1e30f;
    for (int j = tid; j < L_; j += 256) m = fmaxf(m, s[j]);
#pragma unroll
    for (int o = 1; o < 64; o <<= 1) m = fmaxf(m, __shfl_xor(m, o));
    if ((tid & 63) == 0) r1[tid >> 6] = m;
    __syncthreads();
    m = fmaxf(fmaxf(r1[0], r1[1]), fmaxf(r1[2], r1[3]));

    float sum = 0.f;
    for (int j = tid; j < L_; j += 256) {
        float e = __expf(s[j] - m);
        wbuf[j] = e;
        sum += e;
    }
#pragma unroll
    for (int o = 1; o < 64; o <<= 1) sum += __shfl_xor(sum, o);
    if ((tid & 63) == 0) r2[tid >> 6] = sum;
    __syncthreads();
    float inv = 1.0f / (r2[0] + r2[1] + r2[2] + r2[3]);

    int c = tid & 63, pt = tid >> 6;
    int col = cg * 64 + c;
    float acc = 0.f;
    const float* xb = X + (size_t)b * L_ * D_ + col;
    for (int l = pt; l < L_; l += 4) acc += wbuf[l] * xb[(size_t)l * D_];
    part[pt][c] = acc;
    __syncthreads();
    if (pt == 0)
        outp[b * D_ + col] = (part[0][c] + part[1][c] + part[2][c] + part[3][c]) * inv;
}

// ---------------------------------------------------------------------------
extern "C" void kernel_launch(void* const* d_in, const int* in_sizes, int n_in,
                              void* d_out, int out_size, void* d_ws, size_t ws_size,
                              hipStream_t stream)
{
    const float* gene   = (const float*)d_in[0];
    const float* coords = (const float*)d_in[1];
    const float* w_in   = (const float*)d_in[2];
    const float* b_in   = (const float*)d_in[3];
    const float* w_cls  = (const float*)d_in[4];
    const float* b_cls  = (const float*)d_in[5];
    const float* qkv_w  = (const float*)d_in[6];
    const float* qkv_b  = (const float*)d_in[7];
    const float* ln1_g  = (const float*)d_in[8];
    const float* ln1_b  = (const float*)d_in[9];
    const float* ffn_w1 = (const float*)d_in[10];
    const float* ffn_b1 = (const float*)d_in[11];
    const float* ffn_w2 = (const float*)d_in[12];
    const float* ffn_b2 = (const float*)d_in[13];
    const float* ln2_g  = (const float*)d_in[14];
    const float* ln2_b  = (const float*)d_in[15];
    const float* th1_w  = (const float*)d_in[16];
    const float* th1_b  = (const float*)d_in[17];
    const float* bn_g   = (const float*)d_in[18];
    const float* bn_b   = (const float*)d_in[19];
    const float* th2_w  = (const float*)d_in[20];
    const float* th2_b  = (const float*)d_in[21];
    float* out = (float*)d_out;

    const int ROWS = B_ * L_;   // 29248
    char* p = (char*)d_ws;
    float*  X    = (float*)p;  p += (size_t)MPAD * 256 * 4;
    ushort* AOb  = (ushort*)p; p += (size_t)MPAD * 256 * 2;   // bf16 branch output
    ushort* Xb   = (ushort*)p; p += (size_t)MPAD * 256 * 2;
    ushort* SH   = (ushort*)p; p += (size_t)MPAD * 1024 * 2;
    ushort* qkvT = (ushort*)p; p += (size_t)NL_ * 768 * 256 * 2;
    ushort* w1T  = (ushort*)p; p += (size_t)NL_ * 1024 * 256 * 2;
    ushort* w2T  = (ushort*)p; p += (size_t)NL_ * 256 * 1024 * 2;
    float*  SCp  = (float*)p;  p += (size_t)ROWS * 4;

    wcast_kernel<<<dim3(768 / 32, 256 / 32, NL_), dim3(32, 8), 0, stream>>>(qkv_w, qkvT, 256, 768);
    wcast_kernel<<<dim3(1024 / 32, 256 / 32, NL_), dim3(32, 8), 0, stream>>>(ffn_w1, w1T, 256, 1024);
    wcast_kernel<<<dim3(256 / 32, 1024 / 32, NL_), dim3(32, 8), 0, stream>>>(ffn_w2, w2T, 1024, 256);

    sgemm_kernel<<<dim3(D_ / 64, (B_ * NT_) / 64), 256, 0, stream>>>(
        gene, w_in, b_in, X, Xb, B_ * NT_, D_, TOK_);
    cls_kernel<<<B_, 256, 0, stream>>>(coords, w_cls, b_cls, X, Xb);

    for (int l = 0; l < NL_; ++l) {
        mfma_gemm<<<dim3(768 / 128, MPAD / 128), 256, 0, stream>>>(
            Xb, qkvT + (size_t)l * 768 * 256, qkv_b + l * 768, SH, 768, 256, 0, 1);
        attn_kernel<<<dim3(H_, B_), 512, 0, stream>>>(SH, AOb);
        ln_kernel<<<ROWS / 4, 256, 0, stream>>>(X, AOb, ln1_g + l * D_, ln1_b + l * D_, X, Xb);
        mfma_gemm<<<dim3(1024 / 128, MPAD / 128), 256, 0, stream>>>(
            Xb, w1T + (size_t)l * 1024 * 256, ffn_b1 + l * 1024, SH, 1024, 256, 1, 1);
        mfma_gemm<<<dim3(256 / 128, MPAD / 128), 256, 0, stream>>>(
            SH, w2T + (size_t)l * 256 * 1024, ffn_b2 + l * D_, AOb, 256, 1024, 0, 1);
        ln_kernel<<<ROWS / 4, 256, 0, stream>>>(X, AOb, ln2_g + l * D_, ln2_b + l * D_, X, Xb);
    }

    head1_kernel<<<ROWS / 8, 256, 0, stream>>>(
        X, th1_w, th1_b, bn_g, bn_b, th2_w, th2_b, SCp);
    head2_kernel<<<dim3(4, B_), 256, 0, stream>>>(SCp, X, out);
}

// Round 12
// 990.124 us; speedup vs baseline: 1.1904x; 1.0572x over previous
//
#include <hip/hip_runtime.h>
#include <math.h>

#define B_   64
#define TOK_ 64
#define NT_  456
#define L_   457
#define D_   256
#define H_   8
#define HD_  32
#define FF_  1024
#define NL_  4
#define PH_  32
#define MPAD 29312   // 229 * 128 (rows padded for 128-row GEMM tiles)

typedef unsigned int uint;
typedef unsigned short ushort;
typedef __bf16 v8bf __attribute__((ext_vector_type(8)));
typedef __bf16 v4bf __attribute__((ext_vector_type(4)));
typedef short v4s __attribute__((ext_vector_type(4)));
typedef float v4f __attribute__((ext_vector_type(4)));

__device__ __forceinline__ float bu2f(ushort x) {
    return __uint_as_float(((uint)x) << 16);
}
__device__ __forceinline__ ushort f2bu(float f) {
    union { float f; uint u; } x; x.f = f;
    uint r = (x.u + 0x7fffu + ((x.u >> 16) & 1u)) >> 16;
    return (ushort)r;
}
__device__ __forceinline__ uint pack_bf2(float a, float b) {
#if defined(__HIP_DEVICE_COMPILE__) && __has_builtin(__builtin_amdgcn_cvt_pk_bf16_f32)
    typedef __bf16 bf2v __attribute__((ext_vector_type(2)));
    bf2v v = __builtin_amdgcn_cvt_pk_bf16_f32(a, b);
    return *(uint*)&v;
#else
    return (uint)f2bu(a) | ((uint)f2bu(b) << 16);
#endif
}

// K=16 bf16 MFMA (PV with register-resident P). Guarded for the host pass.
__device__ __forceinline__ v4f mfma16(uint2 a, uint2 b, v4f c) {
#if defined(__HIP_DEVICE_COMPILE__)
#if __has_builtin(__builtin_amdgcn_mfma_f32_16x16x16_bf16)
    return __builtin_amdgcn_mfma_f32_16x16x16_bf16(*(v4bf*)&a, *(v4bf*)&b, c, 0, 0, 0);
#else
    return __builtin_amdgcn_mfma_f32_16x16x16bf16_1k(*(v4s*)&a, *(v4s*)&b, c, 0, 0, 0);
#endif
#else
    (void)a; (void)b;
    return c;
#endif
}

// async global->LDS 16B copy; lds base wave-uniform, data at base + lane*16.
__device__ __forceinline__ void gload16(const void* g, void* l) {
    __builtin_amdgcn_global_load_lds(
        (const __attribute__((address_space(1))) void*)(unsigned long long)(uintptr_t)g,
        (__attribute__((address_space(3))) void*)(uint)(uintptr_t)l,
        16, 0, 0);
}

// ---------------------------------------------------------------------------
// bf16 MFMA GEMM (m97 structure): C[M,N] = A[M,K]·W^T[N,K] + bias.
// ---------------------------------------------------------------------------
__global__ __launch_bounds__(256) void mfma_gemm(
    const ushort* __restrict__ A, const ushort* __restrict__ WT,
    const float* __restrict__ bias, void* __restrict__ Cout,
    int N, int K, int relu, int obf16)
{
    __shared__ ushort As[128 * 32];
    __shared__ ushort Bs[128 * 32];
    int tid = threadIdx.x;
    int wave = tid >> 6, lane = tid & 63;
    int colblk = blockIdx.x * 128;
    int rowblk = blockIdx.y * 128;
    int wm = wave >> 1, wn = wave & 1;

    v4f acc[4][4];
#pragma unroll
    for (int i = 0; i < 4; ++i)
#pragma unroll
        for (int j = 0; j < 4; ++j) acc[i][j] = (v4f)0.0f;

    int fr = lane & 15, fq = lane >> 4;
    int scol = fq ^ (lane & 3) ^ ((lane >> 2) & 1);

    int c0 = wave * 64 + lane;
    int r0 = c0 >> 2, k0g = (c0 & 3) ^ (r0 & 3) ^ ((r0 >> 2) & 1);
    int c1 = 256 + c0;
    int r1 = c1 >> 2, k1g = (c1 & 3) ^ (r1 & 3) ^ ((r1 >> 2) & 1);

    const ushort* Ag0 = A + (size_t)(rowblk + r0) * K + k0g * 8;
    const ushort* Ag1 = A + (size_t)(rowblk + r1) * K + k1g * 8;
    const ushort* Bg0 = WT + (size_t)(colblk + r0) * K + k0g * 8;
    const ushort* Bg1 = WT + (size_t)(colblk + r1) * K + k1g * 8;
    ushort* lA0 = As + (size_t)(wave * 64) * 8;
    ushort* lA1 = As + (size_t)(256 + wave * 64) * 8;
    ushort* lB0 = Bs + (size_t)(wave * 64) * 8;
    ushort* lB1 = Bs + (size_t)(256 + wave * 64) * 8;

    for (int kt = 0; kt < K; kt += 32) {
        gload16(Ag0 + kt, lA0);
        gload16(Ag1 + kt, lA1);
        gload16(Bg0 + kt, lB0);
        gload16(Bg1 + kt, lB1);
        __syncthreads();

        v8bf a[4], b[4];
#pragma unroll
        for (int mi = 0; mi < 4; ++mi)
            a[mi] = *(const v8bf*)(As + (size_t)(wm * 64 + mi * 16 + fr) * 32 + scol * 8);
#pragma unroll
        for (int ni = 0; ni < 4; ++ni)
            b[ni] = *(const v8bf*)(Bs + (size_t)(wn * 64 + ni * 16 + fr) * 32 + scol * 8);
#pragma unroll
        for (int mi = 0; mi < 4; ++mi)
#pragma unroll
            for (int ni = 0; ni < 4; ++ni)
                acc[mi][ni] = __builtin_amdgcn_mfma_f32_16x16x32_bf16(
                    a[mi], b[ni], acc[mi][ni], 0, 0, 0);
        __syncthreads();
    }

#pragma unroll
    for (int ni = 0; ni < 4; ++ni) {
        int col = colblk + wn * 64 + ni * 16 + fr;
        float bv = bias[col];
#pragma unroll
        for (int mi = 0; mi < 4; ++mi) {
            int row = rowblk + wm * 64 + mi * 16 + fq * 4;
#pragma unroll
            for (int r = 0; r < 4; ++r) {
                float v = acc[mi][ni][r] + bv;
                if (relu) v = fmaxf(v, 0.f);
                if (obf16)
                    ((ushort*)Cout)[(size_t)(row + r) * N + col] = f2bu(v);
                else
                    ((float*)Cout)[(size_t)(row + r) * N + col] = v;
            }
        }
    }
}

// ---------------------------------------------------------------------------
__global__ __launch_bounds__(256) void wcast_kernel(
    const float* __restrict__ W, ushort* __restrict__ WT, int K, int N)
{
    __shared__ float t[32][33];
    const float* Wl = W + (size_t)blockIdx.z * K * N;
    ushort* WTl = WT + (size_t)blockIdx.z * K * N;
    int n0 = blockIdx.x * 32, k0 = blockIdx.y * 32;
    int tx = threadIdx.x, ty = threadIdx.y;
#pragma unroll
    for (int r = 0; r < 32; r += 8)
        t[ty + r][tx] = Wl[(size_t)(k0 + ty + r) * N + n0 + tx];
    __syncthreads();
#pragma unroll
    for (int r = 0; r < 32; r += 8)
        WTl[(size_t)(n0 + ty + r) * K + k0 + tx] = f2bu(t[tx][ty + r]);
}

// ---------------------------------------------------------------------------
// fp32 SGEMM for the embed GEMM only; row-remap; writes fp32 X and bf16 Xb.
// ---------------------------------------------------------------------------
__global__ __launch_bounds__(256) void sgemm_kernel(
    const float* __restrict__ A, const float* __restrict__ W,
    const float* __restrict__ bias, float* __restrict__ C,
    ushort* __restrict__ Cb, int M, int N, int K)
{
    __shared__ float As_[16][64];
    __shared__ float Bs_[16][64];
    int tid = threadIdx.x;
    int rowblk = blockIdx.y * 64;
    int colblk = blockIdx.x * 64;
    int a_row = tid & 63, a_q = tid >> 6;
    int b_kr = tid >> 4, b_cg = tid & 15;
    int rm = tid >> 4, cn = tid & 15;
    float acc[4][4] = {};
    const float* Aptr = A + (size_t)(rowblk + a_row) * K;
    for (int kt = 0; kt < K; kt += 16) {
        float4 av = *(const float4*)(Aptr + kt + a_q * 4);
        float4 bv = *(const float4*)(W + (size_t)(kt + b_kr) * N + colblk + b_cg * 4);
        As_[a_q * 4 + 0][a_row] = av.x;
        As_[a_q * 4 + 1][a_row] = av.y;
        As_[a_q * 4 + 2][a_row] = av.z;
        As_[a_q * 4 + 3][a_row] = av.w;
        *(float4*)&Bs_[b_kr][b_cg * 4] = bv;
        __syncthreads();
#pragma unroll
        for (int kk = 0; kk < 16; ++kk) {
            float4 a4 = *(const float4*)&As_[kk][rm * 4];
            float4 b4 = *(const float4*)&Bs_[kk][cn * 4];
            float ar[4] = {a4.x, a4.y, a4.z, a4.w};
            float br[4] = {b4.x, b4.y, b4.z, b4.w};
#pragma unroll
            for (int i = 0; i < 4; ++i)
#pragma unroll
                for (int j = 0; j < 4; ++j) acc[i][j] += ar[i] * br[j];
        }
        __syncthreads();
    }
    float4 bv = *(const float4*)(bias + colblk + cn * 4);
    float bb[4] = {bv.x, bv.y, bv.z, bv.w};
#pragma unroll
    for (int i = 0; i < 4; ++i) {
        int grow = rowblk + rm * 4 + i;
        size_t orow = (size_t)(grow + grow / NT_ + 1);
        float4 r;
        r.x = acc[i][0] + bb[0]; r.y = acc[i][1] + bb[1];
        r.z = acc[i][2] + bb[2]; r.w = acc[i][3] + bb[3];
        *(float4*)(C + orow * N + colblk + cn * 4) = r;
        ushort4 h;
        h.x = f2bu(r.x); h.y = f2bu(r.y); h.z = f2bu(r.z); h.w = f2bu(r.w);
        *(ushort4*)(Cb + orow * N + colblk + cn * 4) = h;
    }
}

__global__ __launch_bounds__(256) void cls_kernel(
    const float* __restrict__ coords, const float* __restrict__ w_cls,
    const float* __restrict__ b_cls, float* __restrict__ X,
    ushort* __restrict__ Xb)
{
    int b = blockIdx.x;
    int t = threadIdx.x;
    float c0 = coords[b * 3 + 0], c1 = coords[b * 3 + 1], c2 = coords[b * 3 + 2];
    float v = c0 * w_cls[t] + c1 * w_cls[D_ + t] + c2 * w_cls[2 * D_ + t] + b_cls[t];
    X[(size_t)b * L_ * D_ + t] = v;
    Xb[(size_t)b * L_ * D_ + t] = f2bu(v);
}

// ---------------------------------------------------------------------------
// MFMA attention v6: one block per (b,h), 512 threads (8 waves).
// K/V^T staged once (68.4 KB, 2 blocks/CU). Each wave processes TWO 16-row
// q-tiles per pass so every K/V fragment read feeds 2x the MFMAs. exp2-based
// softmax (log2e folded into scale/slope). PV from registers via mfma16.
// O-stores ALWAYS guarded q<L (pr=14's A-tile spans q 448..463; rows >=457
// alias the next batch's rows -> unguarded store is a cross-block race).
// ---------------------------------------------------------------------------
__global__ __launch_bounds__(512) void attn_kernel(
    const ushort* __restrict__ qkv, ushort* __restrict__ out)
{
    __shared__ __align__(16) ushort Ks[464][40];    // 36.3 KB
    __shared__ __align__(16) ushort Vt[32][488];    // 30.5 KB

    int h = blockIdx.x, b = blockIdx.y;
    int tid = threadIdx.x;
    int wave = tid >> 6, lane = tid & 63;
    int fr = lane & 15, fq = lane >> 4;
    const float scale2 = 0.17677669529663687f * 1.4426950408889634f;
    float slope2 = ((h < 4) ? 1.0f : 0.5f) * 1.4426950408889634f;
    const ushort* base = qkv + (size_t)b * L_ * 768;

    for (int j = tid >> 2; j < 464; j += 128) {
        int c8 = (tid & 3) * 8;
        uint4 u = make_uint4(0u, 0u, 0u, 0u);
        if (j < L_) u = *(const uint4*)(base + (size_t)j * 768 + 256 + h * 32 + c8);
        *(uint4*)&Ks[j][c8] = u;
    }
    for (int m = wave; m < 32; m += 8) {
        int dg = (m >> 3) * 8, jb = m & 7;
        int j = jb * 64 + lane;
        uint4 u = make_uint4(0u, 0u, 0u, 0u);
        if (j < L_) u = *(const uint4*)(base + (size_t)j * 768 + 512 + h * 32 + dg);
        if (j < 488) {
            const ushort* pu = (const ushort*)&u;
#pragma unroll
            for (int e = 0; e < 8; ++e) Vt[dg + e][j] = pu[e];
        }
    }
    __syncthreads();

    // 15 tile-pairs (29 tiles; pair 14's second tile is OOB-guarded)
    for (int pr = wave; pr < 15; pr += 8) {
        int q0 = pr * 32;
        int twoB = (pr < 14);
        uint4 quA = *(const uint4*)(base + (size_t)(q0 + fr) * 768 + h * 32 + fq * 8);
        v8bf qfA = *(v8bf*)&quA;
        uint4 quB = *(const uint4*)(base + (size_t)(q0 + 16 + fr) * 768 + h * 32 + fq * 8);
        v8bf qfB = *(v8bf*)&quB;
        float fqAq = (float)(q0 + fr);
        float fqBq = fqAq + 16.0f;
        float psA = 0.f, psB = 0.f;
        v4f oA0 = (v4f)0.0f, oA1 = (v4f)0.0f, oB0 = (v4f)0.0f, oB1 = (v4f)0.0f;

        for (int kc = 0; kc < 14; ++kc) {
            int kb = kc * 32;
            v8bf kf0 = *(const v8bf*)&Ks[kb + fr][fq * 8];
            v8bf kf1 = *(const v8bf*)&Ks[kb + 16 + fr][fq * 8];
            uint2 va0 = *(const uint2*)&Vt[fr][kb + fq * 4];
            uint2 va1 = *(const uint2*)&Vt[16 + fr][kb + fq * 4];
            uint2 vb0 = *(const uint2*)&Vt[fr][kb + 16 + fq * 4];
            uint2 vb1 = *(const uint2*)&Vt[16 + fr][kb + 16 + fq * 4];
            float ke = (float)(kb + 4 * fq);

            v4f dA0 = (v4f)0.0f, dA1 = (v4f)0.0f;
            dA0 = __builtin_amdgcn_mfma_f32_16x16x32_bf16(kf0, qfA, dA0, 0, 0, 0);
            dA1 = __builtin_amdgcn_mfma_f32_16x16x32_bf16(kf1, qfA, dA1, 0, 0, 0);
            {
                float dl0 = fqAq - ke, dl1 = dl0 - 16.0f;
                float pe[4], po[4];
#pragma unroll
                for (int r = 0; r < 4; ++r) {
                    pe[r] = exp2f(fmaf(dA0[r], scale2, -slope2 * fabsf(dl0 - (float)r)));
                    po[r] = exp2f(fmaf(dA1[r], scale2, -slope2 * fabsf(dl1 - (float)r)));
                    psA += pe[r] + po[r];
                }
                uint2 ue, uo;
                ue.x = pack_bf2(pe[0], pe[1]); ue.y = pack_bf2(pe[2], pe[3]);
                uo.x = pack_bf2(po[0], po[1]); uo.y = pack_bf2(po[2], po[3]);
                oA0 = mfma16(va0, ue, oA0);
                oA1 = mfma16(va1, ue, oA1);
                oA0 = mfma16(vb0, uo, oA0);
                oA1 = mfma16(vb1, uo, oA1);
            }
            if (twoB) {
                v4f dB0 = (v4f)0.0f, dB1 = (v4f)0.0f;
                dB0 = __builtin_amdgcn_mfma_f32_16x16x32_bf16(kf0, qfB, dB0, 0, 0, 0);
                dB1 = __builtin_amdgcn_mfma_f32_16x16x32_bf16(kf1, qfB, dB1, 0, 0, 0);
                float dl0 = fqBq - ke, dl1 = dl0 - 16.0f;
                float pe[4], po[4];
#pragma unroll
                for (int r = 0; r < 4; ++r) {
                    pe[r] = exp2f(fmaf(dB0[r], scale2, -slope2 * fabsf(dl0 - (float)r)));
                    po[r] = exp2f(fmaf(dB1[r], scale2, -slope2 * fabsf(dl1 - (float)r)));
                    psB += pe[r] + po[r];
                }
                uint2 ue, uo;
                ue.x = pack_bf2(pe[0], pe[1]); ue.y = pack_bf2(pe[2], pe[3]);
                uo.x = pack_bf2(po[0], po[1]); uo.y = pack_bf2(po[2], po[3]);
                oB0 = mfma16(va0, ue, oB0);
                oB1 = mfma16(va1, ue, oB1);
                oB0 = mfma16(vb0, uo, oB0);
                oB1 = mfma16(vb1, uo, oB1);
            }
        }
        // tail: k 448..463
        {
            v8bf kf0 = *(const v8bf*)&Ks[448 + fr][fq * 8];
            uint2 va0 = *(const uint2*)&Vt[fr][448 + fq * 4];
            uint2 va1 = *(const uint2*)&Vt[16 + fr][448 + fq * 4];
            v4f dA0 = (v4f)0.0f;
            dA0 = __builtin_amdgcn_mfma_f32_16x16x32_bf16(kf0, qfA, dA0, 0, 0, 0);
            float pe[4];
#pragma unroll
            for (int r = 0; r < 4; ++r) {
                int k = 448 + 4 * fq + r;
                pe[r] = (k < L_)
                    ? exp2f(fmaf(dA0[r], scale2, -slope2 * fabsf(fqAq - (float)k))) : 0.f;
                psA += pe[r];
            }
            uint2 ue;
            ue.x = pack_bf2(pe[0], pe[1]); ue.y = pack_bf2(pe[2], pe[3]);
            oA0 = mfma16(va0, ue, oA0);
            oA1 = mfma16(va1, ue, oA1);
            if (twoB) {
                v4f dB0 = (v4f)0.0f;
                dB0 = __builtin_amdgcn_mfma_f32_16x16x32_bf16(kf0, qfB, dB0, 0, 0, 0);
                float pf[4];
#pragma unroll
                for (int r = 0; r < 4; ++r) {
                    int k = 448 + 4 * fq + r;
                    pf[r] = (k < L_)
                        ? exp2f(fmaf(dB0[r], scale2, -slope2 * fabsf(fqBq - (float)k))) : 0.f;
                    psB += pf[r];
                }
                uint2 ub;
                ub.x = pack_bf2(pf[0], pf[1]); ub.y = pack_bf2(pf[2], pf[3]);
                oB0 = mfma16(va0, ub, oB0);
                oB1 = mfma16(va1, ub, oB1);
            }
        }

        psA += __shfl_xor(psA, 16);
        psA += __shfl_xor(psA, 32);
        psB += __shfl_xor(psB, 16);
        psB += __shfl_xor(psB, 32);
        {
            int q = q0 + fr;
            if (q < L_) {
                float inv = 1.0f / psA;
                uint2 w0, w1;
                w0.x = pack_bf2(oA0[0] * inv, oA0[1] * inv);
                w0.y = pack_bf2(oA0[2] * inv, oA0[3] * inv);
                w1.x = pack_bf2(oA1[0] * inv, oA1[1] * inv);
                w1.y = pack_bf2(oA1[2] * inv, oA1[3] * inv);
                ushort* op = out + (size_t)(b * L_ + q) * D_ + h * 32;
                *(uint2*)(op + fq * 4) = w0;
                *(uint2*)(op + 16 + fq * 4) = w1;
            }
        }
        if (twoB) {
            int q = q0 + 16 + fr;
            if (q < L_) {
                float inv = 1.0f / psB;
                uint2 w0, w1;
                w0.x = pack_bf2(oB0[0] * inv, oB0[1] * inv);
                w0.y = pack_bf2(oB0[2] * inv, oB0[3] * inv);
                w1.x = pack_bf2(oB1[0] * inv, oB1[1] * inv);
                w1.y = pack_bf2(oB1[2] * inv, oB1[3] * inv);
                ushort* op = out + (size_t)(b * L_ + q) * D_ + h * 32;
                *(uint2*)(op + fq * 4) = w0;
                *(uint2*)(op + 16 + fq * 4) = w1;
            }
        }
    }
}

// ---------------------------------------------------------------------------
// Fused residual+LN: wave per row, shuffle-only, 4 rows/block.
// ---------------------------------------------------------------------------
__global__ __launch_bounds__(256) void ln_kernel(
    const float* __restrict__ res, const ushort* __restrict__ y,
    const float* __restrict__ g, const float* __restrict__ bb,
    float* __restrict__ xout, ushort* __restrict__ xbout)
{
    int row = blockIdx.x * 4 + (threadIdx.x >> 6);
    int lane = threadIdx.x & 63;
    size_t off = (size_t)row * D_ + lane * 4;
    float4 rv = *(const float4*)(res + off);
    ushort4 yv4 = *(const ushort4*)(y + off);
    float4 v;
    v.x = rv.x + bu2f(yv4.x);
    v.y = rv.y + bu2f(yv4.y);
    v.z = rv.z + bu2f(yv4.z);
    v.w = rv.w + bu2f(yv4.w);

    float s = v.x + v.y + v.z + v.w;
#pragma unroll
    for (int o = 1; o < 64; o <<= 1) s += __shfl_xor(s, o);
    float mean = s * (1.0f / 256.0f);

    float4 d;
    d.x = v.x - mean; d.y = v.y - mean; d.z = v.z - mean; d.w = v.w - mean;
    float sq = d.x * d.x + d.y * d.y + d.z * d.z + d.w * d.w;
#pragma unroll
    for (int o = 1; o < 64; o <<= 1) sq += __shfl_xor(sq, o);
    float rstd = rsqrtf(sq * (1.0f / 256.0f) + 1e-5f);

    float4 gv = *(const float4*)(g + lane * 4);
    float4 bv = *(const float4*)(bb + lane * 4);
    float4 o;
    o.x = d.x * rstd * gv.x + bv.x;
    o.y = d.y * rstd * gv.y + bv.y;
    o.z = d.z * rstd * gv.z + bv.z;
    o.w = d.w * rstd * gv.w + bv.w;
    *(float4*)(xout + off) = o;
    ushort4 hb;
    hb.x = f2bu(o.x); hb.y = f2bu(o.y); hb.z = f2bu(o.z); hb.w = f2bu(o.w);
    *(ushort4*)(xbout + off) = hb;
}

// ---------------------------------------------------------------------------
// head1 via MFMA: SCp[row] = gelu(bn(Xb@th1_w + b1)) @ th2_w + b2.
// ---------------------------------------------------------------------------
__global__ __launch_bounds__(256) void head1_kernel(
    const ushort* __restrict__ Xb, const ushort* __restrict__ th1T,
    const float* __restrict__ b1, const float* __restrict__ bng,
    const float* __restrict__ bnb, const float* __restrict__ w2,
    const float* __restrict__ b2, float* __restrict__ SCp)
{
    __shared__ ushort As[128 * 32];
    __shared__ ushort Bs[32 * 264];
    int tid = threadIdx.x;
    int wave = tid >> 6, lane = tid & 63;
    int fr = lane & 15, fq = lane >> 4;
    int rowblk = blockIdx.x * 128;
    int scol = fq ^ (lane & 3) ^ ((lane >> 2) & 1);

    for (int i = tid; i < 1024; i += 256) {
        int r = i >> 5, c8 = (i & 31) * 8;
        *(uint4*)&Bs[r * 264 + c8] = *(const uint4*)(th1T + r * 256 + c8);
    }

    int c0 = wave * 64 + lane;
    int r0 = c0 >> 2, k0g = (c0 & 3) ^ (r0 & 3) ^ ((r0 >> 2) & 1);
    int c1 = 256 + c0;
    int r1 = c1 >> 2, k1g = (c1 & 3) ^ (r1 & 3) ^ ((r1 >> 2) & 1);
    const ushort* Ag0 = Xb + (size_t)(rowblk + r0) * 256 + k0g * 8;
    const ushort* Ag1 = Xb + (size_t)(rowblk + r1) * 256 + k1g * 8;
    ushort* lA0 = As + (size_t)(wave * 64) * 8;
    ushort* lA1 = As + (size_t)(256 + wave * 64) * 8;

    v4f acc[2][2];
#pragma unroll
    for (int i = 0; i < 2; ++i)
#pragma unroll
        for (int j = 0; j < 2; ++j) acc[i][j] = (v4f)0.0f;

    for (int kt = 0; kt < 256; kt += 32) {
        gload16(Ag0 + kt, lA0);
        gload16(Ag1 + kt, lA1);
        __syncthreads();
        v8bf a[2], bfr[2];
#pragma unroll
        for (int mi = 0; mi < 2; ++mi)
            a[mi] = *(const v8bf*)(As + (size_t)((wave * 2 + mi) * 16 + fr) * 32 + scol * 8);
#pragma unroll
        for (int ni = 0; ni < 2; ++ni)
            bfr[ni] = *(const v8bf*)(Bs + (size_t)(ni * 16 + fr) * 264 + kt + fq * 8);
#pragma unroll
        for (int mi = 0; mi < 2; ++mi)
#pragma unroll
            for (int ni = 0; ni < 2; ++ni)
                acc[mi][ni] = __builtin_amdgcn_mfma_f32_16x16x32_bf16(
                    a[mi], bfr[ni], acc[mi][ni], 0, 0, 0);
        __syncthreads();
    }

    const float bnr = 0.9999950000374997f;  // rsqrt(1+1e-5)
    float b1v[2], bsv[2], bbv[2], w2v[2];
#pragma unroll
    for (int ni = 0; ni < 2; ++ni) {
        int j = ni * 16 + fr;
        b1v[ni] = b1[j];
        bsv[ni] = bng[j] * bnr;
        bbv[ni] = bnb[j];
        w2v[ni] = w2[j];
    }
    const float gc = 0.7978845608028654f;
    float b2v = b2[0];
#pragma unroll
    for (int mi = 0; mi < 2; ++mi) {
#pragma unroll
        for (int r = 0; r < 4; ++r) {
            float s = 0.f;
#pragma unroll
            for (int ni = 0; ni < 2; ++ni) {
                float hb = (acc[mi][ni][r] + b1v[ni]) * bsv[ni] + bbv[ni];
                float t = tanhf(gc * (hb + 0.044715f * hb * hb * hb));
                s += 0.5f * hb * (1.0f + t) * w2v[ni];
            }
#pragma unroll
            for (int o = 1; o < 16; o <<= 1) s += __shfl_xor(s, o);
            int row = rowblk + (wave * 2 + mi) * 16 + fq * 4 + r;
            if (fr == 0 && row < B_ * L_) SCp[row] = s + b2v;
        }
    }
}

// ---------------------------------------------------------------------------
// head2: block (colgroup, b); 64 cols x 4 L-partitions per block.
// ---------------------------------------------------------------------------
__global__ __launch_bounds__(256) void head2_kernel(
    const float* __restrict__ SCp, const float* __restrict__ X,
    float* __restrict__ outp)
{
    int cg = blockIdx.x, b = blockIdx.y;
    int tid = threadIdx.x;
    __shared__ float wbuf[L_];
    __shared__ float r1[4], r2[4];
    __shared__ float part[4][64];
    const float* s = SCp + (size_t)b * L_;

    float m = -1e30f;
    for (int j = tid; j < L_; j += 256) m = fmaxf(m, s[j]);
#pragma unroll
    for (int o = 1; o < 64; o <<= 1) m = fmaxf(m, __shfl_xor(m, o));
    if ((tid & 63) == 0) r1[tid >> 6] = m;
    __syncthreads();
    m = fmaxf(fmaxf(r1[0], r1[1]), fmaxf(r1[2], r1[3]));

    float sum = 0.f;
    for (int j = tid; j < L_; j += 256) {
        float e = __expf(s[j] - m);
        wbuf[j] = e;
        sum += e;
    }
#pragma unroll
    for (int o = 1; o < 64; o <<= 1) sum += __shfl_xor(sum, o);
    if ((tid & 63) == 0) r2[tid >> 6] = sum;
    __syncthreads();
    float inv = 1.0f / (r2[0] + r2[1] + r2[2] + r2[3]);

    int c = tid & 63, pt = tid >> 6;
    int col = cg * 64 + c;
    float acc = 0.f;
    const float* xb = X + (size_t)b * L_ * D_ + col;
    for (int l = pt; l < L_; l += 4) acc += wbuf[l] * xb[(size_t)l * D_];
    part[pt][c] = acc;
    __syncthreads();
    if (pt == 0)
        outp[b * D_ + col] = (part[0][c] + part[1][c] + part[2][c] + part[3][c]) * inv;
}

// ---------------------------------------------------------------------------
extern "C" void kernel_launch(void* const* d_in, const int* in_sizes, int n_in,
                              void* d_out, int out_size, void* d_ws, size_t ws_size,
                              hipStream_t stream)
{
    const float* gene   = (const float*)d_in[0];
    const float* coords = (const float*)d_in[1];
    const float* w_in   = (const float*)d_in[2];
    const float* b_in   = (const float*)d_in[3];
    const float* w_cls  = (const float*)d_in[4];
    const float* b_cls  = (const float*)d_in[5];
    const float* qkv_w  = (const float*)d_in[6];
    const float* qkv_b  = (const float*)d_in[7];
    const float* ln1_g  = (const float*)d_in[8];
    const float* ln1_b  = (const float*)d_in[9];
    const float* ffn_w1 = (const float*)d_in[10];
    const float* ffn_b1 = (const float*)d_in[11];
    const float* ffn_w2 = (const float*)d_in[12];
    const float* ffn_b2 = (const float*)d_in[13];
    const float* ln2_g  = (const float*)d_in[14];
    const float* ln2_b  = (const float*)d_in[15];
    const float* th1_w  = (const float*)d_in[16];
    const float* th1_b  = (const float*)d_in[17];
    const float* bn_g   = (const float*)d_in[18];
    const float* bn_b   = (const float*)d_in[19];
    const float* th2_w  = (const float*)d_in[20];
    const float* th2_b  = (const float*)d_in[21];
    float* out = (float*)d_out;

    const int ROWS = B_ * L_;   // 29248
    char* p = (char*)d_ws;
    float*  X    = (float*)p;  p += (size_t)MPAD * 256 * 4;
    ushort* AOb  = (ushort*)p; p += (size_t)MPAD * 256 * 2;
    ushort* Xb   = (ushort*)p; p += (size_t)MPAD * 256 * 2;
    ushort* SH   = (ushort*)p; p += (size_t)MPAD * 1024 * 2;
    ushort* qkvT = (ushort*)p; p += (size_t)NL_ * 768 * 256 * 2;
    ushort* w1T  = (ushort*)p; p += (size_t)NL_ * 1024 * 256 * 2;
    ushort* w2T  = (ushort*)p; p += (size_t)NL_ * 256 * 1024 * 2;
    ushort* th1T = (ushort*)p; p += (size_t)32 * 256 * 2;
    float*  SCp  = (float*)p;  p += (size_t)ROWS * 4;

    wcast_kernel<<<dim3(768 / 32, 256 / 32, NL_), dim3(32, 8), 0, stream>>>(qkv_w, qkvT, 256, 768);
    wcast_kernel<<<dim3(1024 / 32, 256 / 32, NL_), dim3(32, 8), 0, stream>>>(ffn_w1, w1T, 256, 1024);
    wcast_kernel<<<dim3(256 / 32, 1024 / 32, NL_), dim3(32, 8), 0, stream>>>(ffn_w2, w2T, 1024, 256);
    wcast_kernel<<<dim3(1, 8, 1), dim3(32, 8), 0, stream>>>(th1_w, th1T, 256, 32);

    sgemm_kernel<<<dim3(D_ / 64, (B_ * NT_) / 64), 256, 0, stream>>>(
        gene, w_in, b_in, X, Xb, B_ * NT_, D_, TOK_);
    cls_kernel<<<B_, 256, 0, stream>>>(coords, w_cls, b_cls, X, Xb);

    for (int l = 0; l < NL_; ++l) {
        mfma_gemm<<<dim3(768 / 128, MPAD / 128), 256, 0, stream>>>(
            Xb, qkvT + (size_t)l * 768 * 256, qkv_b + l * 768, SH, 768, 256, 0, 1);
        attn_kernel<<<dim3(H_, B_), 512, 0, stream>>>(SH, AOb);
        ln_kernel<<<ROWS / 4, 256, 0, stream>>>(X, AOb, ln1_g + l * D_, ln1_b + l * D_, X, Xb);
        mfma_gemm<<<dim3(1024 / 128, MPAD / 128), 256, 0, stream>>>(
            Xb, w1T + (size_t)l * 1024 * 256, ffn_b1 + l * 1024, SH, 1024, 256, 1, 1);
        mfma_gemm<<<dim3(256 / 128, MPAD / 128), 256, 0, stream>>>(
            SH, w2T + (size_t)l * 256 * 1024, ffn_b2 + l * D_, AOb, 256, 1024, 0, 1);
        ln_kernel<<<ROWS / 4, 256, 0, stream>>>(X, AOb, ln2_g + l * D_, ln2_b + l * D_, X, Xb);
    }

    head1_kernel<<<MPAD / 128, 256, 0, stream>>>(
        Xb, th1T, th1_b, bn_g, bn_b, th2_w, th2_b, SCp);
    head2_kernel<<<dim3(4, B_), 256, 0, stream>>>(SCp, X, out);
}

// Round 13
// 936.746 us; speedup vs baseline: 1.2583x; 1.0570x over previous
//
#include <hip/hip_runtime.h>
#include <math.h>

#define B_   64
#define TOK_ 64
#define NT_  456
#define L_   457
#define D_   256
#define H_   8
#define HD_  32
#define FF_  1024
#define NL_  4
#define PH_  32
#define MPAD 29312   // 229 * 128 (rows padded for 128-row GEMM tiles)

typedef unsigned int uint;
typedef unsigned short ushort;
typedef __bf16 v8bf __attribute__((ext_vector_type(8)));
typedef __bf16 v4bf __attribute__((ext_vector_type(4)));
typedef short v4s __attribute__((ext_vector_type(4)));
typedef float v4f __attribute__((ext_vector_type(4)));

__device__ __forceinline__ float bu2f(ushort x) {
    return __uint_as_float(((uint)x) << 16);
}
__device__ __forceinline__ ushort f2bu(float f) {
    union { float f; uint u; } x; x.f = f;
    uint r = (x.u + 0x7fffu + ((x.u >> 16) & 1u)) >> 16;
    return (ushort)r;
}
__device__ __forceinline__ uint pack_bf2(float a, float b) {
#if defined(__HIP_DEVICE_COMPILE__) && __has_builtin(__builtin_amdgcn_cvt_pk_bf16_f32)
    typedef __bf16 bf2v __attribute__((ext_vector_type(2)));
    bf2v v = __builtin_amdgcn_cvt_pk_bf16_f32(a, b);
    return *(uint*)&v;
#else
    return (uint)f2bu(a) | ((uint)f2bu(b) << 16);
#endif
}

// K=16 bf16 MFMA (PV with register-resident P). Guarded for the host pass.
__device__ __forceinline__ v4f mfma16(uint2 a, uint2 b, v4f c) {
#if defined(__HIP_DEVICE_COMPILE__)
#if __has_builtin(__builtin_amdgcn_mfma_f32_16x16x16_bf16)
    return __builtin_amdgcn_mfma_f32_16x16x16_bf16(*(v4bf*)&a, *(v4bf*)&b, c, 0, 0, 0);
#else
    return __builtin_amdgcn_mfma_f32_16x16x16bf16_1k(*(v4s*)&a, *(v4s*)&b, c, 0, 0, 0);
#endif
#else
    (void)a; (void)b;
    return c;
#endif
}

// async global->LDS 16B copy; lds base wave-uniform, data at base + lane*16.
__device__ __forceinline__ void gload16(const void* g, void* l) {
    __builtin_amdgcn_global_load_lds(
        (const __attribute__((address_space(1))) void*)(unsigned long long)(uintptr_t)g,
        (__attribute__((address_space(3))) void*)(uint)(uintptr_t)l,
        16, 0, 0);
}

// ---------------------------------------------------------------------------
// bf16 MFMA GEMM, BK=64: C[M,N] = A[M,K]·W^T[N,K] + bias. 128x128 tile,
// 4 waves (2x2). K%64==0. LDS 32 KB. Flat-granule layout with XOR swizzle:
// granule g (16B) of row r stored at position g^(r&7); fragment b128 reads
// spread over all 8 bank groups (2 lanes each = free); staging writes are
// consecutive granules (bank-uniform sweep). Halves barrier count vs BK=32.
// ---------------------------------------------------------------------------
__global__ __launch_bounds__(256) void mfma_gemm(
    const ushort* __restrict__ A, const ushort* __restrict__ WT,
    const float* __restrict__ bias, void* __restrict__ Cout,
    int N, int K, int relu, int obf16)
{
    __shared__ ushort As[128 * 64];
    __shared__ ushort Bs[128 * 64];
    int tid = threadIdx.x;
    int wave = tid >> 6, lane = tid & 63;
    int colblk = blockIdx.x * 128;
    int rowblk = blockIdx.y * 128;
    int wm = wave >> 1, wn = wave & 1;
    int fr = lane & 15, fq = lane >> 4;

    v4f acc[4][4];
#pragma unroll
    for (int i = 0; i < 4; ++i)
#pragma unroll
        for (int j = 0; j < 4; ++j) acc[i][j] = (v4f)0.0f;

    // staging: 1024 granules per matrix per iter; 4 passes of 256
    const ushort* Ag[4];
    const ushort* Bg[4];
    ushort* lA[4];
    ushort* lB[4];
#pragma unroll
    for (int p = 0; p < 4; ++p) {
        int c = p * 256 + wave * 64 + lane;
        int r = c >> 3, gs = (c & 7) ^ (r & 7);
        Ag[p] = A + (size_t)(rowblk + r) * K + gs * 8;
        Bg[p] = WT + (size_t)(colblk + r) * K + gs * 8;
        lA[p] = As + (size_t)(p * 256 + wave * 64) * 8;
        lB[p] = Bs + (size_t)(p * 256 + wave * 64) * 8;
    }

    for (int kt = 0; kt < K; kt += 64) {
#pragma unroll
        for (int p = 0; p < 4; ++p) gload16(Ag[p] + kt, lA[p]);
#pragma unroll
        for (int p = 0; p < 4; ++p) gload16(Bg[p] + kt, lB[p]);
        __syncthreads();

#pragma unroll
        for (int ks = 0; ks < 2; ++ks) {
            int pa = (ks * 4 + fq) ^ (fr & 7);
            v8bf a[4], b[4];
#pragma unroll
            for (int mi = 0; mi < 4; ++mi) {
                int rl = wm * 64 + mi * 16 + fr;
                a[mi] = *(const v8bf*)(As + (size_t)(rl * 8 + pa) * 8);
            }
#pragma unroll
            for (int ni = 0; ni < 4; ++ni) {
                int rl = wn * 64 + ni * 16 + fr;
                b[ni] = *(const v8bf*)(Bs + (size_t)(rl * 8 + pa) * 8);
            }
#pragma unroll
            for (int mi = 0; mi < 4; ++mi)
#pragma unroll
                for (int ni = 0; ni < 4; ++ni)
                    acc[mi][ni] = __builtin_amdgcn_mfma_f32_16x16x32_bf16(
                        a[mi], b[ni], acc[mi][ni], 0, 0, 0);
        }
        __syncthreads();
    }

#pragma unroll
    for (int ni = 0; ni < 4; ++ni) {
        int col = colblk + wn * 64 + ni * 16 + fr;
        float bv = bias[col];
#pragma unroll
        for (int mi = 0; mi < 4; ++mi) {
            int row = rowblk + wm * 64 + mi * 16 + fq * 4;
#pragma unroll
            for (int r = 0; r < 4; ++r) {
                float v = acc[mi][ni][r] + bv;
                if (relu) v = fmaxf(v, 0.f);
                if (obf16)
                    ((ushort*)Cout)[(size_t)(row + r) * N + col] = f2bu(v);
                else
                    ((float*)Cout)[(size_t)(row + r) * N + col] = v;
            }
        }
    }
}

// ---------------------------------------------------------------------------
__global__ __launch_bounds__(256) void wcast_kernel(
    const float* __restrict__ W, ushort* __restrict__ WT, int K, int N)
{
    __shared__ float t[32][33];
    const float* Wl = W + (size_t)blockIdx.z * K * N;
    ushort* WTl = WT + (size_t)blockIdx.z * K * N;
    int n0 = blockIdx.x * 32, k0 = blockIdx.y * 32;
    int tx = threadIdx.x, ty = threadIdx.y;
#pragma unroll
    for (int r = 0; r < 32; r += 8)
        t[ty + r][tx] = Wl[(size_t)(k0 + ty + r) * N + n0 + tx];
    __syncthreads();
#pragma unroll
    for (int r = 0; r < 32; r += 8)
        WTl[(size_t)(n0 + ty + r) * K + k0 + tx] = f2bu(t[tx][ty + r]);
}

// ---------------------------------------------------------------------------
// fp32 SGEMM for the embed GEMM only; row-remap; writes bf16 Xb only
// (residual stream is bf16 everywhere now).
// ---------------------------------------------------------------------------
__global__ __launch_bounds__(256) void sgemm_kernel(
    const float* __restrict__ A, const float* __restrict__ W,
    const float* __restrict__ bias, ushort* __restrict__ Cb,
    int M, int N, int K)
{
    __shared__ float As_[16][64];
    __shared__ float Bs_[16][64];
    int tid = threadIdx.x;
    int rowblk = blockIdx.y * 64;
    int colblk = blockIdx.x * 64;
    int a_row = tid & 63, a_q = tid >> 6;
    int b_kr = tid >> 4, b_cg = tid & 15;
    int rm = tid >> 4, cn = tid & 15;
    float acc[4][4] = {};
    const float* Aptr = A + (size_t)(rowblk + a_row) * K;
    for (int kt = 0; kt < K; kt += 16) {
        float4 av = *(const float4*)(Aptr + kt + a_q * 4);
        float4 bv = *(const float4*)(W + (size_t)(kt + b_kr) * N + colblk + b_cg * 4);
        As_[a_q * 4 + 0][a_row] = av.x;
        As_[a_q * 4 + 1][a_row] = av.y;
        As_[a_q * 4 + 2][a_row] = av.z;
        As_[a_q * 4 + 3][a_row] = av.w;
        *(float4*)&Bs_[b_kr][b_cg * 4] = bv;
        __syncthreads();
#pragma unroll
        for (int kk = 0; kk < 16; ++kk) {
            float4 a4 = *(const float4*)&As_[kk][rm * 4];
            float4 b4 = *(const float4*)&Bs_[kk][cn * 4];
            float ar[4] = {a4.x, a4.y, a4.z, a4.w};
            float br[4] = {b4.x, b4.y, b4.z, b4.w};
#pragma unroll
            for (int i = 0; i < 4; ++i)
#pragma unroll
                for (int j = 0; j < 4; ++j) acc[i][j] += ar[i] * br[j];
        }
        __syncthreads();
    }
    float4 bv = *(const float4*)(bias + colblk + cn * 4);
    float bb[4] = {bv.x, bv.y, bv.z, bv.w};
#pragma unroll
    for (int i = 0; i < 4; ++i) {
        int grow = rowblk + rm * 4 + i;
        size_t orow = (size_t)(grow + grow / NT_ + 1);
        ushort4 h;
        h.x = f2bu(acc[i][0] + bb[0]);
        h.y = f2bu(acc[i][1] + bb[1]);
        h.z = f2bu(acc[i][2] + bb[2]);
        h.w = f2bu(acc[i][3] + bb[3]);
        *(ushort4*)(Cb + orow * N + colblk + cn * 4) = h;
    }
}

__global__ __launch_bounds__(256) void cls_kernel(
    const float* __restrict__ coords, const float* __restrict__ w_cls,
    const float* __restrict__ b_cls, ushort* __restrict__ Xb)
{
    int b = blockIdx.x;
    int t = threadIdx.x;
    float c0 = coords[b * 3 + 0], c1 = coords[b * 3 + 1], c2 = coords[b * 3 + 2];
    float v = c0 * w_cls[t] + c1 * w_cls[D_ + t] + c2 * w_cls[2 * D_ + t] + b_cls[t];
    Xb[(size_t)b * L_ * D_ + t] = f2bu(v);
}

// ---------------------------------------------------------------------------
// MFMA attention v6: one block per (b,h), 512 threads (8 waves).
// K/V^T staged once (68.4 KB, 2 blocks/CU). Dual 16-row q-tiles per pass;
// exp2-based softmax; PV from registers via mfma16. O-stores guarded q<L.
// ---------------------------------------------------------------------------
__global__ __launch_bounds__(512) void attn_kernel(
    const ushort* __restrict__ qkv, ushort* __restrict__ out)
{
    __shared__ __align__(16) ushort Ks[464][40];    // 36.3 KB
    __shared__ __align__(16) ushort Vt[32][488];    // 30.5 KB

    int h = blockIdx.x, b = blockIdx.y;
    int tid = threadIdx.x;
    int wave = tid >> 6, lane = tid & 63;
    int fr = lane & 15, fq = lane >> 4;
    const float scale2 = 0.17677669529663687f * 1.4426950408889634f;
    float slope2 = ((h < 4) ? 1.0f : 0.5f) * 1.4426950408889634f;
    const ushort* base = qkv + (size_t)b * L_ * 768;

    for (int j = tid >> 2; j < 464; j += 128) {
        int c8 = (tid & 3) * 8;
        uint4 u = make_uint4(0u, 0u, 0u, 0u);
        if (j < L_) u = *(const uint4*)(base + (size_t)j * 768 + 256 + h * 32 + c8);
        *(uint4*)&Ks[j][c8] = u;
    }
    for (int m = wave; m < 32; m += 8) {
        int dg = (m >> 3) * 8, jb = m & 7;
        int j = jb * 64 + lane;
        uint4 u = make_uint4(0u, 0u, 0u, 0u);
        if (j < L_) u = *(const uint4*)(base + (size_t)j * 768 + 512 + h * 32 + dg);
        if (j < 488) {
            const ushort* pu = (const ushort*)&u;
#pragma unroll
            for (int e = 0; e < 8; ++e) Vt[dg + e][j] = pu[e];
        }
    }
    __syncthreads();

    for (int pr = wave; pr < 15; pr += 8) {
        int q0 = pr * 32;
        int twoB = (pr < 14);
        uint4 quA = *(const uint4*)(base + (size_t)(q0 + fr) * 768 + h * 32 + fq * 8);
        v8bf qfA = *(v8bf*)&quA;
        uint4 quB = *(const uint4*)(base + (size_t)(q0 + 16 + fr) * 768 + h * 32 + fq * 8);
        v8bf qfB = *(v8bf*)&quB;
        float fqAq = (float)(q0 + fr);
        float fqBq = fqAq + 16.0f;
        float psA = 0.f, psB = 0.f;
        v4f oA0 = (v4f)0.0f, oA1 = (v4f)0.0f, oB0 = (v4f)0.0f, oB1 = (v4f)0.0f;

        for (int kc = 0; kc < 14; ++kc) {
            int kb = kc * 32;
            v8bf kf0 = *(const v8bf*)&Ks[kb + fr][fq * 8];
            v8bf kf1 = *(const v8bf*)&Ks[kb + 16 + fr][fq * 8];
            uint2 va0 = *(const uint2*)&Vt[fr][kb + fq * 4];
            uint2 va1 = *(const uint2*)&Vt[16 + fr][kb + fq * 4];
            uint2 vb0 = *(const uint2*)&Vt[fr][kb + 16 + fq * 4];
            uint2 vb1 = *(const uint2*)&Vt[16 + fr][kb + 16 + fq * 4];
            float ke = (float)(kb + 4 * fq);

            v4f dA0 = (v4f)0.0f, dA1 = (v4f)0.0f;
            dA0 = __builtin_amdgcn_mfma_f32_16x16x32_bf16(kf0, qfA, dA0, 0, 0, 0);
            dA1 = __builtin_amdgcn_mfma_f32_16x16x32_bf16(kf1, qfA, dA1, 0, 0, 0);
            {
                float dl0 = fqAq - ke, dl1 = dl0 - 16.0f;
                float pe[4], po[4];
#pragma unroll
                for (int r = 0; r < 4; ++r) {
                    pe[r] = exp2f(fmaf(dA0[r], scale2, -slope2 * fabsf(dl0 - (float)r)));
                    po[r] = exp2f(fmaf(dA1[r], scale2, -slope2 * fabsf(dl1 - (float)r)));
                    psA += pe[r] + po[r];
                }
                uint2 ue, uo;
                ue.x = pack_bf2(pe[0], pe[1]); ue.y = pack_bf2(pe[2], pe[3]);
                uo.x = pack_bf2(po[0], po[1]); uo.y = pack_bf2(po[2], po[3]);
                oA0 = mfma16(va0, ue, oA0);
                oA1 = mfma16(va1, ue, oA1);
                oA0 = mfma16(vb0, uo, oA0);
                oA1 = mfma16(vb1, uo, oA1);
            }
            if (twoB) {
                v4f dB0 = (v4f)0.0f, dB1 = (v4f)0.0f;
                dB0 = __builtin_amdgcn_mfma_f32_16x16x32_bf16(kf0, qfB, dB0, 0, 0, 0);
                dB1 = __builtin_amdgcn_mfma_f32_16x16x32_bf16(kf1, qfB, dB1, 0, 0, 0);
                float dl0 = fqBq - ke, dl1 = dl0 - 16.0f;
                float pe[4], po[4];
#pragma unroll
                for (int r = 0; r < 4; ++r) {
                    pe[r] = exp2f(fmaf(dB0[r], scale2, -slope2 * fabsf(dl0 - (float)r)));
                    po[r] = exp2f(fmaf(dB1[r], scale2, -slope2 * fabsf(dl1 - (float)r)));
                    psB += pe[r] + po[r];
                }
                uint2 ue, uo;
                ue.x = pack_bf2(pe[0], pe[1]); ue.y = pack_bf2(pe[2], pe[3]);
                uo.x = pack_bf2(po[0], po[1]); uo.y = pack_bf2(po[2], po[3]);
                oB0 = mfma16(va0, ue, oB0);
                oB1 = mfma16(va1, ue, oB1);
                oB0 = mfma16(vb0, uo, oB0);
                oB1 = mfma16(vb1, uo, oB1);
            }
        }
        // tail: k 448..463
        {
            v8bf kf0 = *(const v8bf*)&Ks[448 + fr][fq * 8];
            uint2 va0 = *(const uint2*)&Vt[fr][448 + fq * 4];
            uint2 va1 = *(const uint2*)&Vt[16 + fr][448 + fq * 4];
            v4f dA0 = (v4f)0.0f;
            dA0 = __builtin_amdgcn_mfma_f32_16x16x32_bf16(kf0, qfA, dA0, 0, 0, 0);
            float pe[4];
#pragma unroll
            for (int r = 0; r < 4; ++r) {
                int k = 448 + 4 * fq + r;
                pe[r] = (k < L_)
                    ? exp2f(fmaf(dA0[r], scale2, -slope2 * fabsf(fqAq - (float)k))) : 0.f;
                psA += pe[r];
            }
            uint2 ue;
            ue.x = pack_bf2(pe[0], pe[1]); ue.y = pack_bf2(pe[2], pe[3]);
            oA0 = mfma16(va0, ue, oA0);
            oA1 = mfma16(va1, ue, oA1);
            if (twoB) {
                v4f dB0 = (v4f)0.0f;
                dB0 = __builtin_amdgcn_mfma_f32_16x16x32_bf16(kf0, qfB, dB0, 0, 0, 0);
                float pf[4];
#pragma unroll
                for (int r = 0; r < 4; ++r) {
                    int k = 448 + 4 * fq + r;
                    pf[r] = (k < L_)
                        ? exp2f(fmaf(dB0[r], scale2, -slope2 * fabsf(fqBq - (float)k))) : 0.f;
                    psB += pf[r];
                }
                uint2 ub;
                ub.x = pack_bf2(pf[0], pf[1]); ub.y = pack_bf2(pf[2], pf[3]);
                oB0 = mfma16(va0, ub, oB0);
                oB1 = mfma16(va1, ub, oB1);
            }
        }

        psA += __shfl_xor(psA, 16);
        psA += __shfl_xor(psA, 32);
        psB += __shfl_xor(psB, 16);
        psB += __shfl_xor(psB, 32);
        {
            int q = q0 + fr;
            if (q < L_) {
                float inv = 1.0f / psA;
                uint2 w0, w1;
                w0.x = pack_bf2(oA0[0] * inv, oA0[1] * inv);
                w0.y = pack_bf2(oA0[2] * inv, oA0[3] * inv);
                w1.x = pack_bf2(oA1[0] * inv, oA1[1] * inv);
                w1.y = pack_bf2(oA1[2] * inv, oA1[3] * inv);
                ushort* op = out + (size_t)(b * L_ + q) * D_ + h * 32;
                *(uint2*)(op + fq * 4) = w0;
                *(uint2*)(op + 16 + fq * 4) = w1;
            }
        }
        if (twoB) {
            int q = q0 + 16 + fr;
            if (q < L_) {
                float inv = 1.0f / psB;
                uint2 w0, w1;
                w0.x = pack_bf2(oB0[0] * inv, oB0[1] * inv);
                w0.y = pack_bf2(oB0[2] * inv, oB0[3] * inv);
                w1.x = pack_bf2(oB1[0] * inv, oB1[1] * inv);
                w1.y = pack_bf2(oB1[2] * inv, oB1[3] * inv);
                ushort* op = out + (size_t)(b * L_ + q) * D_ + h * 32;
                *(uint2*)(op + fq * 4) = w0;
                *(uint2*)(op + 16 + fq * 4) = w1;
            }
        }
    }
}

// ---------------------------------------------------------------------------
// Fused residual+LN, all-bf16 streams: Xb <- LN(Xb + AOb). fp32 math inside.
// wave per row, shuffle-only, 4 rows/block.
// ---------------------------------------------------------------------------
__global__ __launch_bounds__(256) void ln_kernel(
    const ushort* __restrict__ res, const ushort* __restrict__ y,
    const float* __restrict__ g, const float* __restrict__ bb,
    ushort* __restrict__ xbout)
{
    int row = blockIdx.x * 4 + (threadIdx.x >> 6);
    int lane = threadIdx.x & 63;
    size_t off = (size_t)row * D_ + lane * 4;
    ushort4 rv4 = *(const ushort4*)(res + off);
    ushort4 yv4 = *(const ushort4*)(y + off);
    float4 v;
    v.x = bu2f(rv4.x) + bu2f(yv4.x);
    v.y = bu2f(rv4.y) + bu2f(yv4.y);
    v.z = bu2f(rv4.z) + bu2f(yv4.z);
    v.w = bu2f(rv4.w) + bu2f(yv4.w);

    float s = v.x + v.y + v.z + v.w;
#pragma unroll
    for (int o = 1; o < 64; o <<= 1) s += __shfl_xor(s, o);
    float mean = s * (1.0f / 256.0f);

    float4 d;
    d.x = v.x - mean; d.y = v.y - mean; d.z = v.z - mean; d.w = v.w - mean;
    float sq = d.x * d.x + d.y * d.y + d.z * d.z + d.w * d.w;
#pragma unroll
    for (int o = 1; o < 64; o <<= 1) sq += __shfl_xor(sq, o);
    float rstd = rsqrtf(sq * (1.0f / 256.0f) + 1e-5f);

    float4 gv = *(const float4*)(g + lane * 4);
    float4 bv = *(const float4*)(bb + lane * 4);
    ushort4 hb;
    hb.x = f2bu(d.x * rstd * gv.x + bv.x);
    hb.y = f2bu(d.y * rstd * gv.y + bv.y);
    hb.z = f2bu(d.z * rstd * gv.z + bv.z);
    hb.w = f2bu(d.w * rstd * gv.w + bv.w);
    *(ushort4*)(xbout + off) = hb;
}

// ---------------------------------------------------------------------------
// head1 via MFMA: SCp[row] = gelu(bn(Xb@th1_w + b1)) @ th2_w + b2.
// ---------------------------------------------------------------------------
__global__ __launch_bounds__(256) void head1_kernel(
    const ushort* __restrict__ Xb, const ushort* __restrict__ th1T,
    const float* __restrict__ b1, const float* __restrict__ bng,
    const float* __restrict__ bnb, const float* __restrict__ w2,
    const float* __restrict__ b2, float* __restrict__ SCp)
{
    __shared__ ushort As[128 * 32];
    __shared__ ushort Bs[32 * 264];
    int tid = threadIdx.x;
    int wave = tid >> 6, lane = tid & 63;
    int fr = lane & 15, fq = lane >> 4;
    int rowblk = blockIdx.x * 128;
    int scol = fq ^ (lane & 3) ^ ((lane >> 2) & 1);

    for (int i = tid; i < 1024; i += 256) {
        int r = i >> 5, c8 = (i & 31) * 8;
        *(uint4*)&Bs[r * 264 + c8] = *(const uint4*)(th1T + r * 256 + c8);
    }

    int c0 = wave * 64 + lane;
    int r0 = c0 >> 2, k0g = (c0 & 3) ^ (r0 & 3) ^ ((r0 >> 2) & 1);
    int c1 = 256 + c0;
    int r1 = c1 >> 2, k1g = (c1 & 3) ^ (r1 & 3) ^ ((r1 >> 2) & 1);
    const ushort* Ag0 = Xb + (size_t)(rowblk + r0) * 256 + k0g * 8;
    const ushort* Ag1 = Xb + (size_t)(rowblk + r1) * 256 + k1g * 8;
    ushort* lA0 = As + (size_t)(wave * 64) * 8;
    ushort* lA1 = As + (size_t)(256 + wave * 64) * 8;

    v4f acc[2][2];
#pragma unroll
    for (int i = 0; i < 2; ++i)
#pragma unroll
        for (int j = 0; j < 2; ++j) acc[i][j] = (v4f)0.0f;

    for (int kt = 0; kt < 256; kt += 32) {
        gload16(Ag0 + kt, lA0);
        gload16(Ag1 + kt, lA1);
        __syncthreads();
        v8bf a[2], bfr[2];
#pragma unroll
        for (int mi = 0; mi < 2; ++mi)
            a[mi] = *(const v8bf*)(As + (size_t)((wave * 2 + mi) * 16 + fr) * 32 + scol * 8);
#pragma unroll
        for (int ni = 0; ni < 2; ++ni)
            bfr[ni] = *(const v8bf*)(Bs + (size_t)(ni * 16 + fr) * 264 + kt + fq * 8);
#pragma unroll
        for (int mi = 0; mi < 2; ++mi)
#pragma unroll
            for (int ni = 0; ni < 2; ++ni)
                acc[mi][ni] = __builtin_amdgcn_mfma_f32_16x16x32_bf16(
                    a[mi], bfr[ni], acc[mi][ni], 0, 0, 0);
        __syncthreads();
    }

    const float bnr = 0.9999950000374997f;  // rsqrt(1+1e-5)
    float b1v[2], bsv[2], bbv[2], w2v[2];
#pragma unroll
    for (int ni = 0; ni < 2; ++ni) {
        int j = ni * 16 + fr;
        b1v[ni] = b1[j];
        bsv[ni] = bng[j] * bnr;
        bbv[ni] = bnb[j];
        w2v[ni] = w2[j];
    }
    const float gc = 0.7978845608028654f;
    float b2v = b2[0];
#pragma unroll
    for (int mi = 0; mi < 2; ++mi) {
#pragma unroll
        for (int r = 0; r < 4; ++r) {
            float s = 0.f;
#pragma unroll
            for (int ni = 0; ni < 2; ++ni) {
                float hb = (acc[mi][ni][r] + b1v[ni]) * bsv[ni] + bbv[ni];
                float t = tanhf(gc * (hb + 0.044715f * hb * hb * hb));
                s += 0.5f * hb * (1.0f + t) * w2v[ni];
            }
#pragma unroll
            for (int o = 1; o < 16; o <<= 1) s += __shfl_xor(s, o);
            int row = rowblk + (wave * 2 + mi) * 16 + fq * 4 + r;
            if (fr == 0 && row < B_ * L_) SCp[row] = s + b2v;
        }
    }
}

// ---------------------------------------------------------------------------
// head2: block (colgroup, b); 64 cols x 4 L-partitions per block. Pools bf16 Xb.
// ---------------------------------------------------------------------------
__global__ __launch_bounds__(256) void head2_kernel(
    const float* __restrict__ SCp, const ushort* __restrict__ Xb,
    float* __restrict__ outp)
{
    int cg = blockIdx.x, b = blockIdx.y;
    int tid = threadIdx.x;
    __shared__ float wbuf[L_];
    __shared__ float r1[4], r2[4];
    __shared__ float part[4][64];
    const float* s = SCp + (size_t)b * L_;

    float m = -1e30f;
    for (int j = tid; j < L_; j += 256) m = fmaxf(m, s[j]);
#pragma unroll
    for (int o = 1; o < 64; o <<= 1) m = fmaxf(m, __shfl_xor(m, o));
    if ((tid & 63) == 0) r1[tid >> 6] = m;
    __syncthreads();
    m = fmaxf(fmaxf(r1[0], r1[1]), fmaxf(r1[2], r1[3]));

    float sum = 0.f;
    for (int j = tid; j < L_; j += 256) {
        float e = __expf(s[j] - m);
        wbuf[j] = e;
        sum += e;
    }
#pragma unroll
    for (int o = 1; o < 64; o <<= 1) sum += __shfl_xor(sum, o);
    if ((tid & 63) == 0) r2[tid >> 6] = sum;
    __syncthreads();
    float inv = 1.0f / (r2[0] + r2[1] + r2[2] + r2[3]);

    int c = tid & 63, pt = tid >> 6;
    int col = cg * 64 + c;
    float acc = 0.f;
    const ushort* xb = Xb + (size_t)b * L_ * D_ + col;
    for (int l = pt; l < L_; l += 4) acc += wbuf[l] * bu2f(xb[(size_t)l * D_]);
    part[pt][c] = acc;
    __syncthreads();
    if (pt == 0)
        outp[b * D_ + col] = (part[0][c] + part[1][c] + part[2][c] + part[3][c]) * inv;
}

// ---------------------------------------------------------------------------
extern "C" void kernel_launch(void* const* d_in, const int* in_sizes, int n_in,
                              void* d_out, int out_size, void* d_ws, size_t ws_size,
                              hipStream_t stream)
{
    const float* gene   = (const float*)d_in[0];
    const float* coords = (const float*)d_in[1];
    const float* w_in   = (const float*)d_in[2];
    const float* b_in   = (const float*)d_in[3];
    const float* w_cls  = (const float*)d_in[4];
    const float* b_cls  = (const float*)d_in[5];
    const float* qkv_w  = (const float*)d_in[6];
    const float* qkv_b  = (const float*)d_in[7];
    const float* ln1_g  = (const float*)d_in[8];
    const float* ln1_b  = (const float*)d_in[9];
    const float* ffn_w1 = (const float*)d_in[10];
    const float* ffn_b1 = (const float*)d_in[11];
    const float* ffn_w2 = (const float*)d_in[12];
    const float* ffn_b2 = (const float*)d_in[13];
    const float* ln2_g  = (const float*)d_in[14];
    const float* ln2_b  = (const float*)d_in[15];
    const float* th1_w  = (const float*)d_in[16];
    const float* th1_b  = (const float*)d_in[17];
    const float* bn_g   = (const float*)d_in[18];
    const float* bn_b   = (const float*)d_in[19];
    const float* th2_w  = (const float*)d_in[20];
    const float* th2_b  = (const float*)d_in[21];
    float* out = (float*)d_out;

    const int ROWS = B_ * L_;   // 29248
    char* p = (char*)d_ws;
    ushort* AOb  = (ushort*)p; p += (size_t)MPAD * 256 * 2;
    ushort* Xb   = (ushort*)p; p += (size_t)MPAD * 256 * 2;
    ushort* SH   = (ushort*)p; p += (size_t)MPAD * 1024 * 2;
    ushort* qkvT = (ushort*)p; p += (size_t)NL_ * 768 * 256 * 2;
    ushort* w1T  = (ushort*)p; p += (size_t)NL_ * 1024 * 256 * 2;
    ushort* w2T  = (ushort*)p; p += (size_t)NL_ * 256 * 1024 * 2;
    ushort* th1T = (ushort*)p; p += (size_t)32 * 256 * 2;
    float*  SCp  = (float*)p;  p += (size_t)ROWS * 4;

    wcast_kernel<<<dim3(768 / 32, 256 / 32, NL_), dim3(32, 8), 0, stream>>>(qkv_w, qkvT, 256, 768);
    wcast_kernel<<<dim3(1024 / 32, 256 / 32, NL_), dim3(32, 8), 0, stream>>>(ffn_w1, w1T, 256, 1024);
    wcast_kernel<<<dim3(256 / 32, 1024 / 32, NL_), dim3(32, 8), 0, stream>>>(ffn_w2, w2T, 1024, 256);
    wcast_kernel<<<dim3(1, 8, 1), dim3(32, 8), 0, stream>>>(th1_w, th1T, 256, 32);

    sgemm_kernel<<<dim3(D_ / 64, (B_ * NT_) / 64), 256, 0, stream>>>(
        gene, w_in, b_in, Xb, B_ * NT_, D_, TOK_);
    cls_kernel<<<B_, 256, 0, stream>>>(coords, w_cls, b_cls, Xb);

    for (int l = 0; l < NL_; ++l) {
        mfma_gemm<<<dim3(768 / 128, MPAD / 128), 256, 0, stream>>>(
            Xb, qkvT + (size_t)l * 768 * 256, qkv_b + l * 768, SH, 768, 256, 0, 1);
        attn_kernel<<<dim3(H_, B_), 512, 0, stream>>>(SH, AOb);
        ln_kernel<<<ROWS / 4, 256, 0, stream>>>(Xb, AOb, ln1_g + l * D_, ln1_b + l * D_, Xb);
        mfma_gemm<<<dim3(1024 / 128, MPAD / 128), 256, 0, stream>>>(
            Xb, w1T + (size_t)l * 1024 * 256, ffn_b1 + l * 1024, SH, 1024, 256, 1, 1);
        mfma_gemm<<<dim3(256 / 128, MPAD / 128), 256, 0, stream>>>(
            SH, w2T + (size_t)l * 256 * 1024, ffn_b2 + l * D_, AOb, 256, 1024, 0, 1);
        ln_kernel<<<ROWS / 4, 256, 0, stream>>>(Xb, AOb, ln2_g + l * D_, ln2_b + l * D_, Xb);
    }

    head1_kernel<<<MPAD / 128, 256, 0, stream>>>(
        Xb, th1T, th1_b, bn_g, bn_b, th2_w, th2_b, SCp);
    head2_kernel<<<dim3(4, B_), 256, 0, stream>>>(SCp, Xb, out);
}

// Round 14
// 838.530 us; speedup vs baseline: 1.4056x; 1.1171x over previous
//
#include <hip/hip_runtime.h>
#include <math.h>

#define B_   64
#define TOK_ 64
#define NT_  456
#define L_   457
#define D_   256
#define H_   8
#define HD_  32
#define FF_  1024
#define NL_  4
#define PH_  32
#define MPAD 29312   // 229 * 128 (rows padded for 128-row GEMM tiles)

typedef unsigned int uint;
typedef unsigned short ushort;
typedef __bf16 v8bf __attribute__((ext_vector_type(8)));
typedef __bf16 v4bf __attribute__((ext_vector_type(4)));
typedef short v4s __attribute__((ext_vector_type(4)));
typedef float v4f __attribute__((ext_vector_type(4)));

__device__ __forceinline__ float bu2f(ushort x) {
    return __uint_as_float(((uint)x) << 16);
}
__device__ __forceinline__ ushort f2bu(float f) {
    union { float f; uint u; } x; x.f = f;
    uint r = (x.u + 0x7fffu + ((x.u >> 16) & 1u)) >> 16;
    return (ushort)r;
}
__device__ __forceinline__ uint pack_bf2(float a, float b) {
#if defined(__HIP_DEVICE_COMPILE__) && __has_builtin(__builtin_amdgcn_cvt_pk_bf16_f32)
    typedef __bf16 bf2v __attribute__((ext_vector_type(2)));
    bf2v v = __builtin_amdgcn_cvt_pk_bf16_f32(a, b);
    return *(uint*)&v;
#else
    return (uint)f2bu(a) | ((uint)f2bu(b) << 16);
#endif
}

// K=16 bf16 MFMA (PV with register-resident P). Guarded for the host pass.
__device__ __forceinline__ v4f mfma16(uint2 a, uint2 b, v4f c) {
#if defined(__HIP_DEVICE_COMPILE__)
#if __has_builtin(__builtin_amdgcn_mfma_f32_16x16x16_bf16)
    return __builtin_amdgcn_mfma_f32_16x16x16_bf16(*(v4bf*)&a, *(v4bf*)&b, c, 0, 0, 0);
#else
    return __builtin_amdgcn_mfma_f32_16x16x16bf16_1k(*(v4s*)&a, *(v4s*)&b, c, 0, 0, 0);
#endif
#else
    (void)a; (void)b;
    return c;
#endif
}

// async global->LDS 16B copy; lds base wave-uniform, data at base + lane*16.
__device__ __forceinline__ void gload16(const void* g, void* l) {
    __builtin_amdgcn_global_load_lds(
        (const __attribute__((address_space(1))) void*)(unsigned long long)(uintptr_t)g,
        (__attribute__((address_space(3))) void*)(uint)(uintptr_t)l,
        16, 0, 0);
}

// ---------------------------------------------------------------------------
// bf16 MFMA GEMM, BK=64: C[M,N] = A[M,K]·W^T[N,K] + bias. 128x128 tile,
// 4 waves (2x2). K%64==0. LDS 32 KB. Flat-granule layout with XOR swizzle.
// ---------------------------------------------------------------------------
__global__ __launch_bounds__(256) void mfma_gemm(
    const ushort* __restrict__ A, const ushort* __restrict__ WT,
    const float* __restrict__ bias, void* __restrict__ Cout,
    int N, int K, int relu, int obf16)
{
    __shared__ ushort As[128 * 64];
    __shared__ ushort Bs[128 * 64];
    int tid = threadIdx.x;
    int wave = tid >> 6, lane = tid & 63;
    int colblk = blockIdx.x * 128;
    int rowblk = blockIdx.y * 128;
    int wm = wave >> 1, wn = wave & 1;
    int fr = lane & 15, fq = lane >> 4;

    v4f acc[4][4];
#pragma unroll
    for (int i = 0; i < 4; ++i)
#pragma unroll
        for (int j = 0; j < 4; ++j) acc[i][j] = (v4f)0.0f;

    const ushort* Ag[4];
    const ushort* Bg[4];
    ushort* lA[4];
    ushort* lB[4];
#pragma unroll
    for (int p = 0; p < 4; ++p) {
        int c = p * 256 + wave * 64 + lane;
        int r = c >> 3, gs = (c & 7) ^ (r & 7);
        Ag[p] = A + (size_t)(rowblk + r) * K + gs * 8;
        Bg[p] = WT + (size_t)(colblk + r) * K + gs * 8;
        lA[p] = As + (size_t)(p * 256 + wave * 64) * 8;
        lB[p] = Bs + (size_t)(p * 256 + wave * 64) * 8;
    }

    for (int kt = 0; kt < K; kt += 64) {
#pragma unroll
        for (int p = 0; p < 4; ++p) gload16(Ag[p] + kt, lA[p]);
#pragma unroll
        for (int p = 0; p < 4; ++p) gload16(Bg[p] + kt, lB[p]);
        __syncthreads();

#pragma unroll
        for (int ks = 0; ks < 2; ++ks) {
            int pa = (ks * 4 + fq) ^ (fr & 7);
            v8bf a[4], b[4];
#pragma unroll
            for (int mi = 0; mi < 4; ++mi) {
                int rl = wm * 64 + mi * 16 + fr;
                a[mi] = *(const v8bf*)(As + (size_t)(rl * 8 + pa) * 8);
            }
#pragma unroll
            for (int ni = 0; ni < 4; ++ni) {
                int rl = wn * 64 + ni * 16 + fr;
                b[ni] = *(const v8bf*)(Bs + (size_t)(rl * 8 + pa) * 8);
            }
#pragma unroll
            for (int mi = 0; mi < 4; ++mi)
#pragma unroll
                for (int ni = 0; ni < 4; ++ni)
                    acc[mi][ni] = __builtin_amdgcn_mfma_f32_16x16x32_bf16(
                        a[mi], b[ni], acc[mi][ni], 0, 0, 0);
        }
        __syncthreads();
    }

#pragma unroll
    for (int ni = 0; ni < 4; ++ni) {
        int col = colblk + wn * 64 + ni * 16 + fr;
        float bv = bias[col];
#pragma unroll
        for (int mi = 0; mi < 4; ++mi) {
            int row = rowblk + wm * 64 + mi * 16 + fq * 4;
#pragma unroll
            for (int r = 0; r < 4; ++r) {
                float v = acc[mi][ni][r] + bv;
                if (relu) v = fmaxf(v, 0.f);
                if (obf16)
                    ((ushort*)Cout)[(size_t)(row + r) * N + col] = f2bu(v);
                else
                    ((float*)Cout)[(size_t)(row + r) * N + col] = v;
            }
        }
    }
}

// ---------------------------------------------------------------------------
__global__ __launch_bounds__(256) void wcast_kernel(
    const float* __restrict__ W, ushort* __restrict__ WT, int K, int N)
{
    __shared__ float t[32][33];
    const float* Wl = W + (size_t)blockIdx.z * K * N;
    ushort* WTl = WT + (size_t)blockIdx.z * K * N;
    int n0 = blockIdx.x * 32, k0 = blockIdx.y * 32;
    int tx = threadIdx.x, ty = threadIdx.y;
#pragma unroll
    for (int r = 0; r < 32; r += 8)
        t[ty + r][tx] = Wl[(size_t)(k0 + ty + r) * N + n0 + tx];
    __syncthreads();
#pragma unroll
    for (int r = 0; r < 32; r += 8)
        WTl[(size_t)(n0 + ty + r) * K + k0 + tx] = f2bu(t[tx][ty + r]);
}

// ---------------------------------------------------------------------------
// fp32 SGEMM for the embed GEMM only; row-remap; writes bf16 Xb only.
// ---------------------------------------------------------------------------
__global__ __launch_bounds__(256) void sgemm_kernel(
    const float* __restrict__ A, const float* __restrict__ W,
    const float* __restrict__ bias, ushort* __restrict__ Cb,
    int M, int N, int K)
{
    __shared__ float As_[16][64];
    __shared__ float Bs_[16][64];
    int tid = threadIdx.x;
    int rowblk = blockIdx.y * 64;
    int colblk = blockIdx.x * 64;
    int a_row = tid & 63, a_q = tid >> 6;
    int b_kr = tid >> 4, b_cg = tid & 15;
    int rm = tid >> 4, cn = tid & 15;
    float acc[4][4] = {};
    const float* Aptr = A + (size_t)(rowblk + a_row) * K;
    for (int kt = 0; kt < K; kt += 16) {
        float4 av = *(const float4*)(Aptr + kt + a_q * 4);
        float4 bv = *(const float4*)(W + (size_t)(kt + b_kr) * N + colblk + b_cg * 4);
        As_[a_q * 4 + 0][a_row] = av.x;
        As_[a_q * 4 + 1][a_row] = av.y;
        As_[a_q * 4 + 2][a_row] = av.z;
        As_[a_q * 4 + 3][a_row] = av.w;
        *(float4*)&Bs_[b_kr][b_cg * 4] = bv;
        __syncthreads();
#pragma unroll
        for (int kk = 0; kk < 16; ++kk) {
            float4 a4 = *(const float4*)&As_[kk][rm * 4];
            float4 b4 = *(const float4*)&Bs_[kk][cn * 4];
            float ar[4] = {a4.x, a4.y, a4.z, a4.w};
            float br[4] = {b4.x, b4.y, b4.z, b4.w};
#pragma unroll
            for (int i = 0; i < 4; ++i)
#pragma unroll
                for (int j = 0; j < 4; ++j) acc[i][j] += ar[i] * br[j];
        }
        __syncthreads();
    }
    float4 bv = *(const float4*)(bias + colblk + cn * 4);
    float bb[4] = {bv.x, bv.y, bv.z, bv.w};
#pragma unroll
    for (int i = 0; i < 4; ++i) {
        int grow = rowblk + rm * 4 + i;
        size_t orow = (size_t)(grow + grow / NT_ + 1);
        ushort4 h;
        h.x = f2bu(acc[i][0] + bb[0]);
        h.y = f2bu(acc[i][1] + bb[1]);
        h.z = f2bu(acc[i][2] + bb[2]);
        h.w = f2bu(acc[i][3] + bb[3]);
        *(ushort4*)(Cb + orow * N + colblk + cn * 4) = h;
    }
}

__global__ __launch_bounds__(256) void cls_kernel(
    const float* __restrict__ coords, const float* __restrict__ w_cls,
    const float* __restrict__ b_cls, ushort* __restrict__ Xb)
{
    int b = blockIdx.x;
    int t = threadIdx.x;
    float c0 = coords[b * 3 + 0], c1 = coords[b * 3 + 1], c2 = coords[b * 3 + 2];
    float v = c0 * w_cls[t] + c1 * w_cls[D_ + t] + c2 * w_cls[2 * D_ + t] + b_cls[t];
    Xb[(size_t)b * L_ * D_ + t] = f2bu(v);
}

// ---------------------------------------------------------------------------
// MFMA attention v7 (banded alibi): one block per (b,h), 512 threads.
// alibi decay makes P(q,k) < e^{-50} outside |q-k| <= W (W=80 slope-1 heads,
// 112 slope-0.5 heads; score spread <= ~4) -> skip those k-chunks entirely.
// Exact at bf16 output precision. K/V^T staged once (full range; bands of
// all q overlap). Dual 16-row q-tiles per pass; exp2 softmax; PV via mfma16.
// O-stores guarded q<L.
// ---------------------------------------------------------------------------
__global__ __launch_bounds__(512) void attn_kernel(
    const ushort* __restrict__ qkv, ushort* __restrict__ out)
{
    __shared__ __align__(16) ushort Ks[464][40];    // 36.3 KB
    __shared__ __align__(16) ushort Vt[32][488];    // 30.5 KB

    int h = blockIdx.x, b = blockIdx.y;
    int tid = threadIdx.x;
    int wave = tid >> 6, lane = tid & 63;
    int fr = lane & 15, fq = lane >> 4;
    const float scale2 = 0.17677669529663687f * 1.4426950408889634f;
    float slope2 = ((h < 4) ? 1.0f : 0.5f) * 1.4426950408889634f;
    int W = (h < 4) ? 80 : 112;   // band half-width (wave-uniform)
    const ushort* base = qkv + (size_t)b * L_ * 768;

    for (int j = tid >> 2; j < 464; j += 128) {
        int c8 = (tid & 3) * 8;
        uint4 u = make_uint4(0u, 0u, 0u, 0u);
        if (j < L_) u = *(const uint4*)(base + (size_t)j * 768 + 256 + h * 32 + c8);
        *(uint4*)&Ks[j][c8] = u;
    }
    for (int m = wave; m < 32; m += 8) {
        int dg = (m >> 3) * 8, jb = m & 7;
        int j = jb * 64 + lane;
        uint4 u = make_uint4(0u, 0u, 0u, 0u);
        if (j < L_) u = *(const uint4*)(base + (size_t)j * 768 + 512 + h * 32 + dg);
        if (j < 488) {
            const ushort* pu = (const ushort*)&u;
#pragma unroll
            for (int e = 0; e < 8; ++e) Vt[dg + e][j] = pu[e];
        }
    }
    __syncthreads();

    for (int pr = wave; pr < 15; pr += 8) {
        int q0 = pr * 32;
        int twoB = (pr < 14);
        int kclo = max(0, (q0 - W) >> 5);
        int kchi = min(13, (q0 + 31 + W) >> 5);      // last full 32-chunk
        int doTail = (q0 + 31 + W >= 448);
        uint4 quA = *(const uint4*)(base + (size_t)(q0 + fr) * 768 + h * 32 + fq * 8);
        v8bf qfA = *(v8bf*)&quA;
        uint4 quB = *(const uint4*)(base + (size_t)(q0 + 16 + fr) * 768 + h * 32 + fq * 8);
        v8bf qfB = *(v8bf*)&quB;
        float fqAq = (float)(q0 + fr);
        float fqBq = fqAq + 16.0f;
        float psA = 0.f, psB = 0.f;
        v4f oA0 = (v4f)0.0f, oA1 = (v4f)0.0f, oB0 = (v4f)0.0f, oB1 = (v4f)0.0f;

        for (int kc = kclo; kc <= kchi; ++kc) {
            int kb = kc * 32;
            v8bf kf0 = *(const v8bf*)&Ks[kb + fr][fq * 8];
            v8bf kf1 = *(const v8bf*)&Ks[kb + 16 + fr][fq * 8];
            uint2 va0 = *(const uint2*)&Vt[fr][kb + fq * 4];
            uint2 va1 = *(const uint2*)&Vt[16 + fr][kb + fq * 4];
            uint2 vb0 = *(const uint2*)&Vt[fr][kb + 16 + fq * 4];
            uint2 vb1 = *(const uint2*)&Vt[16 + fr][kb + 16 + fq * 4];
            float ke = (float)(kb + 4 * fq);

            v4f dA0 = (v4f)0.0f, dA1 = (v4f)0.0f;
            dA0 = __builtin_amdgcn_mfma_f32_16x16x32_bf16(kf0, qfA, dA0, 0, 0, 0);
            dA1 = __builtin_amdgcn_mfma_f32_16x16x32_bf16(kf1, qfA, dA1, 0, 0, 0);
            {
                float dl0 = fqAq - ke, dl1 = dl0 - 16.0f;
                float pe[4], po[4];
#pragma unroll
                for (int r = 0; r < 4; ++r) {
                    pe[r] = exp2f(fmaf(dA0[r], scale2, -slope2 * fabsf(dl0 - (float)r)));
                    po[r] = exp2f(fmaf(dA1[r], scale2, -slope2 * fabsf(dl1 - (float)r)));
                    psA += pe[r] + po[r];
                }
                uint2 ue, uo;
                ue.x = pack_bf2(pe[0], pe[1]); ue.y = pack_bf2(pe[2], pe[3]);
                uo.x = pack_bf2(po[0], po[1]); uo.y = pack_bf2(po[2], po[3]);
                oA0 = mfma16(va0, ue, oA0);
                oA1 = mfma16(va1, ue, oA1);
                oA0 = mfma16(vb0, uo, oA0);
                oA1 = mfma16(vb1, uo, oA1);
            }
            if (twoB) {
                v4f dB0 = (v4f)0.0f, dB1 = (v4f)0.0f;
                dB0 = __builtin_amdgcn_mfma_f32_16x16x32_bf16(kf0, qfB, dB0, 0, 0, 0);
                dB1 = __builtin_amdgcn_mfma_f32_16x16x32_bf16(kf1, qfB, dB1, 0, 0, 0);
                float dl0 = fqBq - ke, dl1 = dl0 - 16.0f;
                float pe[4], po[4];
#pragma unroll
                for (int r = 0; r < 4; ++r) {
                    pe[r] = exp2f(fmaf(dB0[r], scale2, -slope2 * fabsf(dl0 - (float)r)));
                    po[r] = exp2f(fmaf(dB1[r], scale2, -slope2 * fabsf(dl1 - (float)r)));
                    psB += pe[r] + po[r];
                }
                uint2 ue, uo;
                ue.x = pack_bf2(pe[0], pe[1]); ue.y = pack_bf2(pe[2], pe[3]);
                uo.x = pack_bf2(po[0], po[1]); uo.y = pack_bf2(po[2], po[3]);
                oB0 = mfma16(va0, ue, oB0);
                oB1 = mfma16(va1, ue, oB1);
                oB0 = mfma16(vb0, uo, oB0);
                oB1 = mfma16(vb1, uo, oB1);
            }
        }
        // tail chunk: k 448..463 (only if band reaches it)
        if (doTail) {
            v8bf kf0 = *(const v8bf*)&Ks[448 + fr][fq * 8];
            uint2 va0 = *(const uint2*)&Vt[fr][448 + fq * 4];
            uint2 va1 = *(const uint2*)&Vt[16 + fr][448 + fq * 4];
            v4f dA0 = (v4f)0.0f;
            dA0 = __builtin_amdgcn_mfma_f32_16x16x32_bf16(kf0, qfA, dA0, 0, 0, 0);
            float pe[4];
#pragma unroll
            for (int r = 0; r < 4; ++r) {
                int k = 448 + 4 * fq + r;
                pe[r] = (k < L_)
                    ? exp2f(fmaf(dA0[r], scale2, -slope2 * fabsf(fqAq - (float)k))) : 0.f;
                psA += pe[r];
            }
            uint2 ue;
            ue.x = pack_bf2(pe[0], pe[1]); ue.y = pack_bf2(pe[2], pe[3]);
            oA0 = mfma16(va0, ue, oA0);
            oA1 = mfma16(va1, ue, oA1);
            if (twoB) {
                v4f dB0 = (v4f)0.0f;
                dB0 = __builtin_amdgcn_mfma_f32_16x16x32_bf16(kf0, qfB, dB0, 0, 0, 0);
                float pf[4];
#pragma unroll
                for (int r = 0; r < 4; ++r) {
                    int k = 448 + 4 * fq + r;
                    pf[r] = (k < L_)
                        ? exp2f(fmaf(dB0[r], scale2, -slope2 * fabsf(fqBq - (float)k))) : 0.f;
                    psB += pf[r];
                }
                uint2 ub;
                ub.x = pack_bf2(pf[0], pf[1]); ub.y = pack_bf2(pf[2], pf[3]);
                oB0 = mfma16(va0, ub, oB0);
                oB1 = mfma16(va1, ub, oB1);
            }
        }

        psA += __shfl_xor(psA, 16);
        psA += __shfl_xor(psA, 32);
        psB += __shfl_xor(psB, 16);
        psB += __shfl_xor(psB, 32);
        {
            int q = q0 + fr;
            if (q < L_) {
                float inv = 1.0f / psA;
                uint2 w0, w1;
                w0.x = pack_bf2(oA0[0] * inv, oA0[1] * inv);
                w0.y = pack_bf2(oA0[2] * inv, oA0[3] * inv);
                w1.x = pack_bf2(oA1[0] * inv, oA1[1] * inv);
                w1.y = pack_bf2(oA1[2] * inv, oA1[3] * inv);
                ushort* op = out + (size_t)(b * L_ + q) * D_ + h * 32;
                *(uint2*)(op + fq * 4) = w0;
                *(uint2*)(op + 16 + fq * 4) = w1;
            }
        }
        if (twoB) {
            int q = q0 + 16 + fr;
            if (q < L_) {
                float inv = 1.0f / psB;
                uint2 w0, w1;
                w0.x = pack_bf2(oB0[0] * inv, oB0[1] * inv);
                w0.y = pack_bf2(oB0[2] * inv, oB0[3] * inv);
                w1.x = pack_bf2(oB1[0] * inv, oB1[1] * inv);
                w1.y = pack_bf2(oB1[2] * inv, oB1[3] * inv);
                ushort* op = out + (size_t)(b * L_ + q) * D_ + h * 32;
                *(uint2*)(op + fq * 4) = w0;
                *(uint2*)(op + 16 + fq * 4) = w1;
            }
        }
    }
}

// ---------------------------------------------------------------------------
// Fused residual+LN, all-bf16 streams: Xb <- LN(Xb + AOb). fp32 math inside.
// ---------------------------------------------------------------------------
__global__ __launch_bounds__(256) void ln_kernel(
    const ushort* __restrict__ res, const ushort* __restrict__ y,
    const float* __restrict__ g, const float* __restrict__ bb,
    ushort* __restrict__ xbout)
{
    int row = blockIdx.x * 4 + (threadIdx.x >> 6);
    int lane = threadIdx.x & 63;
    size_t off = (size_t)row * D_ + lane * 4;
    ushort4 rv4 = *(const ushort4*)(res + off);
    ushort4 yv4 = *(const ushort4*)(y + off);
    float4 v;
    v.x = bu2f(rv4.x) + bu2f(yv4.x);
    v.y = bu2f(rv4.y) + bu2f(yv4.y);
    v.z = bu2f(rv4.z) + bu2f(yv4.z);
    v.w = bu2f(rv4.w) + bu2f(yv4.w);

    float s = v.x + v.y + v.z + v.w;
#pragma unroll
    for (int o = 1; o < 64; o <<= 1) s += __shfl_xor(s, o);
    float mean = s * (1.0f / 256.0f);

    float4 d;
    d.x = v.x - mean; d.y = v.y - mean; d.z = v.z - mean; d.w = v.w - mean;
    float sq = d.x * d.x + d.y * d.y + d.z * d.z + d.w * d.w;
#pragma unroll
    for (int o = 1; o < 64; o <<= 1) sq += __shfl_xor(sq, o);
    float rstd = rsqrtf(sq * (1.0f / 256.0f) + 1e-5f);

    float4 gv = *(const float4*)(g + lane * 4);
    float4 bv = *(const float4*)(bb + lane * 4);
    ushort4 hb;
    hb.x = f2bu(d.x * rstd * gv.x + bv.x);
    hb.y = f2bu(d.y * rstd * gv.y + bv.y);
    hb.z = f2bu(d.z * rstd * gv.z + bv.z);
    hb.w = f2bu(d.w * rstd * gv.w + bv.w);
    *(ushort4*)(xbout + off) = hb;
}

// ---------------------------------------------------------------------------
// head1 via MFMA: SCp[row] = gelu(bn(Xb@th1_w + b1)) @ th2_w + b2.
// ---------------------------------------------------------------------------
__global__ __launch_bounds__(256) void head1_kernel(
    const ushort* __restrict__ Xb, const ushort* __restrict__ th1T,
    const float* __restrict__ b1, const float* __restrict__ bng,
    const float* __restrict__ bnb, const float* __restrict__ w2,
    const float* __restrict__ b2, float* __restrict__ SCp)
{
    __shared__ ushort As[128 * 32];
    __shared__ ushort Bs[32 * 264];
    int tid = threadIdx.x;
    int wave = tid >> 6, lane = tid & 63;
    int fr = lane & 15, fq = lane >> 4;
    int rowblk = blockIdx.x * 128;
    int scol = fq ^ (lane & 3) ^ ((lane >> 2) & 1);

    for (int i = tid; i < 1024; i += 256) {
        int r = i >> 5, c8 = (i & 31) * 8;
        *(uint4*)&Bs[r * 264 + c8] = *(const uint4*)(th1T + r * 256 + c8);
    }

    int c0 = wave * 64 + lane;
    int r0 = c0 >> 2, k0g = (c0 & 3) ^ (r0 & 3) ^ ((r0 >> 2) & 1);
    int c1 = 256 + c0;
    int r1 = c1 >> 2, k1g = (c1 & 3) ^ (r1 & 3) ^ ((r1 >> 2) & 1);
    const ushort* Ag0 = Xb + (size_t)(rowblk + r0) * 256 + k0g * 8;
    const ushort* Ag1 = Xb + (size_t)(rowblk + r1) * 256 + k1g * 8;
    ushort* lA0 = As + (size_t)(wave * 64) * 8;
    ushort* lA1 = As + (size_t)(256 + wave * 64) * 8;

    v4f acc[2][2];
#pragma unroll
    for (int i = 0; i < 2; ++i)
#pragma unroll
        for (int j = 0; j < 2; ++j) acc[i][j] = (v4f)0.0f;

    for (int kt = 0; kt < 256; kt += 32) {
        gload16(Ag0 + kt, lA0);
        gload16(Ag1 + kt, lA1);
        __syncthreads();
        v8bf a[2], bfr[2];
#pragma unroll
        for (int mi = 0; mi < 2; ++mi)
            a[mi] = *(const v8bf*)(As + (size_t)((wave * 2 + mi) * 16 + fr) * 32 + scol * 8);
#pragma unroll
        for (int ni = 0; ni < 2; ++ni)
            bfr[ni] = *(const v8bf*)(Bs + (size_t)(ni * 16 + fr) * 264 + kt + fq * 8);
#pragma unroll
        for (int mi = 0; mi < 2; ++mi)
#pragma unroll
            for (int ni = 0; ni < 2; ++ni)
                acc[mi][ni] = __builtin_amdgcn_mfma_f32_16x16x32_bf16(
                    a[mi], bfr[ni], acc[mi][ni], 0, 0, 0);
        __syncthreads();
    }

    const float bnr = 0.9999950000374997f;  // rsqrt(1+1e-5)
    float b1v[2], bsv[2], bbv[2], w2v[2];
#pragma unroll
    for (int ni = 0; ni < 2; ++ni) {
        int j = ni * 16 + fr;
        b1v[ni] = b1[j];
        bsv[ni] = bng[j] * bnr;
        bbv[ni] = bnb[j];
        w2v[ni] = w2[j];
    }
    const float gc = 0.7978845608028654f;
    float b2v = b2[0];
#pragma unroll
    for (int mi = 0; mi < 2; ++mi) {
#pragma unroll
        for (int r = 0; r < 4; ++r) {
            float s = 0.f;
#pragma unroll
            for (int ni = 0; ni < 2; ++ni) {
                float hb = (acc[mi][ni][r] + b1v[ni]) * bsv[ni] + bbv[ni];
                float t = tanhf(gc * (hb + 0.044715f * hb * hb * hb));
                s += 0.5f * hb * (1.0f + t) * w2v[ni];
            }
#pragma unroll
            for (int o = 1; o < 16; o <<= 1) s += __shfl_xor(s, o);
            int row = rowblk + (wave * 2 + mi) * 16 + fq * 4 + r;
            if (fr == 0 && row < B_ * L_) SCp[row] = s + b2v;
        }
    }
}

// ---------------------------------------------------------------------------
// head2: block (colgroup, b); 64 cols x 4 L-partitions per block. Pools bf16 Xb.
// ---------------------------------------------------------------------------
__global__ __launch_bounds__(256) void head2_kernel(
    const float* __restrict__ SCp, const ushort* __restrict__ Xb,
    float* __restrict__ outp)
{
    int cg = blockIdx.x, b = blockIdx.y;
    int tid = threadIdx.x;
    __shared__ float wbuf[L_];
    __shared__ float r1[4], r2[4];
    __shared__ float part[4][64];
    const float* s = SCp + (size_t)b * L_;

    float m = -1e30f;
    for (int j = tid; j < L_; j += 256) m = fmaxf(m, s[j]);
#pragma unroll
    for (int o = 1; o < 64; o <<= 1) m = fmaxf(m, __shfl_xor(m, o));
    if ((tid & 63) == 0) r1[tid >> 6] = m;
    __syncthreads();
    m = fmaxf(fmaxf(r1[0], r1[1]), fmaxf(r1[2], r1[3]));

    float sum = 0.f;
    for (int j = tid; j < L_; j += 256) {
        float e = __expf(s[j] - m);
        wbuf[j] = e;
        sum += e;
    }
#pragma unroll
    for (int o = 1; o < 64; o <<= 1) sum += __shfl_xor(sum, o);
    if ((tid & 63) == 0) r2[tid >> 6] = sum;
    __syncthreads();
    float inv = 1.0f / (r2[0] + r2[1] + r2[2] + r2[3]);

    int c = tid & 63, pt = tid >> 6;
    int col = cg * 64 + c;
    float acc = 0.f;
    const ushort* xb = Xb + (size_t)b * L_ * D_ + col;
    for (int l = pt; l < L_; l += 4) acc += wbuf[l] * bu2f(xb[(size_t)l * D_]);
    part[pt][c] = acc;
    __syncthreads();
    if (pt == 0)
        outp[b * D_ + col] = (part[0][c] + part[1][c] + part[2][c] + part[3][c]) * inv;
}

// ---------------------------------------------------------------------------
extern "C" void kernel_launch(void* const* d_in, const int* in_sizes, int n_in,
                              void* d_out, int out_size, void* d_ws, size_t ws_size,
                              hipStream_t stream)
{
    const float* gene   = (const float*)d_in[0];
    const float* coords = (const float*)d_in[1];
    const float* w_in   = (const float*)d_in[2];
    const float* b_in   = (const float*)d_in[3];
    const float* w_cls  = (const float*)d_in[4];
    const float* b_cls  = (const float*)d_in[5];
    const float* qkv_w  = (const float*)d_in[6];
    const float* qkv_b  = (const float*)d_in[7];
    const float* ln1_g  = (const float*)d_in[8];
    const float* ln1_b  = (const float*)d_in[9];
    const float* ffn_w1 = (const float*)d_in[10];
    const float* ffn_b1 = (const float*)d_in[11];
    const float* ffn_w2 = (const float*)d_in[12];
    const float* ffn_b2 = (const float*)d_in[13];
    const float* ln2_g  = (const float*)d_in[14];
    const float* ln2_b  = (const float*)d_in[15];
    const float* th1_w  = (const float*)d_in[16];
    const float* th1_b  = (const float*)d_in[17];
    const float* bn_g   = (const float*)d_in[18];
    const float* bn_b   = (const float*)d_in[19];
    const float* th2_w  = (const float*)d_in[20];
    const float* th2_b  = (const float*)d_in[21];
    float* out = (float*)d_out;

    const int ROWS = B_ * L_;   // 29248
    char* p = (char*)d_ws;
    ushort* AOb  = (ushort*)p; p += (size_t)MPAD * 256 * 2;
    ushort* Xb   = (ushort*)p; p += (size_t)MPAD * 256 * 2;
    ushort* SH   = (ushort*)p; p += (size_t)MPAD * 1024 * 2;
    ushort* qkvT = (ushort*)p; p += (size_t)NL_ * 768 * 256 * 2;
    ushort* w1T  = (ushort*)p; p += (size_t)NL_ * 1024 * 256 * 2;
    ushort* w2T  = (ushort*)p; p += (size_t)NL_ * 256 * 1024 * 2;
    ushort* th1T = (ushort*)p; p += (size_t)32 * 256 * 2;
    float*  SCp  = (float*)p;  p += (size_t)ROWS * 4;

    wcast_kernel<<<dim3(768 / 32, 256 / 32, NL_), dim3(32, 8), 0, stream>>>(qkv_w, qkvT, 256, 768);
    wcast_kernel<<<dim3(1024 / 32, 256 / 32, NL_), dim3(32, 8), 0, stream>>>(ffn_w1, w1T, 256, 1024);
    wcast_kernel<<<dim3(256 / 32, 1024 / 32, NL_), dim3(32, 8), 0, stream>>>(ffn_w2, w2T, 1024, 256);
    wcast_kernel<<<dim3(1, 8, 1), dim3(32, 8), 0, stream>>>(th1_w, th1T, 256, 32);

    sgemm_kernel<<<dim3(D_ / 64, (B_ * NT_) / 64), 256, 0, stream>>>(
        gene, w_in, b_in, Xb, B_ * NT_, D_, TOK_);
    cls_kernel<<<B_, 256, 0, stream>>>(coords, w_cls, b_cls, Xb);

    for (int l = 0; l < NL_; ++l) {
        mfma_gemm<<<dim3(768 / 128, MPAD / 128), 256, 0, stream>>>(
            Xb, qkvT + (size_t)l * 768 * 256, qkv_b + l * 768, SH, 768, 256, 0, 1);
        attn_kernel<<<dim3(H_, B_), 512, 0, stream>>>(SH, AOb);
        ln_kernel<<<ROWS / 4, 256, 0, stream>>>(Xb, AOb, ln1_g + l * D_, ln1_b + l * D_, Xb);
        mfma_gemm<<<dim3(1024 / 128, MPAD / 128), 256, 0, stream>>>(
            Xb, w1T + (size_t)l * 1024 * 256, ffn_b1 + l * 1024, SH, 1024, 256, 1, 1);
        mfma_gemm<<<dim3(256 / 128, MPAD / 128), 256, 0, stream>>>(
            SH, w2T + (size_t)l * 256 * 1024, ffn_b2 + l * D_, AOb, 256, 1024, 0, 1);
        ln_kernel<<<ROWS / 4, 256, 0, stream>>>(Xb, AOb, ln2_g + l * D_, ln2_b + l * D_, Xb);
    }

    head1_kernel<<<MPAD / 128, 256, 0, stream>>>(
        Xb, th1T, th1_b, bn_g, bn_b, th2_w, th2_b, SCp);
    head2_kernel<<<dim3(4, B_), 256, 0, stream>>>(SCp, Xb, out);
}

// Round 15
// 779.710 us; speedup vs baseline: 1.5117x; 1.0754x over previous
//
#include <hip/hip_runtime.h>
#include <math.h>

#define B_   64
#define TOK_ 64
#define NT_  456
#define L_   457
#define D_   256
#define H_   8
#define HD_  32
#define FF_  1024
#define NL_  4
#define PH_  32
#define MPAD 29312   // 229 * 128 (rows padded for 128-row GEMM tiles)

typedef unsigned int uint;
typedef unsigned short ushort;
typedef __bf16 v8bf __attribute__((ext_vector_type(8)));
typedef __bf16 v4bf __attribute__((ext_vector_type(4)));
typedef short v4s __attribute__((ext_vector_type(4)));
typedef float v4f __attribute__((ext_vector_type(4)));

__device__ __forceinline__ float bu2f(ushort x) {
    return __uint_as_float(((uint)x) << 16);
}
__device__ __forceinline__ ushort f2bu(float f) {
    union { float f; uint u; } x; x.f = f;
    uint r = (x.u + 0x7fffu + ((x.u >> 16) & 1u)) >> 16;
    return (ushort)r;
}
__device__ __forceinline__ uint pack_bf2(float a, float b) {
#if defined(__HIP_DEVICE_COMPILE__) && __has_builtin(__builtin_amdgcn_cvt_pk_bf16_f32)
    typedef __bf16 bf2v __attribute__((ext_vector_type(2)));
    bf2v v = __builtin_amdgcn_cvt_pk_bf16_f32(a, b);
    return *(uint*)&v;
#else
    return (uint)f2bu(a) | ((uint)f2bu(b) << 16);
#endif
}

// K=16 bf16 MFMA (PV with register-resident P). Guarded for the host pass.
__device__ __forceinline__ v4f mfma16(uint2 a, uint2 b, v4f c) {
#if defined(__HIP_DEVICE_COMPILE__)
#if __has_builtin(__builtin_amdgcn_mfma_f32_16x16x16_bf16)
    return __builtin_amdgcn_mfma_f32_16x16x16_bf16(*(v4bf*)&a, *(v4bf*)&b, c, 0, 0, 0);
#else
    return __builtin_amdgcn_mfma_f32_16x16x16bf16_1k(*(v4s*)&a, *(v4s*)&b, c, 0, 0, 0);
#endif
#else
    (void)a; (void)b;
    return c;
#endif
}

// async global->LDS 16B copy; lds base wave-uniform, data at base + lane*16.
__device__ __forceinline__ void gload16(const void* g, void* l) {
    __builtin_amdgcn_global_load_lds(
        (const __attribute__((address_space(1))) void*)(unsigned long long)(uintptr_t)g,
        (__attribute__((address_space(3))) void*)(uint)(uintptr_t)l,
        16, 0, 0);
}

// ---------------------------------------------------------------------------
// bf16 MFMA GEMM, BK=64: C[M,N] = A[M,K]·W^T[N,K] + bias. 128x128 tile,
// 4 waves (2x2). K%64==0. LDS 32 KB. Flat-granule layout with XOR swizzle.
// ---------------------------------------------------------------------------
__global__ __launch_bounds__(256) void mfma_gemm(
    const ushort* __restrict__ A, const ushort* __restrict__ WT,
    const float* __restrict__ bias, void* __restrict__ Cout,
    int N, int K, int relu, int obf16)
{
    __shared__ ushort As[128 * 64];
    __shared__ ushort Bs[128 * 64];
    int tid = threadIdx.x;
    int wave = tid >> 6, lane = tid & 63;
    int colblk = blockIdx.x * 128;
    int rowblk = blockIdx.y * 128;
    int wm = wave >> 1, wn = wave & 1;
    int fr = lane & 15, fq = lane >> 4;

    v4f acc[4][4];
#pragma unroll
    for (int i = 0; i < 4; ++i)
#pragma unroll
        for (int j = 0; j < 4; ++j) acc[i][j] = (v4f)0.0f;

    const ushort* Ag[4];
    const ushort* Bg[4];
    ushort* lA[4];
    ushort* lB[4];
#pragma unroll
    for (int p = 0; p < 4; ++p) {
        int c = p * 256 + wave * 64 + lane;
        int r = c >> 3, gs = (c & 7) ^ (r & 7);
        Ag[p] = A + (size_t)(rowblk + r) * K + gs * 8;
        Bg[p] = WT + (size_t)(colblk + r) * K + gs * 8;
        lA[p] = As + (size_t)(p * 256 + wave * 64) * 8;
        lB[p] = Bs + (size_t)(p * 256 + wave * 64) * 8;
    }

    for (int kt = 0; kt < K; kt += 64) {
#pragma unroll
        for (int p = 0; p < 4; ++p) gload16(Ag[p] + kt, lA[p]);
#pragma unroll
        for (int p = 0; p < 4; ++p) gload16(Bg[p] + kt, lB[p]);
        __syncthreads();

#pragma unroll
        for (int ks = 0; ks < 2; ++ks) {
            int pa = (ks * 4 + fq) ^ (fr & 7);
            v8bf a[4], b[4];
#pragma unroll
            for (int mi = 0; mi < 4; ++mi) {
                int rl = wm * 64 + mi * 16 + fr;
                a[mi] = *(const v8bf*)(As + (size_t)(rl * 8 + pa) * 8);
            }
#pragma unroll
            for (int ni = 0; ni < 4; ++ni) {
                int rl = wn * 64 + ni * 16 + fr;
                b[ni] = *(const v8bf*)(Bs + (size_t)(rl * 8 + pa) * 8);
            }
#pragma unroll
            for (int mi = 0; mi < 4; ++mi)
#pragma unroll
                for (int ni = 0; ni < 4; ++ni)
                    acc[mi][ni] = __builtin_amdgcn_mfma_f32_16x16x32_bf16(
                        a[mi], b[ni], acc[mi][ni], 0, 0, 0);
        }
        __syncthreads();
    }

#pragma unroll
    for (int ni = 0; ni < 4; ++ni) {
        int col = colblk + wn * 64 + ni * 16 + fr;
        float bv = bias[col];
#pragma unroll
        for (int mi = 0; mi < 4; ++mi) {
            int row = rowblk + wm * 64 + mi * 16 + fq * 4;
#pragma unroll
            for (int r = 0; r < 4; ++r) {
                float v = acc[mi][ni][r] + bv;
                if (relu) v = fmaxf(v, 0.f);
                if (obf16)
                    ((ushort*)Cout)[(size_t)(row + r) * N + col] = f2bu(v);
                else
                    ((float*)Cout)[(size_t)(row + r) * N + col] = v;
            }
        }
    }
}

// ---------------------------------------------------------------------------
__global__ __launch_bounds__(256) void wcast_kernel(
    const float* __restrict__ W, ushort* __restrict__ WT, int K, int N)
{
    __shared__ float t[32][33];
    const float* Wl = W + (size_t)blockIdx.z * K * N;
    ushort* WTl = WT + (size_t)blockIdx.z * K * N;
    int n0 = blockIdx.x * 32, k0 = blockIdx.y * 32;
    int tx = threadIdx.x, ty = threadIdx.y;
#pragma unroll
    for (int r = 0; r < 32; r += 8)
        t[ty + r][tx] = Wl[(size_t)(k0 + ty + r) * N + n0 + tx];
    __syncthreads();
#pragma unroll
    for (int r = 0; r < 32; r += 8)
        WTl[(size_t)(n0 + ty + r) * K + k0 + tx] = f2bu(t[tx][ty + r]);
}

// ---------------------------------------------------------------------------
// fp32 SGEMM for the embed GEMM only; row-remap; writes bf16 Xb only.
// ---------------------------------------------------------------------------
__global__ __launch_bounds__(256) void sgemm_kernel(
    const float* __restrict__ A, const float* __restrict__ W,
    const float* __restrict__ bias, ushort* __restrict__ Cb,
    int M, int N, int K)
{
    __shared__ float As_[16][64];
    __shared__ float Bs_[16][64];
    int tid = threadIdx.x;
    int rowblk = blockIdx.y * 64;
    int colblk = blockIdx.x * 64;
    int a_row = tid & 63, a_q = tid >> 6;
    int b_kr = tid >> 4, b_cg = tid & 15;
    int rm = tid >> 4, cn = tid & 15;
    float acc[4][4] = {};
    const float* Aptr = A + (size_t)(rowblk + a_row) * K;
    for (int kt = 0; kt < K; kt += 16) {
        float4 av = *(const float4*)(Aptr + kt + a_q * 4);
        float4 bv = *(const float4*)(W + (size_t)(kt + b_kr) * N + colblk + b_cg * 4);
        As_[a_q * 4 + 0][a_row] = av.x;
        As_[a_q * 4 + 1][a_row] = av.y;
        As_[a_q * 4 + 2][a_row] = av.z;
        As_[a_q * 4 + 3][a_row] = av.w;
        *(float4*)&Bs_[b_kr][b_cg * 4] = bv;
        __syncthreads();
#pragma unroll
        for (int kk = 0; kk < 16; ++kk) {
            float4 a4 = *(const float4*)&As_[kk][rm * 4];
            float4 b4 = *(const float4*)&Bs_[kk][cn * 4];
            float ar[4] = {a4.x, a4.y, a4.z, a4.w};
            float br[4] = {b4.x, b4.y, b4.z, b4.w};
#pragma unroll
            for (int i = 0; i < 4; ++i)
#pragma unroll
                for (int j = 0; j < 4; ++j) acc[i][j] += ar[i] * br[j];
        }
        __syncthreads();
    }
    float4 bv = *(const float4*)(bias + colblk + cn * 4);
    float bb[4] = {bv.x, bv.y, bv.z, bv.w};
#pragma unroll
    for (int i = 0; i < 4; ++i) {
        int grow = rowblk + rm * 4 + i;
        size_t orow = (size_t)(grow + grow / NT_ + 1);
        ushort4 h;
        h.x = f2bu(acc[i][0] + bb[0]);
        h.y = f2bu(acc[i][1] + bb[1]);
        h.z = f2bu(acc[i][2] + bb[2]);
        h.w = f2bu(acc[i][3] + bb[3]);
        *(ushort4*)(Cb + orow * N + colblk + cn * 4) = h;
    }
}

__global__ __launch_bounds__(256) void cls_kernel(
    const float* __restrict__ coords, const float* __restrict__ w_cls,
    const float* __restrict__ b_cls, ushort* __restrict__ Xb)
{
    int b = blockIdx.x;
    int t = threadIdx.x;
    float c0 = coords[b * 3 + 0], c1 = coords[b * 3 + 1], c2 = coords[b * 3 + 2];
    float v = c0 * w_cls[t] + c1 * w_cls[D_ + t] + c2 * w_cls[2 * D_ + t] + b_cls[t];
    Xb[(size_t)b * L_ * D_ + t] = f2bu(v);
}

// ---------------------------------------------------------------------------
// MFMA attention v7 (banded alibi): one block per (b,h), 512 threads.
// Band W=32 (slope-1) / 64 (slope-0.5): dropped terms have relative weight
// <= e^{4-W} (score spread <= ~4 by LN-variance arithmetic; empirically
// absmax pinned at 1 ulp across W=full,112,80) -> e^{-28} x457 ~ 3e-10,
// invisible at bf16 output precision. Dual 16-row q-tiles per pass; exp2
// softmax; PV via mfma16. O-stores guarded q<L.
// ---------------------------------------------------------------------------
__global__ __launch_bounds__(512) void attn_kernel(
    const ushort* __restrict__ qkv, ushort* __restrict__ out)
{
    __shared__ __align__(16) ushort Ks[464][40];    // 36.3 KB
    __shared__ __align__(16) ushort Vt[32][488];    // 30.5 KB

    int h = blockIdx.x, b = blockIdx.y;
    int tid = threadIdx.x;
    int wave = tid >> 6, lane = tid & 63;
    int fr = lane & 15, fq = lane >> 4;
    const float scale2 = 0.17677669529663687f * 1.4426950408889634f;
    float slope2 = ((h < 4) ? 1.0f : 0.5f) * 1.4426950408889634f;
    int W = (h < 4) ? 32 : 64;   // band half-width (wave-uniform)
    const ushort* base = qkv + (size_t)b * L_ * 768;

    for (int j = tid >> 2; j < 464; j += 128) {
        int c8 = (tid & 3) * 8;
        uint4 u = make_uint4(0u, 0u, 0u, 0u);
        if (j < L_) u = *(const uint4*)(base + (size_t)j * 768 + 256 + h * 32 + c8);
        *(uint4*)&Ks[j][c8] = u;
    }
    for (int m = wave; m < 32; m += 8) {
        int dg = (m >> 3) * 8, jb = m & 7;
        int j = jb * 64 + lane;
        uint4 u = make_uint4(0u, 0u, 0u, 0u);
        if (j < L_) u = *(const uint4*)(base + (size_t)j * 768 + 512 + h * 32 + dg);
        if (j < 488) {
            const ushort* pu = (const ushort*)&u;
#pragma unroll
            for (int e = 0; e < 8; ++e) Vt[dg + e][j] = pu[e];
        }
    }
    __syncthreads();

    for (int pr = wave; pr < 15; pr += 8) {
        int q0 = pr * 32;
        int twoB = (pr < 14);
        int kclo = max(0, (q0 - W) >> 5);
        int kchi = min(13, (q0 + 31 + W) >> 5);      // last full 32-chunk
        int doTail = (q0 + 31 + W >= 448);
        uint4 quA = *(const uint4*)(base + (size_t)(q0 + fr) * 768 + h * 32 + fq * 8);
        v8bf qfA = *(v8bf*)&quA;
        uint4 quB = *(const uint4*)(base + (size_t)(q0 + 16 + fr) * 768 + h * 32 + fq * 8);
        v8bf qfB = *(v8bf*)&quB;
        float fqAq = (float)(q0 + fr);
        float fqBq = fqAq + 16.0f;
        float psA = 0.f, psB = 0.f;
        v4f oA0 = (v4f)0.0f, oA1 = (v4f)0.0f, oB0 = (v4f)0.0f, oB1 = (v4f)0.0f;

        for (int kc = kclo; kc <= kchi; ++kc) {
            int kb = kc * 32;
            v8bf kf0 = *(const v8bf*)&Ks[kb + fr][fq * 8];
            v8bf kf1 = *(const v8bf*)&Ks[kb + 16 + fr][fq * 8];
            uint2 va0 = *(const uint2*)&Vt[fr][kb + fq * 4];
            uint2 va1 = *(const uint2*)&Vt[16 + fr][kb + fq * 4];
            uint2 vb0 = *(const uint2*)&Vt[fr][kb + 16 + fq * 4];
            uint2 vb1 = *(const uint2*)&Vt[16 + fr][kb + 16 + fq * 4];
            float ke = (float)(kb + 4 * fq);

            v4f dA0 = (v4f)0.0f, dA1 = (v4f)0.0f;
            dA0 = __builtin_amdgcn_mfma_f32_16x16x32_bf16(kf0, qfA, dA0, 0, 0, 0);
            dA1 = __builtin_amdgcn_mfma_f32_16x16x32_bf16(kf1, qfA, dA1, 0, 0, 0);
            {
                float dl0 = fqAq - ke, dl1 = dl0 - 16.0f;
                float pe[4], po[4];
#pragma unroll
                for (int r = 0; r < 4; ++r) {
                    pe[r] = exp2f(fmaf(dA0[r], scale2, -slope2 * fabsf(dl0 - (float)r)));
                    po[r] = exp2f(fmaf(dA1[r], scale2, -slope2 * fabsf(dl1 - (float)r)));
                    psA += pe[r] + po[r];
                }
                uint2 ue, uo;
                ue.x = pack_bf2(pe[0], pe[1]); ue.y = pack_bf2(pe[2], pe[3]);
                uo.x = pack_bf2(po[0], po[1]); uo.y = pack_bf2(po[2], po[3]);
                oA0 = mfma16(va0, ue, oA0);
                oA1 = mfma16(va1, ue, oA1);
                oA0 = mfma16(vb0, uo, oA0);
                oA1 = mfma16(vb1, uo, oA1);
            }
            if (twoB) {
                v4f dB0 = (v4f)0.0f, dB1 = (v4f)0.0f;
                dB0 = __builtin_amdgcn_mfma_f32_16x16x32_bf16(kf0, qfB, dB0, 0, 0, 0);
                dB1 = __builtin_amdgcn_mfma_f32_16x16x32_bf16(kf1, qfB, dB1, 0, 0, 0);
                float dl0 = fqBq - ke, dl1 = dl0 - 16.0f;
                float pe[4], po[4];
#pragma unroll
                for (int r = 0; r < 4; ++r) {
                    pe[r] = exp2f(fmaf(dB0[r], scale2, -slope2 * fabsf(dl0 - (float)r)));
                    po[r] = exp2f(fmaf(dB1[r], scale2, -slope2 * fabsf(dl1 - (float)r)));
                    psB += pe[r] + po[r];
                }
                uint2 ue, uo;
                ue.x = pack_bf2(pe[0], pe[1]); ue.y = pack_bf2(pe[2], pe[3]);
                uo.x = pack_bf2(po[0], po[1]); uo.y = pack_bf2(po[2], po[3]);
                oB0 = mfma16(va0, ue, oB0);
                oB1 = mfma16(va1, ue, oB1);
                oB0 = mfma16(vb0, uo, oB0);
                oB1 = mfma16(vb1, uo, oB1);
            }
        }
        // tail chunk: k 448..463 (only if band reaches it)
        if (doTail) {
            v8bf kf0 = *(const v8bf*)&Ks[448 + fr][fq * 8];
            uint2 va0 = *(const uint2*)&Vt[fr][448 + fq * 4];
            uint2 va1 = *(const uint2*)&Vt[16 + fr][448 + fq * 4];
            v4f dA0 = (v4f)0.0f;
            dA0 = __builtin_amdgcn_mfma_f32_16x16x32_bf16(kf0, qfA, dA0, 0, 0, 0);
            float pe[4];
#pragma unroll
            for (int r = 0; r < 4; ++r) {
                int k = 448 + 4 * fq + r;
                pe[r] = (k < L_)
                    ? exp2f(fmaf(dA0[r], scale2, -slope2 * fabsf(fqAq - (float)k))) : 0.f;
                psA += pe[r];
            }
            uint2 ue;
            ue.x = pack_bf2(pe[0], pe[1]); ue.y = pack_bf2(pe[2], pe[3]);
            oA0 = mfma16(va0, ue, oA0);
            oA1 = mfma16(va1, ue, oA1);
            if (twoB) {
                v4f dB0 = (v4f)0.0f;
                dB0 = __builtin_amdgcn_mfma_f32_16x16x32_bf16(kf0, qfB, dB0, 0, 0, 0);
                float pf[4];
#pragma unroll
                for (int r = 0; r < 4; ++r) {
                    int k = 448 + 4 * fq + r;
                    pf[r] = (k < L_)
                        ? exp2f(fmaf(dB0[r], scale2, -slope2 * fabsf(fqBq - (float)k))) : 0.f;
                    psB += pf[r];
                }
                uint2 ub;
                ub.x = pack_bf2(pf[0], pf[1]); ub.y = pack_bf2(pf[2], pf[3]);
                oB0 = mfma16(va0, ub, oB0);
                oB1 = mfma16(va1, ub, oB1);
            }
        }

        psA += __shfl_xor(psA, 16);
        psA += __shfl_xor(psA, 32);
        psB += __shfl_xor(psB, 16);
        psB += __shfl_xor(psB, 32);
        {
            int q = q0 + fr;
            if (q < L_) {
                float inv = 1.0f / psA;
                uint2 w0, w1;
                w0.x = pack_bf2(oA0[0] * inv, oA0[1] * inv);
                w0.y = pack_bf2(oA0[2] * inv, oA0[3] * inv);
                w1.x = pack_bf2(oA1[0] * inv, oA1[1] * inv);
                w1.y = pack_bf2(oA1[2] * inv, oA1[3] * inv);
                ushort* op = out + (size_t)(b * L_ + q) * D_ + h * 32;
                *(uint2*)(op + fq * 4) = w0;
                *(uint2*)(op + 16 + fq * 4) = w1;
            }
        }
        if (twoB) {
            int q = q0 + 16 + fr;
            if (q < L_) {
                float inv = 1.0f / psB;
                uint2 w0, w1;
                w0.x = pack_bf2(oB0[0] * inv, oB0[1] * inv);
                w0.y = pack_bf2(oB0[2] * inv, oB0[3] * inv);
                w1.x = pack_bf2(oB1[0] * inv, oB1[1] * inv);
                w1.y = pack_bf2(oB1[2] * inv, oB1[3] * inv);
                ushort* op = out + (size_t)(b * L_ + q) * D_ + h * 32;
                *(uint2*)(op + fq * 4) = w0;
                *(uint2*)(op + 16 + fq * 4) = w1;
            }
        }
    }
}

// ---------------------------------------------------------------------------
// Fused residual+LN, all-bf16 streams: Xb <- LN(Xb + AOb). fp32 math inside.
// ---------------------------------------------------------------------------
__global__ __launch_bounds__(256) void ln_kernel(
    const ushort* __restrict__ res, const ushort* __restrict__ y,
    const float* __restrict__ g, const float* __restrict__ bb,
    ushort* __restrict__ xbout)
{
    int row = blockIdx.x * 4 + (threadIdx.x >> 6);
    int lane = threadIdx.x & 63;
    size_t off = (size_t)row * D_ + lane * 4;
    ushort4 rv4 = *(const ushort4*)(res + off);
    ushort4 yv4 = *(const ushort4*)(y + off);
    float4 v;
    v.x = bu2f(rv4.x) + bu2f(yv4.x);
    v.y = bu2f(rv4.y) + bu2f(yv4.y);
    v.z = bu2f(rv4.z) + bu2f(yv4.z);
    v.w = bu2f(rv4.w) + bu2f(yv4.w);

    float s = v.x + v.y + v.z + v.w;
#pragma unroll
    for (int o = 1; o < 64; o <<= 1) s += __shfl_xor(s, o);
    float mean = s * (1.0f / 256.0f);

    float4 d;
    d.x = v.x - mean; d.y = v.y - mean; d.z = v.z - mean; d.w = v.w - mean;
    float sq = d.x * d.x + d.y * d.y + d.z * d.z + d.w * d.w;
#pragma unroll
    for (int o = 1; o < 64; o <<= 1) sq += __shfl_xor(sq, o);
    float rstd = rsqrtf(sq * (1.0f / 256.0f) + 1e-5f);

    float4 gv = *(const float4*)(g + lane * 4);
    float4 bv = *(const float4*)(bb + lane * 4);
    ushort4 hb;
    hb.x = f2bu(d.x * rstd * gv.x + bv.x);
    hb.y = f2bu(d.y * rstd * gv.y + bv.y);
    hb.z = f2bu(d.z * rstd * gv.z + bv.z);
    hb.w = f2bu(d.w * rstd * gv.w + bv.w);
    *(ushort4*)(xbout + off) = hb;
}

// ---------------------------------------------------------------------------
// head1 via MFMA: SCp[row] = gelu(bn(Xb@th1_w + b1)) @ th2_w + b2.
// ---------------------------------------------------------------------------
__global__ __launch_bounds__(256) void head1_kernel(
    const ushort* __restrict__ Xb, const ushort* __restrict__ th1T,
    const float* __restrict__ b1, const float* __restrict__ bng,
    const float* __restrict__ bnb, const float* __restrict__ w2,
    const float* __restrict__ b2, float* __restrict__ SCp)
{
    __shared__ ushort As[128 * 32];
    __shared__ ushort Bs[32 * 264];
    int tid = threadIdx.x;
    int wave = tid >> 6, lane = tid & 63;
    int fr = lane & 15, fq = lane >> 4;
    int rowblk = blockIdx.x * 128;
    int scol = fq ^ (lane & 3) ^ ((lane >> 2) & 1);

    for (int i = tid; i < 1024; i += 256) {
        int r = i >> 5, c8 = (i & 31) * 8;
        *(uint4*)&Bs[r * 264 + c8] = *(const uint4*)(th1T + r * 256 + c8);
    }

    int c0 = wave * 64 + lane;
    int r0 = c0 >> 2, k0g = (c0 & 3) ^ (r0 & 3) ^ ((r0 >> 2) & 1);
    int c1 = 256 + c0;
    int r1 = c1 >> 2, k1g = (c1 & 3) ^ (r1 & 3) ^ ((r1 >> 2) & 1);
    const ushort* Ag0 = Xb + (size_t)(rowblk + r0) * 256 + k0g * 8;
    const ushort* Ag1 = Xb + (size_t)(rowblk + r1) * 256 + k1g * 8;
    ushort* lA0 = As + (size_t)(wave * 64) * 8;
    ushort* lA1 = As + (size_t)(256 + wave * 64) * 8;

    v4f acc[2][2];
#pragma unroll
    for (int i = 0; i < 2; ++i)
#pragma unroll
        for (int j = 0; j < 2; ++j) acc[i][j] = (v4f)0.0f;

    for (int kt = 0; kt < 256; kt += 32) {
        gload16(Ag0 + kt, lA0);
        gload16(Ag1 + kt, lA1);
        __syncthreads();
        v8bf a[2], bfr[2];
#pragma unroll
        for (int mi = 0; mi < 2; ++mi)
            a[mi] = *(const v8bf*)(As + (size_t)((wave * 2 + mi) * 16 + fr) * 32 + scol * 8);
#pragma unroll
        for (int ni = 0; ni < 2; ++ni)
            bfr[ni] = *(const v8bf*)(Bs + (size_t)(ni * 16 + fr) * 264 + kt + fq * 8);
#pragma unroll
        for (int mi = 0; mi < 2; ++mi)
#pragma unroll
            for (int ni = 0; ni < 2; ++ni)
                acc[mi][ni] = __builtin_amdgcn_mfma_f32_16x16x32_bf16(
                    a[mi], bfr[ni], acc[mi][ni], 0, 0, 0);
        __syncthreads();
    }

    const float bnr = 0.9999950000374997f;  // rsqrt(1+1e-5)
    float b1v[2], bsv[2], bbv[2], w2v[2];
#pragma unroll
    for (int ni = 0; ni < 2; ++ni) {
        int j = ni * 16 + fr;
        b1v[ni] = b1[j];
        bsv[ni] = bng[j] * bnr;
        bbv[ni] = bnb[j];
        w2v[ni] = w2[j];
    }
    const float gc = 0.7978845608028654f;
    float b2v = b2[0];
#pragma unroll
    for (int mi = 0; mi < 2; ++mi) {
#pragma unroll
        for (int r = 0; r < 4; ++r) {
            float s = 0.f;
#pragma unroll
            for (int ni = 0; ni < 2; ++ni) {
                float hb = (acc[mi][ni][r] + b1v[ni]) * bsv[ni] + bbv[ni];
                float t = tanhf(gc * (hb + 0.044715f * hb * hb * hb));
                s += 0.5f * hb * (1.0f + t) * w2v[ni];
            }
#pragma unroll
            for (int o = 1; o < 16; o <<= 1) s += __shfl_xor(s, o);
            int row = rowblk + (wave * 2 + mi) * 16 + fq * 4 + r;
            if (fr == 0 && row < B_ * L_) SCp[row] = s + b2v;
        }
    }
}

// ---------------------------------------------------------------------------
// head2: block (colgroup, b); 64 cols x 4 L-partitions per block. Pools bf16 Xb.
// ---------------------------------------------------------------------------
__global__ __launch_bounds__(256) void head2_kernel(
    const float* __restrict__ SCp, const ushort* __restrict__ Xb,
    float* __restrict__ outp)
{
    int cg = blockIdx.x, b = blockIdx.y;
    int tid = threadIdx.x;
    __shared__ float wbuf[L_];
    __shared__ float r1[4], r2[4];
    __shared__ float part[4][64];
    const float* s = SCp + (size_t)b * L_;

    float m = -1e30f;
    for (int j = tid; j < L_; j += 256) m = fmaxf(m, s[j]);
#pragma unroll
    for (int o = 1; o < 64; o <<= 1) m = fmaxf(m, __shfl_xor(m, o));
    if ((tid & 63) == 0) r1[tid >> 6] = m;
    __syncthreads();
    m = fmaxf(fmaxf(r1[0], r1[1]), fmaxf(r1[2], r1[3]));

    float sum = 0.f;
    for (int j = tid; j < L_; j += 256) {
        float e = __expf(s[j] - m);
        wbuf[j] = e;
        sum += e;
    }
#pragma unroll
    for (int o = 1; o < 64; o <<= 1) sum += __shfl_xor(sum, o);
    if ((tid & 63) == 0) r2[tid >> 6] = sum;
    __syncthreads();
    float inv = 1.0f / (r2[0] + r2[1] + r2[2] + r2[3]);

    int c = tid & 63, pt = tid >> 6;
    int col = cg * 64 + c;
    float acc = 0.f;
    const ushort* xb = Xb + (size_t)b * L_ * D_ + col;
    for (int l = pt; l < L_; l += 4) acc += wbuf[l] * bu2f(xb[(size_t)l * D_]);
    part[pt][c] = acc;
    __syncthreads();
    if (pt == 0)
        outp[b * D_ + col] = (part[0][c] + part[1][c] + part[2][c] + part[3][c]) * inv;
}

// ---------------------------------------------------------------------------
extern "C" void kernel_launch(void* const* d_in, const int* in_sizes, int n_in,
                              void* d_out, int out_size, void* d_ws, size_t ws_size,
                              hipStream_t stream)
{
    const float* gene   = (const float*)d_in[0];
    const float* coords = (const float*)d_in[1];
    const float* w_in   = (const float*)d_in[2];
    const float* b_in   = (const float*)d_in[3];
    const float* w_cls  = (const float*)d_in[4];
    const float* b_cls  = (const float*)d_in[5];
    const float* qkv_w  = (const float*)d_in[6];
    const float* qkv_b  = (const float*)d_in[7];
    const float* ln1_g  = (const float*)d_in[8];
    const float* ln1_b  = (const float*)d_in[9];
    const float* ffn_w1 = (const float*)d_in[10];
    const float* ffn_b1 = (const float*)d_in[11];
    const float* ffn_w2 = (const float*)d_in[12];
    const float* ffn_b2 = (const float*)d_in[13];
    const float* ln2_g  = (const float*)d_in[14];
    const float* ln2_b  = (const float*)d_in[15];
    const float* th1_w  = (const float*)d_in[16];
    const float* th1_b  = (const float*)d_in[17];
    const float* bn_g   = (const float*)d_in[18];
    const float* bn_b   = (const float*)d_in[19];
    const float* th2_w  = (const float*)d_in[20];
    const float* th2_b  = (const float*)d_in[21];
    float* out = (float*)d_out;

    const int ROWS = B_ * L_;   // 29248
    char* p = (char*)d_ws;
    ushort* AOb  = (ushort*)p; p += (size_t)MPAD * 256 * 2;
    ushort* Xb   = (ushort*)p; p += (size_t)MPAD * 256 * 2;
    ushort* SH   = (ushort*)p; p += (size_t)MPAD * 1024 * 2;
    ushort* qkvT = (ushort*)p; p += (size_t)NL_ * 768 * 256 * 2;
    ushort* w1T  = (ushort*)p; p += (size_t)NL_ * 1024 * 256 * 2;
    ushort* w2T  = (ushort*)p; p += (size_t)NL_ * 256 * 1024 * 2;
    ushort* th1T = (ushort*)p; p += (size_t)32 * 256 * 2;
    float*  SCp  = (float*)p;  p += (size_t)ROWS * 4;

    wcast_kernel<<<dim3(768 / 32, 256 / 32, NL_), dim3(32, 8), 0, stream>>>(qkv_w, qkvT, 256, 768);
    wcast_kernel<<<dim3(1024 / 32, 256 / 32, NL_), dim3(32, 8), 0, stream>>>(ffn_w1, w1T, 256, 1024);
    wcast_kernel<<<dim3(256 / 32, 1024 / 32, NL_), dim3(32, 8), 0, stream>>>(ffn_w2, w2T, 1024, 256);
    wcast_kernel<<<dim3(1, 8, 1), dim3(32, 8), 0, stream>>>(th1_w, th1T, 256, 32);

    sgemm_kernel<<<dim3(D_ / 64, (B_ * NT_) / 64), 256, 0, stream>>>(
        gene, w_in, b_in, Xb, B_ * NT_, D_, TOK_);
    cls_kernel<<<B_, 256, 0, stream>>>(coords, w_cls, b_cls, Xb);

    for (int l = 0; l < NL_; ++l) {
        mfma_gemm<<<dim3(768 / 128, MPAD / 128), 256, 0, stream>>>(
            Xb, qkvT + (size_t)l * 768 * 256, qkv_b + l * 768, SH, 768, 256, 0, 1);
        attn_kernel<<<dim3(H_, B_), 512, 0, stream>>>(SH, AOb);
        ln_kernel<<<ROWS / 4, 256, 0, stream>>>(Xb, AOb, ln1_g + l * D_, ln1_b + l * D_, Xb);
        mfma_gemm<<<dim3(1024 / 128, MPAD / 128), 256, 0, stream>>>(
            Xb, w1T + (size_t)l * 1024 * 256, ffn_b1 + l * 1024, SH, 1024, 256, 1, 1);
        mfma_gemm<<<dim3(256 / 128, MPAD / 128), 256, 0, stream>>>(
            SH, w2T + (size_t)l * 256 * 1024, ffn_b2 + l * D_, AOb, 256, 1024, 0, 1);
        ln_kernel<<<ROWS / 4, 256, 0, stream>>>(Xb, AOb, ln2_g + l * D_, ln2_b + l * D_, Xb);
    }

    head1_kernel<<<MPAD / 128, 256, 0, stream>>>(
        Xb, th1T, th1_b, bn_g, bn_b, th2_w, th2_b, SCp);
    head2_kernel<<<dim3(4, B_), 256, 0, stream>>>(SCp, Xb, out);
}

// Round 16
// 715.393 us; speedup vs baseline: 1.6476x; 1.0899x over previous
//
#include <hip/hip_runtime.h>
#include <math.h>

#define B_   64
#define TOK_ 64
#define NT_  456
#define L_   457
#define D_   256
#define H_   8
#define HD_  32
#define FF_  1024
#define NL_  4
#define PH_  32
#define MPAD 29312   // 229 * 128 (rows padded for 128-row GEMM tiles)

typedef unsigned int uint;
typedef unsigned short ushort;
typedef __bf16 v8bf __attribute__((ext_vector_type(8)));
typedef __bf16 v4bf __attribute__((ext_vector_type(4)));
typedef short v4s __attribute__((ext_vector_type(4)));
typedef float v4f __attribute__((ext_vector_type(4)));

__device__ __forceinline__ float bu2f(ushort x) {
    return __uint_as_float(((uint)x) << 16);
}
__device__ __forceinline__ ushort f2bu(float f) {
    union { float f; uint u; } x; x.f = f;
    uint r = (x.u + 0x7fffu + ((x.u >> 16) & 1u)) >> 16;
    return (ushort)r;
}
__device__ __forceinline__ uint pack_bf2(float a, float b) {
#if defined(__HIP_DEVICE_COMPILE__) && __has_builtin(__builtin_amdgcn_cvt_pk_bf16_f32)
    typedef __bf16 bf2v __attribute__((ext_vector_type(2)));
    bf2v v = __builtin_amdgcn_cvt_pk_bf16_f32(a, b);
    return *(uint*)&v;
#else
    return (uint)f2bu(a) | ((uint)f2bu(b) << 16);
#endif
}

// K=16 bf16 MFMA (PV with register-resident P). Guarded for the host pass.
__device__ __forceinline__ v4f mfma16(uint2 a, uint2 b, v4f c) {
#if defined(__HIP_DEVICE_COMPILE__)
#if __has_builtin(__builtin_amdgcn_mfma_f32_16x16x16_bf16)
    return __builtin_amdgcn_mfma_f32_16x16x16_bf16(*(v4bf*)&a, *(v4bf*)&b, c, 0, 0, 0);
#else
    return __builtin_amdgcn_mfma_f32_16x16x16bf16_1k(*(v4s*)&a, *(v4s*)&b, c, 0, 0, 0);
#endif
#else
    (void)a; (void)b;
    return c;
#endif
}

// async global->LDS 16B copy; lds base wave-uniform, data at base + lane*16.
__device__ __forceinline__ void gload16(const void* g, void* l) {
    __builtin_amdgcn_global_load_lds(
        (const __attribute__((address_space(1))) void*)(unsigned long long)(uintptr_t)g,
        (__attribute__((address_space(3))) void*)(uint)(uintptr_t)l,
        16, 0, 0);
}

// ---------------------------------------------------------------------------
// bf16 MFMA GEMM, BK=64: C[M,N] = A[M,K]·W^T[N,K] + bias (bf16 out, opt relu).
// 128x128 tile, 4 waves (2x2). K%64==0, N%128==0.
// 1-D grid with XCD-aware remap (blocks i -> XCD i%8 round-robin): each XCD
// gets a CONTIGUOUS run of col-fastest block ids, so all col-blocks of one
// A row-tile run on one XCD -> A stays L2-resident (kills the 4x over-fetch
// seen in r15 counters: FETCH 59 MB vs 16 ideal).
// Epilogue stages C in LDS (pitch 132: 2-way banks = free) then stores
// 8 uint4/thread -> full 128B lines (kills 2x write amplification:
// WRITE 115 MB vs 60 logical).
// ---------------------------------------------------------------------------
__global__ __launch_bounds__(256) void mfma_gemm(
    const ushort* __restrict__ A, const ushort* __restrict__ WT,
    const float* __restrict__ bias, ushort* __restrict__ Cout,
    int N, int K, int relu, int T)
{
    __shared__ ushort lds_all[128 * 132];   // staging (2x16KB) / epilogue (33KB)
    ushort* As = lds_all;
    ushort* Bs = lds_all + 128 * 64;

    int nCB = N >> 7;
    int per = gridDim.x >> 3;
    int lid = blockIdx.x;
    int nlid = (lid & 7) * per + (lid >> 3);
    if (nlid >= T) return;
    int colblk = (nlid % nCB) * 128;
    int rowblk = (nlid / nCB) * 128;

    int tid = threadIdx.x;
    int wave = tid >> 6, lane = tid & 63;
    int wm = wave >> 1, wn = wave & 1;
    int fr = lane & 15, fq = lane >> 4;

    v4f acc[4][4];
#pragma unroll
    for (int i = 0; i < 4; ++i)
#pragma unroll
        for (int j = 0; j < 4; ++j) acc[i][j] = (v4f)0.0f;

    const ushort* Ag[4];
    const ushort* Bg[4];
    ushort* lA[4];
    ushort* lB[4];
#pragma unroll
    for (int p = 0; p < 4; ++p) {
        int c = p * 256 + wave * 64 + lane;
        int r = c >> 3, gs = (c & 7) ^ (r & 7);
        Ag[p] = A + (size_t)(rowblk + r) * K + gs * 8;
        Bg[p] = WT + (size_t)(colblk + r) * K + gs * 8;
        lA[p] = As + (size_t)(p * 256 + wave * 64) * 8;
        lB[p] = Bs + (size_t)(p * 256 + wave * 64) * 8;
    }

    for (int kt = 0; kt < K; kt += 64) {
#pragma unroll
        for (int p = 0; p < 4; ++p) gload16(Ag[p] + kt, lA[p]);
#pragma unroll
        for (int p = 0; p < 4; ++p) gload16(Bg[p] + kt, lB[p]);
        __syncthreads();

#pragma unroll
        for (int ks = 0; ks < 2; ++ks) {
            int pa = (ks * 4 + fq) ^ (fr & 7);
            v8bf a[4], b[4];
#pragma unroll
            for (int mi = 0; mi < 4; ++mi) {
                int rl = wm * 64 + mi * 16 + fr;
                a[mi] = *(const v8bf*)(As + (size_t)(rl * 8 + pa) * 8);
            }
#pragma unroll
            for (int ni = 0; ni < 4; ++ni) {
                int rl = wn * 64 + ni * 16 + fr;
                b[ni] = *(const v8bf*)(Bs + (size_t)(rl * 8 + pa) * 8);
            }
#pragma unroll
            for (int mi = 0; mi < 4; ++mi)
#pragma unroll
                for (int ni = 0; ni < 4; ++ni)
                    acc[mi][ni] = __builtin_amdgcn_mfma_f32_16x16x32_bf16(
                        a[mi], b[ni], acc[mi][ni], 0, 0, 0);
        }
        __syncthreads();
    }

    // ---- epilogue: acc -> LDS (pitch 132) -> coalesced uint4 stores ----
#pragma unroll
    for (int ni = 0; ni < 4; ++ni) {
        int col = wn * 64 + ni * 16 + fr;
        float bv = bias[colblk + col];
#pragma unroll
        for (int mi = 0; mi < 4; ++mi) {
            int row0 = wm * 64 + mi * 16 + fq * 4;
#pragma unroll
            for (int r = 0; r < 4; ++r) {
                float v = acc[mi][ni][r] + bv;
                if (relu) v = fmaxf(v, 0.f);
                lds_all[(size_t)(row0 + r) * 132 + col] = f2bu(v);
            }
        }
    }
    __syncthreads();
#pragma unroll
    for (int i = 0; i < 8; ++i) {
        int u = tid + 256 * i;            // 0..2047
        int row = u >> 4, c8 = (u & 15) * 8;
        uint4 val = *(const uint4*)&lds_all[(size_t)row * 132 + c8];
        *(uint4*)(Cout + (size_t)(rowblk + row) * N + colblk + c8) = val;
    }
}

// ---------------------------------------------------------------------------
__global__ __launch_bounds__(256) void wcast_kernel(
    const float* __restrict__ W, ushort* __restrict__ WT, int K, int N)
{
    __shared__ float t[32][33];
    const float* Wl = W + (size_t)blockIdx.z * K * N;
    ushort* WTl = WT + (size_t)blockIdx.z * K * N;
    int n0 = blockIdx.x * 32, k0 = blockIdx.y * 32;
    int tx = threadIdx.x, ty = threadIdx.y;
#pragma unroll
    for (int r = 0; r < 32; r += 8)
        t[ty + r][tx] = Wl[(size_t)(k0 + ty + r) * N + n0 + tx];
    __syncthreads();
#pragma unroll
    for (int r = 0; r < 32; r += 8)
        WTl[(size_t)(n0 + ty + r) * K + k0 + tx] = f2bu(t[tx][ty + r]);
}

// ---------------------------------------------------------------------------
// fp32 SGEMM for the embed GEMM only; row-remap; writes bf16 Xb only.
// ---------------------------------------------------------------------------
__global__ __launch_bounds__(256) void sgemm_kernel(
    const float* __restrict__ A, const float* __restrict__ W,
    const float* __restrict__ bias, ushort* __restrict__ Cb,
    int M, int N, int K)
{
    __shared__ float As_[16][64];
    __shared__ float Bs_[16][64];
    int tid = threadIdx.x;
    int rowblk = blockIdx.y * 64;
    int colblk = blockIdx.x * 64;
    int a_row = tid & 63, a_q = tid >> 6;
    int b_kr = tid >> 4, b_cg = tid & 15;
    int rm = tid >> 4, cn = tid & 15;
    float acc[4][4] = {};
    const float* Aptr = A + (size_t)(rowblk + a_row) * K;
    for (int kt = 0; kt < K; kt += 16) {
        float4 av = *(const float4*)(Aptr + kt + a_q * 4);
        float4 bv = *(const float4*)(W + (size_t)(kt + b_kr) * N + colblk + b_cg * 4);
        As_[a_q * 4 + 0][a_row] = av.x;
        As_[a_q * 4 + 1][a_row] = av.y;
        As_[a_q * 4 + 2][a_row] = av.z;
        As_[a_q * 4 + 3][a_row] = av.w;
        *(float4*)&Bs_[b_kr][b_cg * 4] = bv;
        __syncthreads();
#pragma unroll
        for (int kk = 0; kk < 16; ++kk) {
            float4 a4 = *(const float4*)&As_[kk][rm * 4];
            float4 b4 = *(const float4*)&Bs_[kk][cn * 4];
            float ar[4] = {a4.x, a4.y, a4.z, a4.w};
            float br[4] = {b4.x, b4.y, b4.z, b4.w};
#pragma unroll
            for (int i = 0; i < 4; ++i)
#pragma unroll
                for (int j = 0; j < 4; ++j) acc[i][j] += ar[i] * br[j];
        }
        __syncthreads();
    }
    float4 bv = *(const float4*)(bias + colblk + cn * 4);
    float bb[4] = {bv.x, bv.y, bv.z, bv.w};
#pragma unroll
    for (int i = 0; i < 4; ++i) {
        int grow = rowblk + rm * 4 + i;
        size_t orow = (size_t)(grow + grow / NT_ + 1);
        ushort4 h;
        h.x = f2bu(acc[i][0] + bb[0]);
        h.y = f2bu(acc[i][1] + bb[1]);
        h.z = f2bu(acc[i][2] + bb[2]);
        h.w = f2bu(acc[i][3] + bb[3]);
        *(ushort4*)(Cb + orow * N + colblk + cn * 4) = h;
    }
}

__global__ __launch_bounds__(256) void cls_kernel(
    const float* __restrict__ coords, const float* __restrict__ w_cls,
    const float* __restrict__ b_cls, ushort* __restrict__ Xb)
{
    int b = blockIdx.x;
    int t = threadIdx.x;
    float c0 = coords[b * 3 + 0], c1 = coords[b * 3 + 1], c2 = coords[b * 3 + 2];
    float v = c0 * w_cls[t] + c1 * w_cls[D_ + t] + c2 * w_cls[2 * D_ + t] + b_cls[t];
    Xb[(size_t)b * L_ * D_ + t] = f2bu(v);
}

// ---------------------------------------------------------------------------
// MFMA attention v7 (banded alibi): one block per (b,h), 512 threads.
// Band W=32 (slope-1) / 64 (slope-0.5). Dual 16-row q-tiles per pass; exp2
// softmax; PV via mfma16. O-stores guarded q<L.
// ---------------------------------------------------------------------------
__global__ __launch_bounds__(512) void attn_kernel(
    const ushort* __restrict__ qkv, ushort* __restrict__ out)
{
    __shared__ __align__(16) ushort Ks[464][40];    // 36.3 KB
    __shared__ __align__(16) ushort Vt[32][488];    // 30.5 KB

    int h = blockIdx.x, b = blockIdx.y;
    int tid = threadIdx.x;
    int wave = tid >> 6, lane = tid & 63;
    int fr = lane & 15, fq = lane >> 4;
    const float scale2 = 0.17677669529663687f * 1.4426950408889634f;
    float slope2 = ((h < 4) ? 1.0f : 0.5f) * 1.4426950408889634f;
    int W = (h < 4) ? 32 : 64;   // band half-width (wave-uniform)
    const ushort* base = qkv + (size_t)b * L_ * 768;

    for (int j = tid >> 2; j < 464; j += 128) {
        int c8 = (tid & 3) * 8;
        uint4 u = make_uint4(0u, 0u, 0u, 0u);
        if (j < L_) u = *(const uint4*)(base + (size_t)j * 768 + 256 + h * 32 + c8);
        *(uint4*)&Ks[j][c8] = u;
    }
    for (int m = wave; m < 32; m += 8) {
        int dg = (m >> 3) * 8, jb = m & 7;
        int j = jb * 64 + lane;
        uint4 u = make_uint4(0u, 0u, 0u, 0u);
        if (j < L_) u = *(const uint4*)(base + (size_t)j * 768 + 512 + h * 32 + dg);
        if (j < 488) {
            const ushort* pu = (const ushort*)&u;
#pragma unroll
            for (int e = 0; e < 8; ++e) Vt[dg + e][j] = pu[e];
        }
    }
    __syncthreads();

    for (int pr = wave; pr < 15; pr += 8) {
        int q0 = pr * 32;
        int twoB = (pr < 14);
        int kclo = max(0, (q0 - W) >> 5);
        int kchi = min(13, (q0 + 31 + W) >> 5);      // last full 32-chunk
        int doTail = (q0 + 31 + W >= 448);
        uint4 quA = *(const uint4*)(base + (size_t)(q0 + fr) * 768 + h * 32 + fq * 8);
        v8bf qfA = *(v8bf*)&quA;
        uint4 quB = *(const uint4*)(base + (size_t)(q0 + 16 + fr) * 768 + h * 32 + fq * 8);
        v8bf qfB = *(v8bf*)&quB;
        float fqAq = (float)(q0 + fr);
        float fqBq = fqAq + 16.0f;
        float psA = 0.f, psB = 0.f;
        v4f oA0 = (v4f)0.0f, oA1 = (v4f)0.0f, oB0 = (v4f)0.0f, oB1 = (v4f)0.0f;

        for (int kc = kclo; kc <= kchi; ++kc) {
            int kb = kc * 32;
            v8bf kf0 = *(const v8bf*)&Ks[kb + fr][fq * 8];
            v8bf kf1 = *(const v8bf*)&Ks[kb + 16 + fr][fq * 8];
            uint2 va0 = *(const uint2*)&Vt[fr][kb + fq * 4];
            uint2 va1 = *(const uint2*)&Vt[16 + fr][kb + fq * 4];
            uint2 vb0 = *(const uint2*)&Vt[fr][kb + 16 + fq * 4];
            uint2 vb1 = *(const uint2*)&Vt[16 + fr][kb + 16 + fq * 4];
            float ke = (float)(kb + 4 * fq);

            v4f dA0 = (v4f)0.0f, dA1 = (v4f)0.0f;
            dA0 = __builtin_amdgcn_mfma_f32_16x16x32_bf16(kf0, qfA, dA0, 0, 0, 0);
            dA1 = __builtin_amdgcn_mfma_f32_16x16x32_bf16(kf1, qfA, dA1, 0, 0, 0);
            {
                float dl0 = fqAq - ke, dl1 = dl0 - 16.0f;
                float pe[4], po[4];
#pragma unroll
                for (int r = 0; r < 4; ++r) {
                    pe[r] = exp2f(fmaf(dA0[r], scale2, -slope2 * fabsf(dl0 - (float)r)));
                    po[r] = exp2f(fmaf(dA1[r], scale2, -slope2 * fabsf(dl1 - (float)r)));
                    psA += pe[r] + po[r];
                }
                uint2 ue, uo;
                ue.x = pack_bf2(pe[0], pe[1]); ue.y = pack_bf2(pe[2], pe[3]);
                uo.x = pack_bf2(po[0], po[1]); uo.y = pack_bf2(po[2], po[3]);
                oA0 = mfma16(va0, ue, oA0);
                oA1 = mfma16(va1, ue, oA1);
                oA0 = mfma16(vb0, uo, oA0);
                oA1 = mfma16(vb1, uo, oA1);
            }
            if (twoB) {
                v4f dB0 = (v4f)0.0f, dB1 = (v4f)0.0f;
                dB0 = __builtin_amdgcn_mfma_f32_16x16x32_bf16(kf0, qfB, dB0, 0, 0, 0);
                dB1 = __builtin_amdgcn_mfma_f32_16x16x32_bf16(kf1, qfB, dB1, 0, 0, 0);
                float dl0 = fqBq - ke, dl1 = dl0 - 16.0f;
                float pe[4], po[4];
#pragma unroll
                for (int r = 0; r < 4; ++r) {
                    pe[r] = exp2f(fmaf(dB0[r], scale2, -slope2 * fabsf(dl0 - (float)r)));
                    po[r] = exp2f(fmaf(dB1[r], scale2, -slope2 * fabsf(dl1 - (float)r)));
                    psB += pe[r] + po[r];
                }
                uint2 ue, uo;
                ue.x = pack_bf2(pe[0], pe[1]); ue.y = pack_bf2(pe[2], pe[3]);
                uo.x = pack_bf2(po[0], po[1]); uo.y = pack_bf2(po[2], po[3]);
                oB0 = mfma16(va0, ue, oB0);
                oB1 = mfma16(va1, ue, oB1);
                oB0 = mfma16(vb0, uo, oB0);
                oB1 = mfma16(vb1, uo, oB1);
            }
        }
        // tail chunk: k 448..463 (only if band reaches it)
        if (doTail) {
            v8bf kf0 = *(const v8bf*)&Ks[448 + fr][fq * 8];
            uint2 va0 = *(const uint2*)&Vt[fr][448 + fq * 4];
            uint2 va1 = *(const uint2*)&Vt[16 + fr][448 + fq * 4];
            v4f dA0 = (v4f)0.0f;
            dA0 = __builtin_amdgcn_mfma_f32_16x16x32_bf16(kf0, qfA, dA0, 0, 0, 0);
            float pe[4];
#pragma unroll
            for (int r = 0; r < 4; ++r) {
                int k = 448 + 4 * fq + r;
                pe[r] = (k < L_)
                    ? exp2f(fmaf(dA0[r], scale2, -slope2 * fabsf(fqAq - (float)k))) : 0.f;
                psA += pe[r];
            }
            uint2 ue;
            ue.x = pack_bf2(pe[0], pe[1]); ue.y = pack_bf2(pe[2], pe[3]);
            oA0 = mfma16(va0, ue, oA0);
            oA1 = mfma16(va1, ue, oA1);
            if (twoB) {
                v4f dB0 = (v4f)0.0f;
                dB0 = __builtin_amdgcn_mfma_f32_16x16x32_bf16(kf0, qfB, dB0, 0, 0, 0);
                float pf[4];
#pragma unroll
                for (int r = 0; r < 4; ++r) {
                    int k = 448 + 4 * fq + r;
                    pf[r] = (k < L_)
                        ? exp2f(fmaf(dB0[r], scale2, -slope2 * fabsf(fqBq - (float)k))) : 0.f;
                    psB += pf[r];
                }
                uint2 ub;
                ub.x = pack_bf2(pf[0], pf[1]); ub.y = pack_bf2(pf[2], pf[3]);
                oB0 = mfma16(va0, ub, oB0);
                oB1 = mfma16(va1, ub, oB1);
            }
        }

        psA += __shfl_xor(psA, 16);
        psA += __shfl_xor(psA, 32);
        psB += __shfl_xor(psB, 16);
        psB += __shfl_xor(psB, 32);
        {
            int q = q0 + fr;
            if (q < L_) {
                float inv = 1.0f / psA;
                uint2 w0, w1;
                w0.x = pack_bf2(oA0[0] * inv, oA0[1] * inv);
                w0.y = pack_bf2(oA0[2] * inv, oA0[3] * inv);
                w1.x = pack_bf2(oA1[0] * inv, oA1[1] * inv);
                w1.y = pack_bf2(oA1[2] * inv, oA1[3] * inv);
                ushort* op = out + (size_t)(b * L_ + q) * D_ + h * 32;
                *(uint2*)(op + fq * 4) = w0;
                *(uint2*)(op + 16 + fq * 4) = w1;
            }
        }
        if (twoB) {
            int q = q0 + 16 + fr;
            if (q < L_) {
                float inv = 1.0f / psB;
                uint2 w0, w1;
                w0.x = pack_bf2(oB0[0] * inv, oB0[1] * inv);
                w0.y = pack_bf2(oB0[2] * inv, oB0[3] * inv);
                w1.x = pack_bf2(oB1[0] * inv, oB1[1] * inv);
                w1.y = pack_bf2(oB1[2] * inv, oB1[3] * inv);
                ushort* op = out + (size_t)(b * L_ + q) * D_ + h * 32;
                *(uint2*)(op + fq * 4) = w0;
                *(uint2*)(op + 16 + fq * 4) = w1;
            }
        }
    }
}

// ---------------------------------------------------------------------------
// Fused residual+LN, all-bf16 streams: Xb <- LN(Xb + AOb). fp32 math inside.
// ---------------------------------------------------------------------------
__global__ __launch_bounds__(256) void ln_kernel(
    const ushort* __restrict__ res, const ushort* __restrict__ y,
    const float* __restrict__ g, const float* __restrict__ bb,
    ushort* __restrict__ xbout)
{
    int row = blockIdx.x * 4 + (threadIdx.x >> 6);
    int lane = threadIdx.x & 63;
    size_t off = (size_t)row * D_ + lane * 4;
    ushort4 rv4 = *(const ushort4*)(res + off);
    ushort4 yv4 = *(const ushort4*)(y + off);
    float4 v;
    v.x = bu2f(rv4.x) + bu2f(yv4.x);
    v.y = bu2f(rv4.y) + bu2f(yv4.y);
    v.z = bu2f(rv4.z) + bu2f(yv4.z);
    v.w = bu2f(rv4.w) + bu2f(yv4.w);

    float s = v.x + v.y + v.z + v.w;
#pragma unroll
    for (int o = 1; o < 64; o <<= 1) s += __shfl_xor(s, o);
    float mean = s * (1.0f / 256.0f);

    float4 d;
    d.x = v.x - mean; d.y = v.y - mean; d.z = v.z - mean; d.w = v.w - mean;
    float sq = d.x * d.x + d.y * d.y + d.z * d.z + d.w * d.w;
#pragma unroll
    for (int o = 1; o < 64; o <<= 1) sq += __shfl_xor(sq, o);
    float rstd = rsqrtf(sq * (1.0f / 256.0f) + 1e-5f);

    float4 gv = *(const float4*)(g + lane * 4);
    float4 bv = *(const float4*)(bb + lane * 4);
    ushort4 hb;
    hb.x = f2bu(d.x * rstd * gv.x + bv.x);
    hb.y = f2bu(d.y * rstd * gv.y + bv.y);
    hb.z = f2bu(d.z * rstd * gv.z + bv.z);
    hb.w = f2bu(d.w * rstd * gv.w + bv.w);
    *(ushort4*)(xbout + off) = hb;
}

// ---------------------------------------------------------------------------
// head1 via MFMA: SCp[row] = gelu(bn(Xb@th1_w + b1)) @ th2_w + b2.
// ---------------------------------------------------------------------------
__global__ __launch_bounds__(256) void head1_kernel(
    const ushort* __restrict__ Xb, const ushort* __restrict__ th1T,
    const float* __restrict__ b1, const float* __restrict__ bng,
    const float* __restrict__ bnb, const float* __restrict__ w2,
    const float* __restrict__ b2, float* __restrict__ SCp)
{
    __shared__ ushort As[128 * 32];
    __shared__ ushort Bs[32 * 264];
    int tid = threadIdx.x;
    int wave = tid >> 6, lane = tid & 63;
    int fr = lane & 15, fq = lane >> 4;
    int rowblk = blockIdx.x * 128;
    int scol = fq ^ (lane & 3) ^ ((lane >> 2) & 1);

    for (int i = tid; i < 1024; i += 256) {
        int r = i >> 5, c8 = (i & 31) * 8;
        *(uint4*)&Bs[r * 264 + c8] = *(const uint4*)(th1T + r * 256 + c8);
    }

    int c0 = wave * 64 + lane;
    int r0 = c0 >> 2, k0g = (c0 & 3) ^ (r0 & 3) ^ ((r0 >> 2) & 1);
    int c1 = 256 + c0;
    int r1 = c1 >> 2, k1g = (c1 & 3) ^ (r1 & 3) ^ ((r1 >> 2) & 1);
    const ushort* Ag0 = Xb + (size_t)(rowblk + r0) * 256 + k0g * 8;
    const ushort* Ag1 = Xb + (size_t)(rowblk + r1) * 256 + k1g * 8;
    ushort* lA0 = As + (size_t)(wave * 64) * 8;
    ushort* lA1 = As + (size_t)(256 + wave * 64) * 8;

    v4f acc[2][2];
#pragma unroll
    for (int i = 0; i < 2; ++i)
#pragma unroll
        for (int j = 0; j < 2; ++j) acc[i][j] = (v4f)0.0f;

    for (int kt = 0; kt < 256; kt += 32) {
        gload16(Ag0 + kt, lA0);
        gload16(Ag1 + kt, lA1);
        __syncthreads();
        v8bf a[2], bfr[2];
#pragma unroll
        for (int mi = 0; mi < 2; ++mi)
            a[mi] = *(const v8bf*)(As + (size_t)((wave * 2 + mi) * 16 + fr) * 32 + scol * 8);
#pragma unroll
        for (int ni = 0; ni < 2; ++ni)
            bfr[ni] = *(const v8bf*)(Bs + (size_t)(ni * 16 + fr) * 264 + kt + fq * 8);
#pragma unroll
        for (int mi = 0; mi < 2; ++mi)
#pragma unroll
            for (int ni = 0; ni < 2; ++ni)
                acc[mi][ni] = __builtin_amdgcn_mfma_f32_16x16x32_bf16(
                    a[mi], bfr[ni], acc[mi][ni], 0, 0, 0);
        __syncthreads();
    }

    const float bnr = 0.9999950000374997f;  // rsqrt(1+1e-5)
    float b1v[2], bsv[2], bbv[2], w2v[2];
#pragma unroll
    for (int ni = 0; ni < 2; ++ni) {
        int j = ni * 16 + fr;
        b1v[ni] = b1[j];
        bsv[ni] = bng[j] * bnr;
        bbv[ni] = bnb[j];
        w2v[ni] = w2[j];
    }
    const float gc = 0.7978845608028654f;
    float b2v = b2[0];
#pragma unroll
    for (int mi = 0; mi < 2; ++mi) {
#pragma unroll
        for (int r = 0; r < 4; ++r) {
            float s = 0.f;
#pragma unroll
            for (int ni = 0; ni < 2; ++ni) {
                float hb = (acc[mi][ni][r] + b1v[ni]) * bsv[ni] + bbv[ni];
                float t = tanhf(gc * (hb + 0.044715f * hb * hb * hb));
                s += 0.5f * hb * (1.0f + t) * w2v[ni];
            }
#pragma unroll
            for (int o = 1; o < 16; o <<= 1) s += __shfl_xor(s, o);
            int row = rowblk + (wave * 2 + mi) * 16 + fq * 4 + r;
            if (fr == 0 && row < B_ * L_) SCp[row] = s + b2v;
        }
    }
}

// ---------------------------------------------------------------------------
// head2: block (colgroup, b); 64 cols x 4 L-partitions per block. Pools bf16 Xb.
// ---------------------------------------------------------------------------
__global__ __launch_bounds__(256) void head2_kernel(
    const float* __restrict__ SCp, const ushort* __restrict__ Xb,
    float* __restrict__ outp)
{
    int cg = blockIdx.x, b = blockIdx.y;
    int tid = threadIdx.x;
    __shared__ float wbuf[L_];
    __shared__ float r1[4], r2[4];
    __shared__ float part[4][64];
    const float* s = SCp + (size_t)b * L_;

    float m = -1e30f;
    for (int j = tid; j < L_; j += 256) m = fmaxf(m, s[j]);
#pragma unroll
    for (int o = 1; o < 64; o <<= 1) m = fmaxf(m, __shfl_xor(m, o));
    if ((tid & 63) == 0) r1[tid >> 6] = m;
    __syncthreads();
    m = fmaxf(fmaxf(r1[0], r1[1]), fmaxf(r1[2], r1[3]));

    float sum = 0.f;
    for (int j = tid; j < L_; j += 256) {
        float e = __expf(s[j] - m);
        wbuf[j] = e;
        sum += e;
    }
#pragma unroll
    for (int o = 1; o < 64; o <<= 1) sum += __shfl_xor(sum, o);
    if ((tid & 63) == 0) r2[tid >> 6] = sum;
    __syncthreads();
    float inv = 1.0f / (r2[0] + r2[1] + r2[2] + r2[3]);

    int c = tid & 63, pt = tid >> 6;
    int col = cg * 64 + c;
    float acc = 0.f;
    const ushort* xb = Xb + (size_t)b * L_ * D_ + col;
    for (int l = pt; l < L_; l += 4) acc += wbuf[l] * bu2f(xb[(size_t)l * D_]);
    part[pt][c] = acc;
    __syncthreads();
    if (pt == 0)
        outp[b * D_ + col] = (part[0][c] + part[1][c] + part[2][c] + part[3][c]) * inv;
}

// ---------------------------------------------------------------------------
extern "C" void kernel_launch(void* const* d_in, const int* in_sizes, int n_in,
                              void* d_out, int out_size, void* d_ws, size_t ws_size,
                              hipStream_t stream)
{
    const float* gene   = (const float*)d_in[0];
    const float* coords = (const float*)d_in[1];
    const float* w_in   = (const float*)d_in[2];
    const float* b_in   = (const float*)d_in[3];
    const float* w_cls  = (const float*)d_in[4];
    const float* b_cls  = (const float*)d_in[5];
    const float* qkv_w  = (const float*)d_in[6];
    const float* qkv_b  = (const float*)d_in[7];
    const float* ln1_g  = (const float*)d_in[8];
    const float* ln1_b  = (const float*)d_in[9];
    const float* ffn_w1 = (const float*)d_in[10];
    const float* ffn_b1 = (const float*)d_in[11];
    const float* ffn_w2 = (const float*)d_in[12];
    const float* ffn_b2 = (const float*)d_in[13];
    const float* ln2_g  = (const float*)d_in[14];
    const float* ln2_b  = (const float*)d_in[15];
    const float* th1_w  = (const float*)d_in[16];
    const float* th1_b  = (const float*)d_in[17];
    const float* bn_g   = (const float*)d_in[18];
    const float* bn_b   = (const float*)d_in[19];
    const float* th2_w  = (const float*)d_in[20];
    const float* th2_b  = (const float*)d_in[21];
    float* out = (float*)d_out;

    const int ROWS = B_ * L_;   // 29248
    char* p = (char*)d_ws;
    ushort* AOb  = (ushort*)p; p += (size_t)MPAD * 256 * 2;
    ushort* Xb   = (ushort*)p; p += (size_t)MPAD * 256 * 2;
    ushort* SH   = (ushort*)p; p += (size_t)MPAD * 1024 * 2;
    ushort* qkvT = (ushort*)p; p += (size_t)NL_ * 768 * 256 * 2;
    ushort* w1T  = (ushort*)p; p += (size_t)NL_ * 1024 * 256 * 2;
    ushort* w2T  = (ushort*)p; p += (size_t)NL_ * 256 * 1024 * 2;
    ushort* th1T = (ushort*)p; p += (size_t)32 * 256 * 2;
    float*  SCp  = (float*)p;  p += (size_t)ROWS * 4;

    const int RB = MPAD / 128;                 // 229 row blocks
    const int Tqkv = (768 / 128) * RB;         // 1374
    const int Tff1 = (1024 / 128) * RB;        // 1832
    const int Tff2 = (256 / 128) * RB;         // 458
    const int Pqkv = (Tqkv + 7) & ~7;          // 1376
    const int Pff1 = (Tff1 + 7) & ~7;          // 1832
    const int Pff2 = (Tff2 + 7) & ~7;          // 464

    wcast_kernel<<<dim3(768 / 32, 256 / 32, NL_), dim3(32, 8), 0, stream>>>(qkv_w, qkvT, 256, 768);
    wcast_kernel<<<dim3(1024 / 32, 256 / 32, NL_), dim3(32, 8), 0, stream>>>(ffn_w1, w1T, 256, 1024);
    wcast_kernel<<<dim3(256 / 32, 1024 / 32, NL_), dim3(32, 8), 0, stream>>>(ffn_w2, w2T, 1024, 256);
    wcast_kernel<<<dim3(1, 8, 1), dim3(32, 8), 0, stream>>>(th1_w, th1T, 256, 32);

    sgemm_kernel<<<dim3(D_ / 64, (B_ * NT_) / 64), 256, 0, stream>>>(
        gene, w_in, b_in, Xb, B_ * NT_, D_, TOK_);
    cls_kernel<<<B_, 256, 0, stream>>>(coords, w_cls, b_cls, Xb);

    for (int l = 0; l < NL_; ++l) {
        mfma_gemm<<<Pqkv, 256, 0, stream>>>(
            Xb, qkvT + (size_t)l * 768 * 256, qkv_b + l * 768, SH, 768, 256, 0, Tqkv);
        attn_kernel<<<dim3(H_, B_), 512, 0, stream>>>(SH, AOb);
        ln_kernel<<<ROWS / 4, 256, 0, stream>>>(Xb, AOb, ln1_g + l * D_, ln1_b + l * D_, Xb);
        mfma_gemm<<<Pff1, 256, 0, stream>>>(
            Xb, w1T + (size_t)l * 1024 * 256, ffn_b1 + l * 1024, SH, 1024, 256, 1, Tff1);
        mfma_gemm<<<Pff2, 256, 0, stream>>>(
            SH, w2T + (size_t)l * 256 * 1024, ffn_b2 + l * D_, AOb, 256, 1024, 0, Tff2);
        ln_kernel<<<ROWS / 4, 256, 0, stream>>>(Xb, AOb, ln2_g + l * D_, ln2_b + l * D_, Xb);
    }

    head1_kernel<<<MPAD / 128, 256, 0, stream>>>(
        Xb, th1T, th1_b, bn_g, bn_b, th2_w, th2_b, SCp);
    head2_kernel<<<dim3(4, B_), 256, 0, stream>>>(SCp, Xb, out);
}